// Round 1
// baseline (1405.379 us; speedup 1.0000x reference)
//
#include <hip/hip_runtime.h>
#include <hip/hip_bf16.h>

#define B_    2
#define H_    512
#define W_    512
#define HW_   262144   // 512*512
#define EPSV  1e-12f

// ---------------------------------------------------------------------------
// K0: q = metainfo @ Wq^T + bq, then elementwise sign (F.normalize over dim of
// size 1). 512 values total.
__global__ __launch_bounds__(256) void k0_qsign(
    const float* __restrict__ metainfo, const float* __restrict__ Wq,
    const float* __restrict__ bq, float* __restrict__ qsign) {
  for (int idx = threadIdx.x; idx < 512; idx += 256) {
    const int b = idx >> 8, n = (idx >> 6) & 3, d = idx & 63;
    float acc = bq[n * 64 + d];
#pragma unroll
    for (int m = 0; m < 4; ++m)
      acc += metainfo[(b * 4 + n) * 4 + m] * Wq[(n * 64 + d) * 4 + m];
    qsign[idx] = acc / fmaxf(fabsf(acc), EPSV);
  }
}

// ---------------------------------------------------------------------------
// K1: fused 1x1 conv (64->128) + 3x3 depthwise (pad=1), writing k (ws) and v
// (d_out). Strip kernel: block owns a 16-col x 64-row interior tile, marches
// rows keeping a 3-row ring of the 1x1 output (18 halo cols) in LDS.
// Thread t: channel o = t/2, column half = t&1 (9 halo cols for 1x1 phase,
// 8 interior cols for depthwise phase). 1x1 weights live in 64 VGPRs.
// Also accumulates per-block sum-of-squares partials for k channels
// (deterministic: no atomics).
__global__ __launch_bounds__(256) void k1_conv(
    const float* __restrict__ x, const float* __restrict__ kv_w,
    const float* __restrict__ kv_b, const float* __restrict__ dw_w,
    const float* __restrict__ dw_b, float* __restrict__ k_out,
    float* __restrict__ v_out, float* __restrict__ ssqpart) {
  const int tid = threadIdx.x;
  const int b = blockIdx.z;
  const int c0 = blockIdx.x << 4;   // interior col start (16 per block)
  const int r0 = blockIdx.y << 6;   // interior row start (64 per block)
  const int o = tid >> 1;           // output channel 0..127
  const int half = tid & 1;
  const int cbase9 = half * 9;      // halo-col base for 1x1 phase

  __shared__ float xrow[18 * 68];        // [halo col][in ch], padded stride 68
  __shared__ float ring[3 * 128 * 21];   // [slot][o][halo col], stride 21
  __shared__ float ssql[256];

  // per-thread weights in registers
  float wr[64];
#pragma unroll
  for (int i = 0; i < 64; i += 4) {
    const float4 w4 = *reinterpret_cast<const float4*>(kv_w + o * 64 + i);
    wr[i] = w4.x; wr[i + 1] = w4.y; wr[i + 2] = w4.z; wr[i + 3] = w4.w;
  }
  float dwr[9];
#pragma unroll
  for (int t = 0; t < 9; ++t) dwr[t] = dw_w[o * 9 + t];
  const float b1r = kv_b[o];
  const float bdr = dw_b[o];
  const bool is_k = (o < 64);
  float* outbase = is_k ? (k_out + (size_t)(b * 64 + o) * HW_)
                        : (v_out + (size_t)(b * 64 + (o - 64)) * HW_);
  float sqacc = 0.f;

  for (int rr = 0; rr <= 65; ++rr) {
    const int gr = r0 - 1 + rr;           // kv1 row being produced
    const int slot = rr % 3;
    const bool rowvalid = (gr >= 0) && (gr < H_);
    // ---- stage x row (18 halo cols x 64 in-ch) ----
    if (rowvalid) {
      const float* xr = x + (size_t)(b * 64) * HW_ + (size_t)gr * W_;
      for (int idx = tid; idx < 1152; idx += 256) {
        const int i = idx / 18, cc = idx % 18;
        const int gc = c0 - 1 + cc;
        xrow[cc * 68 + i] = (gc >= 0 && gc < W_) ? xr[(size_t)i * HW_ + gc] : 0.f;
      }
    }
    __syncthreads();
    // ---- 1x1 conv into ring[slot] ----
    {
      float acc[9];
#pragma unroll
      for (int cc = 0; cc < 9; ++cc) acc[cc] = 0.f;
      if (rowvalid) {
#pragma unroll
        for (int i = 0; i < 64; i += 4) {
          const float w0 = wr[i], w1 = wr[i + 1], w2 = wr[i + 2], w3 = wr[i + 3];
#pragma unroll
          for (int cc = 0; cc < 9; ++cc) {
            const float4 xv =
                *reinterpret_cast<const float4*>(&xrow[(cbase9 + cc) * 68 + i]);
            acc[cc] += xv.x * w0 + xv.y * w1 + xv.z * w2 + xv.w * w3;
          }
        }
      }
      float* rp = &ring[slot * 2688 + o * 21];
#pragma unroll
      for (int cc = 0; cc < 9; ++cc) {
        const int hc = cbase9 + cc;
        const int gc = c0 - 1 + hc;
        rp[hc] = (rowvalid && gc >= 0 && gc < W_) ? (acc[cc] + b1r) : 0.f;
      }
    }
    __syncthreads();
    // ---- depthwise 3x3 for output row gr-1 (interior rows only) ----
    if (rr >= 2) {
      const int orow = gr - 1;  // in [r0, r0+63]
      const float* rp0 = &ring[((rr - 2) % 3) * 2688 + o * 21 + half * 8];
      const float* rp1 = &ring[((rr - 1) % 3) * 2688 + o * 21 + half * 8];
      const float* rp2 = &ring[(rr % 3) * 2688 + o * 21 + half * 8];
      float r0v[10], r1v[10], r2v[10];
#pragma unroll
      for (int t = 0; t < 10; ++t) {
        r0v[t] = rp0[t]; r1v[t] = rp1[t]; r2v[t] = rp2[t];
      }
      float ov[8];
#pragma unroll
      for (int j = 0; j < 8; ++j) {
        ov[j] = bdr + dwr[0] * r0v[j] + dwr[1] * r0v[j + 1] + dwr[2] * r0v[j + 2]
                    + dwr[3] * r1v[j] + dwr[4] * r1v[j + 1] + dwr[5] * r1v[j + 2]
                    + dwr[6] * r2v[j] + dwr[7] * r2v[j + 1] + dwr[8] * r2v[j + 2];
        if (is_k) sqacc += ov[j] * ov[j];
      }
      float* dst = outbase + (size_t)orow * W_ + c0 + half * 8;
      *reinterpret_cast<float4*>(dst) = make_float4(ov[0], ov[1], ov[2], ov[3]);
      *reinterpret_cast<float4*>(dst + 4) = make_float4(ov[4], ov[5], ov[6], ov[7]);
    }
  }
  // ---- per-block k sum-of-squares partials ----
  ssql[tid] = is_k ? sqacc : 0.f;
  __syncthreads();
  if (tid < 64) {
    const int blin = blockIdx.y * 32 + blockIdx.x;  // 0..255 within b
    ssqpart[(size_t)(b * 256 + blin) * 64 + tid] = ssql[2 * tid] + ssql[2 * tid + 1];
  }
}

// ---------------------------------------------------------------------------
// K2: reduce sumsq partials -> rnorm = 1/max(||k||,eps); qn = qsign*rnorm*temps
__global__ __launch_bounds__(256) void k2_finalize(
    const float* __restrict__ ssqpart, const float* __restrict__ temps,
    const float* __restrict__ qsign, float* __restrict__ rnorm,
    float* __restrict__ qn) {
  const int tid = threadIdx.x;
  if (tid < 128) {
    const int b = tid >> 6, c = tid & 63;
    float s = 0.f;
    for (int p = 0; p < 256; ++p) s += ssqpart[(size_t)(b * 256 + p) * 64 + c];
    rnorm[tid] = 1.f / fmaxf(sqrtf(s), EPSV);
  }
  __syncthreads();
  for (int idx = tid; idx < 512; idx += 256) {
    const int b = idx >> 8, n = (idx >> 6) & 3, d = idx & 63;
    qn[idx] = qsign[idx] * rnorm[b * 64 + d] * temps[n * 8 + (d >> 3)];
  }
}

// ---------------------------------------------------------------------------
// K3: softmax denominators. logits are in [-8,8] (|k_norm|<=1, q=+-1) so
// exp without max-subtraction is safe. Deterministic per-block partials.
__global__ __launch_bounds__(256) void k3_denom(
    const float* __restrict__ k_ws, const float* __restrict__ qn,
    float* __restrict__ dpart) {
  const int tile = blockIdx.x, e = blockIdx.y, b = blockIdx.z;
  const int tid = threadIdx.x;
  float q[4][8];
#pragma unroll
  for (int n = 0; n < 4; ++n)
#pragma unroll
    for (int cc = 0; cc < 8; ++cc)
      q[n][cc] = qn[b * 256 + n * 64 + e * 8 + cc];
  const float* kb = k_ws + (size_t)(b * 64 + e * 8) * HW_;
  float dsum[4] = {0.f, 0.f, 0.f, 0.f};
  const int sbase = tile * 8192;
  for (int it = 0; it < 32; ++it) {
    const int s = sbase + it * 256 + tid;
    float kv[8];
#pragma unroll
    for (int cc = 0; cc < 8; ++cc) kv[cc] = kb[(size_t)cc * HW_ + s];
#pragma unroll
    for (int n = 0; n < 4; ++n) {
      float l = 0.f;
#pragma unroll
      for (int cc = 0; cc < 8; ++cc) l += q[n][cc] * kv[cc];
      dsum[n] += __expf(l);
    }
  }
  __shared__ float red[256];
#pragma unroll
  for (int n = 0; n < 4; ++n) {
    red[tid] = dsum[n];
    __syncthreads();
    for (int st = 128; st > 0; st >>= 1) {
      if (tid < st) red[tid] += red[tid + st];
      __syncthreads();
    }
    if (tid == 0) dpart[(b * 32 + n * 8 + e) * 32 + tile] = red[0];
    __syncthreads();
  }
}

// ---------------------------------------------------------------------------
// K4: mid[b,cc,s] = sum_e (sum_n exp(l[n,e,s])/denom[n,e]) * v[b,e,cc,s]
__global__ __launch_bounds__(256) void k4_attend(
    const float* __restrict__ k_ws, const float* __restrict__ v_ws,
    const float* __restrict__ qn, const float* __restrict__ dpart,
    float* __restrict__ mid) {
  const int b = blockIdx.y;
  const int tid = threadIdx.x;
  __shared__ float qnl[256];
  __shared__ float rdl[32];
  qnl[tid] = qn[b * 256 + tid];
  if (tid < 32) {
    float s = 0.f;
    for (int t = 0; t < 32; ++t) s += dpart[(b * 32 + tid) * 32 + t];
    rdl[tid] = 1.f / s;
  }
  __syncthreads();
  const float* kb = k_ws + (size_t)b * 64 * HW_;
  const float* vb = v_ws + (size_t)b * 64 * HW_;
  float* mb = mid + (size_t)b * 8 * HW_;
  for (int it = 0; it < 8; ++it) {
    const int s = (blockIdx.x * 8 + it) * 256 + tid;
    float macc[8] = {0.f, 0.f, 0.f, 0.f, 0.f, 0.f, 0.f, 0.f};
#pragma unroll
    for (int e = 0; e < 8; ++e) {
      float kv[8];
#pragma unroll
      for (int cc = 0; cc < 8; ++cc) kv[cc] = kb[(size_t)(e * 8 + cc) * HW_ + s];
      float wsum = 0.f;
#pragma unroll
      for (int n = 0; n < 4; ++n) {
        float l = 0.f;
#pragma unroll
        for (int cc = 0; cc < 8; ++cc) l += qnl[n * 64 + e * 8 + cc] * kv[cc];
        wsum += __expf(l) * rdl[n * 8 + e];
      }
#pragma unroll
      for (int cc = 0; cc < 8; ++cc)
        macc[cc] += wsum * vb[(size_t)(e * 8 + cc) * HW_ + s];
    }
#pragma unroll
    for (int cc = 0; cc < 8; ++cc) mb[(size_t)cc * HW_ + s] = macc[cc];
  }
}

// ---------------------------------------------------------------------------
// K5: grouped 3x3 (8->64, groups=8) + exact GELU + 1x1 (64->64).
// Block = one row x 256 cols; mid tile (3 rows + col halo) staged in LDS;
// g[64] in registers; cc2 weights transposed in LDS for broadcast reads.
__global__ __launch_bounds__(256) void k5_cross(
    const float* __restrict__ mid, const float* __restrict__ cc1_w,
    const float* __restrict__ cc1_b, const float* __restrict__ cc2_w,
    const float* __restrict__ cc2_b, float* __restrict__ out) {
  const int c0 = blockIdx.x * 256;
  const int row = blockIdx.y;
  const int b = blockIdx.z;
  const int tid = threadIdx.x;
  __shared__ float midl[8 * 3 * 260];
  __shared__ float w2t[4096];  // [oo][p]
  __shared__ float w1l[576];
  __shared__ float b1l[64];
  for (int idx = tid; idx < 8 * 3 * 258; idx += 256) {
    const int ch = idx / (3 * 258);
    const int rem = idx % (3 * 258);
    const int dr = rem / 258, cc = rem % 258;
    const int gr = row - 1 + dr, gc = c0 - 1 + cc;
    float v = 0.f;
    if (gr >= 0 && gr < H_ && gc >= 0 && gc < W_)
      v = mid[(size_t)(b * 8 + ch) * HW_ + (size_t)gr * W_ + gc];
    midl[(ch * 3 + dr) * 260 + cc] = v;
  }
  for (int idx = tid; idx < 4096; idx += 256) {
    const int p = idx >> 6, oo = idx & 63;
    w2t[oo * 64 + p] = cc2_w[idx];
  }
  for (int idx = tid; idx < 576; idx += 256) w1l[idx] = cc1_w[idx];
  if (tid < 64) b1l[tid] = cc1_b[tid];
  __syncthreads();

  float g[64];
#pragma unroll
  for (int ch = 0; ch < 8; ++ch) {
    const float* m0 = &midl[(ch * 3 + 0) * 260 + tid];
    const float* m1 = &midl[(ch * 3 + 1) * 260 + tid];
    const float* m2 = &midl[(ch * 3 + 2) * 260 + tid];
    const float a00 = m0[0], a01 = m0[1], a02 = m0[2];
    const float a10 = m1[0], a11 = m1[1], a12 = m1[2];
    const float a20 = m2[0], a21 = m2[1], a22 = m2[2];
#pragma unroll
    for (int j = 0; j < 8; ++j) {
      const int oo = ch * 8 + j;
      const float* w = &w1l[oo * 9];
      float a = b1l[oo] + w[0] * a00 + w[1] * a01 + w[2] * a02
                        + w[3] * a10 + w[4] * a11 + w[5] * a12
                        + w[6] * a20 + w[7] * a21 + w[8] * a22;
      g[oo] = 0.5f * a * (1.f + erff(a * 0.70710678118654752f));
    }
  }
  const size_t sbase = (size_t)row * W_ + c0 + tid;
#pragma unroll 1
  for (int p0 = 0; p0 < 64; p0 += 16) {
    float y[16];
#pragma unroll
    for (int j = 0; j < 16; ++j) y[j] = cc2_b[p0 + j];
#pragma unroll
    for (int oo = 0; oo < 64; ++oo) {
      const float gv = g[oo];
      const float* wp = &w2t[oo * 64 + p0];
#pragma unroll
      for (int j = 0; j < 16; ++j) y[j] += gv * wp[j];
    }
#pragma unroll
    for (int j = 0; j < 16; ++j)
      out[(size_t)(b * 64 + p0 + j) * HW_ + sbase] = y[j];
  }
}

// ---------------------------------------------------------------------------
extern "C" void kernel_launch(void* const* d_in, const int* in_sizes, int n_in,
                              void* d_out, int out_size, void* d_ws, size_t ws_size,
                              hipStream_t stream) {
  const float* x        = (const float*)d_in[0];
  const float* metainfo = (const float*)d_in[1];
  const float* Wq       = (const float*)d_in[2];
  const float* bq       = (const float*)d_in[3];
  const float* temps    = (const float*)d_in[4];
  const float* kv_w     = (const float*)d_in[5];
  const float* kv_b     = (const float*)d_in[6];
  const float* dw_w     = (const float*)d_in[7];
  const float* dw_b     = (const float*)d_in[8];
  const float* cc1_w    = (const float*)d_in[9];
  const float* cc1_b    = (const float*)d_in[10];
  const float* cc2_w    = (const float*)d_in[11];
  const float* cc2_b    = (const float*)d_in[12];
  float* out = (float*)d_out;

  // workspace layout (floats). v lives in d_out until K5 overwrites it.
  float* ws      = (float*)d_ws;
  float* k_ws    = ws;                    // 2*64*HW        = 33,554,432
  float* mid     = ws + 33554432;         // 2*8*HW         =  4,194,304
  float* small_  = ws + 37748736;
  float* ssqpart = small_;                // 2*256*64       = 32,768
  float* qsign   = small_ + 32768;        // 512
  float* rnorm   = small_ + 33280;        // 128
  float* qn      = small_ + 33408;        // 512
  float* dpart   = small_ + 33920;        // 64*32          = 2,048

  k0_qsign<<<1, 256, 0, stream>>>(metainfo, Wq, bq, qsign);
  k1_conv<<<dim3(32, 8, 2), 256, 0, stream>>>(x, kv_w, kv_b, dw_w, dw_b,
                                              k_ws, out /*v*/, ssqpart);
  k2_finalize<<<1, 256, 0, stream>>>(ssqpart, temps, qsign, rnorm, qn);
  k3_denom<<<dim3(32, 8, 2), 256, 0, stream>>>(k_ws, qn, dpart);
  k4_attend<<<dim3(128, 2), 256, 0, stream>>>(k_ws, out /*v*/, qn, dpart, mid);
  k5_cross<<<dim3(2, 512, 2), 256, 0, stream>>>(mid, cc1_w, cc1_b, cc2_w,
                                                cc2_b, out);
}

// Round 2
// 811.489 us; speedup vs baseline: 1.7319x; 1.7319x over previous
//
#include <hip/hip_runtime.h>
#include <hip/hip_bf16.h>

#define B_    2
#define H_    512
#define W_    512
#define HW_   262144   // 512*512
#define EPSV  1e-12f

typedef __hip_bfloat16 bf16;

// ---------------------------------------------------------------------------
// K0: q = metainfo @ Wq^T + bq, then elementwise sign.
__global__ __launch_bounds__(256) void k0_qsign(
    const float* __restrict__ metainfo, const float* __restrict__ Wq,
    const float* __restrict__ bq, float* __restrict__ qsign) {
  for (int idx = threadIdx.x; idx < 512; idx += 256) {
    const int b = idx >> 8, n = (idx >> 6) & 3, d = idx & 63;
    float acc = bq[n * 64 + d];
#pragma unroll
    for (int m = 0; m < 4; ++m)
      acc += metainfo[(b * 4 + n) * 4 + m] * Wq[(n * 64 + d) * 4 + m];
    qsign[idx] = acc / fmaxf(fabsf(acc), EPSV);
  }
}

// ---------------------------------------------------------------------------
// K1a: 1x1 conv as GEMM. kv1[b][o][s] (bf16) = sum_i W[o][i]*x[b][i][s] + bias
// Block tile: 128 outs x 128 px, K=64 (full). Thread tile 8x8 (64 accs).
// LDS: xs[64][128] fp32 (x tile), wt[64][128] fp32 (W transposed, o-index
// XOR-swizzled by k to avoid 64-way write conflicts).
__global__ __launch_bounds__(256) void k1a_conv1x1(
    const float* __restrict__ x, const float* __restrict__ kv_w,
    const float* __restrict__ kv_b, bf16* __restrict__ kv1) {
  const int tid = threadIdx.x;
  const int p0 = blockIdx.x * 128;     // global pixel in [0, 2*HW)
  const int b  = p0 >> 18;
  const int s0 = p0 & (HW_ - 1);
  __shared__ float xs[64 * 128];
  __shared__ float wt[64 * 128];
  // stage W transposed with swizzle: wt[k][o ^ ((k&15)<<3)] = W[o][k]
  for (int idx = tid; idx < 8192; idx += 256) {
    const int o = idx >> 6, k = idx & 63;
    wt[k * 128 + (o ^ ((k & 15) << 3))] = kv_w[idx];
  }
  // stage x tile (coalesced rows)
  const float* xb = x + (size_t)b * 64 * HW_ + s0;
  for (int idx = tid; idx < 8192; idx += 256) {
    const int i = idx >> 7, px = idx & 127;
    xs[i * 128 + px] = xb[(size_t)i * HW_ + px];
  }
  __syncthreads();
  const int ty = tid >> 4, tx = tid & 15;
  const int ty8 = ty * 8, tx8 = tx * 8;
  float acc[8][8];
#pragma unroll
  for (int j = 0; j < 8; ++j)
#pragma unroll
    for (int p = 0; p < 8; ++p) acc[j][p] = 0.f;
#pragma unroll 8
  for (int k = 0; k < 64; ++k) {
    const int wb = k * 128 + (ty8 ^ ((k & 15) << 3));
    const float4 wv0 = *reinterpret_cast<const float4*>(&wt[wb]);
    const float4 wv1 = *reinterpret_cast<const float4*>(&wt[wb + 4]);
    const float4 xv0 = *reinterpret_cast<const float4*>(&xs[k * 128 + tx8]);
    const float4 xv1 = *reinterpret_cast<const float4*>(&xs[k * 128 + tx8 + 4]);
    const float wr[8] = {wv0.x, wv0.y, wv0.z, wv0.w, wv1.x, wv1.y, wv1.z, wv1.w};
    const float xr[8] = {xv0.x, xv0.y, xv0.z, xv0.w, xv1.x, xv1.y, xv1.z, xv1.w};
#pragma unroll
    for (int j = 0; j < 8; ++j)
#pragma unroll
      for (int p = 0; p < 8; ++p) acc[j][p] += wr[j] * xr[p];
  }
  // epilogue: +bias, convert to bf16, 16B stores
#pragma unroll
  for (int j = 0; j < 8; ++j) {
    const int o = ty8 + j;
    const float bv = kv_b[o];
    union { int4 v; bf16 h[8]; } ou;
#pragma unroll
    for (int p = 0; p < 8; ++p) ou.h[p] = __float2bfloat16(acc[j][p] + bv);
    *reinterpret_cast<int4*>(kv1 + (size_t)(b * 128 + o) * HW_ + s0 + tx8) = ou.v;
  }
}

// ---------------------------------------------------------------------------
// K1b: depthwise 3x3 (pad=1) on bf16 kv1 -> bf16 k||v (in d_out), fp32 math.
// Thread: one (b, ch, 8-col chunk) strip of 32 rows, rolling 3-row registers.
// ssq partials for k channels via wave shuffle (lanes of a wave share ch).
__global__ __launch_bounds__(256) void k1b_dw(
    const bf16* __restrict__ kv1, const float* __restrict__ dw_w,
    const float* __restrict__ dw_b, bf16* __restrict__ kvout,
    float* __restrict__ ssqpart) {
  const int tid = threadIdx.x;
  const int cchunk = tid & 63;            // 64 col-chunks of 8
  const int ch_sub = tid >> 6;            // 4 channels per block
  const int rs = blockIdx.x;              // 16 row strips of 32
  const int chgrp = blockIdx.y;           // 32
  const int b = blockIdx.z;
  const int ch = chgrp * 4 + ch_sub;
  const int c0 = cchunk * 8;
  const int r0 = rs * 32;
  const bf16* src = kv1 + (size_t)(b * 128 + ch) * HW_;
  const bool is_k = (ch < 64);
  const size_t obase = is_k ? (size_t)(b * 64 + ch) * HW_
                            : (size_t)(128 + b * 64 + (ch - 64)) * HW_;
  bf16* dst = kvout + obase;
  float dwr[9];
#pragma unroll
  for (int t = 0; t < 9; ++t) dwr[t] = dw_w[ch * 9 + t];
  const float bd = dw_b[ch];

  float a0[10], a1[10], a2[10];
  auto loadrow = [&](int gr, float* a) {
    if (gr < 0 || gr >= H_) {
#pragma unroll
      for (int t = 0; t < 10; ++t) a[t] = 0.f;
      return;
    }
    const bf16* rp = src + (size_t)gr * W_ + c0;
    union { int4 v; bf16 h[8]; } raw;
    raw.v = *reinterpret_cast<const int4*>(rp);
#pragma unroll
    for (int t = 0; t < 8; ++t) a[t + 1] = __bfloat162float(raw.h[t]);
    a[0] = (c0 > 0) ? __bfloat162float(rp[-1]) : 0.f;
    a[9] = (c0 < 504) ? __bfloat162float(rp[8]) : 0.f;
  };
  loadrow(r0 - 1, a0);
  loadrow(r0, a1);
  float sq = 0.f;
#pragma unroll 4
  for (int rr = 0; rr < 32; ++rr) {
    loadrow(r0 + rr + 1, a2);
    union { int4 v; bf16 h[8]; } ou;
#pragma unroll
    for (int j = 0; j < 8; ++j) {
      const float ov = bd
          + dwr[0] * a0[j] + dwr[1] * a0[j + 1] + dwr[2] * a0[j + 2]
          + dwr[3] * a1[j] + dwr[4] * a1[j + 1] + dwr[5] * a1[j + 2]
          + dwr[6] * a2[j] + dwr[7] * a2[j + 1] + dwr[8] * a2[j + 2];
      sq += ov * ov;
      ou.h[j] = __float2bfloat16(ov);
    }
    *reinterpret_cast<int4*>(dst + (size_t)(r0 + rr) * W_ + c0) = ou.v;
#pragma unroll
    for (int t = 0; t < 10; ++t) { a0[t] = a1[t]; a1[t] = a2[t]; }
  }
  // wave reduction of sq over the 64 col-chunk lanes (same ch per wave)
#pragma unroll
  for (int off = 32; off > 0; off >>= 1) sq += __shfl_down(sq, off, 64);
  if (is_k && cchunk == 0)
    ssqpart[(size_t)(b * 64 + ch) * 16 + rs] = sq;
}

// ---------------------------------------------------------------------------
// K2: reduce sumsq partials -> rnorm; qn = qsign*rnorm*temps
__global__ __launch_bounds__(256) void k2_finalize(
    const float* __restrict__ ssqpart, const float* __restrict__ temps,
    const float* __restrict__ qsign, float* __restrict__ rnorm,
    float* __restrict__ qn) {
  const int tid = threadIdx.x;
  if (tid < 128) {
    const int b = tid >> 6, c = tid & 63;
    float s = 0.f;
    for (int p = 0; p < 16; ++p) s += ssqpart[(size_t)(b * 64 + c) * 16 + p];
    rnorm[tid] = 1.f / fmaxf(sqrtf(s), EPSV);
  }
  __syncthreads();
  for (int idx = tid; idx < 512; idx += 256) {
    const int b = idx >> 8, n = (idx >> 6) & 3, d = idx & 63;
    qn[idx] = qsign[idx] * rnorm[b * 64 + d] * temps[n * 8 + (d >> 3)];
  }
}

// ---------------------------------------------------------------------------
// K3: softmax denominators from bf16 k. logits tiny -> exp w/o max-sub safe.
__global__ __launch_bounds__(256) void k3_denom(
    const bf16* __restrict__ kbuf, const float* __restrict__ qn,
    float* __restrict__ dpart) {
  const int tile = blockIdx.x, e = blockIdx.y, b = blockIdx.z;
  const int tid = threadIdx.x;
  float q[4][8];
#pragma unroll
  for (int n = 0; n < 4; ++n)
#pragma unroll
    for (int cc = 0; cc < 8; ++cc)
      q[n][cc] = qn[b * 256 + n * 64 + e * 8 + cc];
  const bf16* kb = kbuf + (size_t)(b * 64 + e * 8) * HW_;
  float dsum[4] = {0.f, 0.f, 0.f, 0.f};
  const int sbase = tile * 8192;
  for (int it = 0; it < 32; ++it) {
    const int s = sbase + it * 256 + tid;
    float kv[8];
#pragma unroll
    for (int cc = 0; cc < 8; ++cc)
      kv[cc] = __bfloat162float(kb[(size_t)cc * HW_ + s]);
#pragma unroll
    for (int n = 0; n < 4; ++n) {
      float l = 0.f;
#pragma unroll
      for (int cc = 0; cc < 8; ++cc) l += q[n][cc] * kv[cc];
      dsum[n] += __expf(l);
    }
  }
  __shared__ float red[256];
#pragma unroll
  for (int n = 0; n < 4; ++n) {
    red[tid] = dsum[n];
    __syncthreads();
    for (int st = 128; st > 0; st >>= 1) {
      if (tid < st) red[tid] += red[tid + st];
      __syncthreads();
    }
    if (tid == 0) dpart[(b * 32 + n * 8 + e) * 32 + tile] = red[0];
    __syncthreads();
  }
}

// ---------------------------------------------------------------------------
// K4: mid[b,cc,s] = sum_e (sum_n exp(l)/denom) * v[b,e,cc,s]  (bf16 k,v)
__global__ __launch_bounds__(256) void k4_attend(
    const bf16* __restrict__ kvbuf, const float* __restrict__ qn,
    const float* __restrict__ dpart, float* __restrict__ mid) {
  const int b = blockIdx.y;
  const int tid = threadIdx.x;
  __shared__ float qnl[256];
  __shared__ float rdl[32];
  qnl[tid] = qn[b * 256 + tid];
  if (tid < 32) {
    float s = 0.f;
    for (int t = 0; t < 32; ++t) s += dpart[(b * 32 + tid) * 32 + t];
    rdl[tid] = 1.f / s;
  }
  __syncthreads();
  const bf16* kb = kvbuf + (size_t)(b * 64) * HW_;
  const bf16* vb = kvbuf + (size_t)(128 + b * 64) * HW_;
  float* mb = mid + (size_t)b * 8 * HW_;
  for (int it = 0; it < 2; ++it) {
    const int s = (blockIdx.x * 2 + it) * 256 + tid;
    float macc[8] = {0.f, 0.f, 0.f, 0.f, 0.f, 0.f, 0.f, 0.f};
#pragma unroll
    for (int e = 0; e < 8; ++e) {
      float kv[8];
#pragma unroll
      for (int cc = 0; cc < 8; ++cc)
        kv[cc] = __bfloat162float(kb[(size_t)(e * 8 + cc) * HW_ + s]);
      float wsum = 0.f;
#pragma unroll
      for (int n = 0; n < 4; ++n) {
        float l = 0.f;
#pragma unroll
        for (int cc = 0; cc < 8; ++cc) l += qnl[n * 64 + e * 8 + cc] * kv[cc];
        wsum += __expf(l) * rdl[n * 8 + e];
      }
#pragma unroll
      for (int cc = 0; cc < 8; ++cc)
        macc[cc] += wsum * __bfloat162float(vb[(size_t)(e * 8 + cc) * HW_ + s]);
    }
#pragma unroll
    for (int cc = 0; cc < 8; ++cc) mb[(size_t)cc * HW_ + s] = macc[cc];
  }
}

// ---------------------------------------------------------------------------
// K5: grouped 3x3 (8->64, groups=8) + exact GELU + 1x1 (64->64).
__global__ __launch_bounds__(256) void k5_cross(
    const float* __restrict__ mid, const float* __restrict__ cc1_w,
    const float* __restrict__ cc1_b, const float* __restrict__ cc2_w,
    const float* __restrict__ cc2_b, float* __restrict__ out) {
  const int c0 = blockIdx.x * 256;
  const int row = blockIdx.y;
  const int b = blockIdx.z;
  const int tid = threadIdx.x;
  __shared__ float midl[8 * 3 * 260];
  __shared__ float w2t[4096];  // [oo][p]
  __shared__ float w1l[576];
  __shared__ float b1l[64];
  for (int idx = tid; idx < 8 * 3 * 258; idx += 256) {
    const int ch = idx / (3 * 258);
    const int rem = idx % (3 * 258);
    const int dr = rem / 258, cc = rem % 258;
    const int gr = row - 1 + dr, gc = c0 - 1 + cc;
    float v = 0.f;
    if (gr >= 0 && gr < H_ && gc >= 0 && gc < W_)
      v = mid[(size_t)(b * 8 + ch) * HW_ + (size_t)gr * W_ + gc];
    midl[(ch * 3 + dr) * 260 + cc] = v;
  }
  for (int idx = tid; idx < 4096; idx += 256) {
    const int p = idx >> 6, oo = idx & 63;
    w2t[oo * 64 + p] = cc2_w[idx];
  }
  for (int idx = tid; idx < 576; idx += 256) w1l[idx] = cc1_w[idx];
  if (tid < 64) b1l[tid] = cc1_b[tid];
  __syncthreads();

  float g[64];
#pragma unroll
  for (int ch = 0; ch < 8; ++ch) {
    const float* m0 = &midl[(ch * 3 + 0) * 260 + tid];
    const float* m1 = &midl[(ch * 3 + 1) * 260 + tid];
    const float* m2 = &midl[(ch * 3 + 2) * 260 + tid];
    const float a00 = m0[0], a01 = m0[1], a02 = m0[2];
    const float a10 = m1[0], a11 = m1[1], a12 = m1[2];
    const float a20 = m2[0], a21 = m2[1], a22 = m2[2];
#pragma unroll
    for (int j = 0; j < 8; ++j) {
      const int oo = ch * 8 + j;
      const float* w = &w1l[oo * 9];
      float a = b1l[oo] + w[0] * a00 + w[1] * a01 + w[2] * a02
                        + w[3] * a10 + w[4] * a11 + w[5] * a12
                        + w[6] * a20 + w[7] * a21 + w[8] * a22;
      g[oo] = 0.5f * a * (1.f + erff(a * 0.70710678118654752f));
    }
  }
  const size_t sbase = (size_t)row * W_ + c0 + tid;
#pragma unroll 1
  for (int p0 = 0; p0 < 64; p0 += 16) {
    float y[16];
#pragma unroll
    for (int j = 0; j < 16; ++j) y[j] = cc2_b[p0 + j];
#pragma unroll
    for (int oo = 0; oo < 64; ++oo) {
      const float gv = g[oo];
      const float* wp = &w2t[oo * 64 + p0];
#pragma unroll
      for (int j = 0; j < 16; ++j) y[j] += gv * wp[j];
    }
#pragma unroll
    for (int j = 0; j < 16; ++j)
      out[(size_t)(b * 64 + p0 + j) * HW_ + sbase] = y[j];
  }
}

// ---------------------------------------------------------------------------
extern "C" void kernel_launch(void* const* d_in, const int* in_sizes, int n_in,
                              void* d_out, int out_size, void* d_ws, size_t ws_size,
                              hipStream_t stream) {
  const float* x        = (const float*)d_in[0];
  const float* metainfo = (const float*)d_in[1];
  const float* Wq       = (const float*)d_in[2];
  const float* bq       = (const float*)d_in[3];
  const float* temps    = (const float*)d_in[4];
  const float* kv_w     = (const float*)d_in[5];
  const float* kv_b     = (const float*)d_in[6];
  const float* dw_w     = (const float*)d_in[7];
  const float* dw_b     = (const float*)d_in[8];
  const float* cc1_w    = (const float*)d_in[9];
  const float* cc1_b    = (const float*)d_in[10];
  const float* cc2_w    = (const float*)d_in[11];
  const float* cc2_b    = (const float*)d_in[12];
  float* out = (float*)d_out;

  // ws layout (float offsets): kv1 bf16 occupies [0, 33554432) float-equiv.
  float* ws      = (float*)d_ws;
  bf16*  kv1     = (bf16*)d_ws;           // 2*128*HW bf16 = 134.2 MB
  float* mid     = ws + 33554432;         // 2*8*HW fp32   = 16.8 MB
  float* small_  = ws + 37748736;
  float* ssqpart = small_;                // 2*64*16 = 2048
  float* qsign   = small_ + 2048;         // 512
  float* rnorm   = small_ + 2560;         // 128
  float* qn      = small_ + 2688;         // 512
  float* dpart   = small_ + 3200;         // 64*32 = 2048

  // k (bf16) and v (bf16) live in d_out until K5 overwrites it with fp32 out.
  bf16* kvout = (bf16*)d_out;             // [k: 2*64*HW][v: 2*64*HW] bf16

  k0_qsign<<<1, 256, 0, stream>>>(metainfo, Wq, bq, qsign);
  k1a_conv1x1<<<4096, 256, 0, stream>>>(x, kv_w, kv_b, kv1);
  k1b_dw<<<dim3(16, 32, 2), 256, 0, stream>>>(kv1, dw_w, dw_b, kvout, ssqpart);
  k2_finalize<<<1, 256, 0, stream>>>(ssqpart, temps, qsign, rnorm, qn);
  k3_denom<<<dim3(32, 8, 2), 256, 0, stream>>>(kvout, qn, dpart);
  k4_attend<<<dim3(512, 2), 256, 0, stream>>>(kvout, qn, dpart, mid);
  k5_cross<<<dim3(2, 512, 2), 256, 0, stream>>>(mid, cc1_w, cc1_b, cc2_w,
                                                cc2_b, out);
}

// Round 3
// 576.843 us; speedup vs baseline: 2.4363x; 1.4068x over previous
//
#include <hip/hip_runtime.h>
#include <hip/hip_bf16.h>

#define B_    2
#define H_    512
#define W_    512
#define HW_   262144   // 512*512
#define EPSV  1e-12f

typedef __hip_bfloat16 bf16;

// ---------------------------------------------------------------------------
// K0: q = metainfo @ Wq^T + bq, then elementwise sign.
__global__ __launch_bounds__(256) void k0_qsign(
    const float* __restrict__ metainfo, const float* __restrict__ Wq,
    const float* __restrict__ bq, float* __restrict__ qsign) {
  for (int idx = threadIdx.x; idx < 512; idx += 256) {
    const int b = idx >> 8, n = (idx >> 6) & 3, d = idx & 63;
    float acc = bq[n * 64 + d];
#pragma unroll
    for (int m = 0; m < 4; ++m)
      acc += metainfo[(b * 4 + n) * 4 + m] * Wq[(n * 64 + d) * 4 + m];
    qsign[idx] = acc / fmaxf(fabsf(acc), EPSV);
  }
}

// ---------------------------------------------------------------------------
// K1a: 1x1 conv as GEMM. kv1[b][o][s] (bf16) = sum_i W[o][i]*x[b][i][s] + bias
// Block tile: 128 outs x 128 px, K=64 (full). Thread tile 8x8 (64 accs).
__global__ __launch_bounds__(256) void k1a_conv1x1(
    const float* __restrict__ x, const float* __restrict__ kv_w,
    const float* __restrict__ kv_b, bf16* __restrict__ kv1) {
  const int tid = threadIdx.x;
  const int p0 = blockIdx.x * 128;     // global pixel in [0, 2*HW)
  const int b  = p0 >> 18;
  const int s0 = p0 & (HW_ - 1);
  __shared__ float xs[64 * 128];
  __shared__ float wt[64 * 128];
  // stage W transposed with swizzle: wt[k][o ^ ((k&15)<<3)] = W[o][k]
  for (int idx = tid; idx < 8192; idx += 256) {
    const int o = idx >> 6, k = idx & 63;
    wt[k * 128 + (o ^ ((k & 15) << 3))] = kv_w[idx];
  }
  // stage x tile (coalesced rows)
  const float* xb = x + (size_t)b * 64 * HW_ + s0;
  for (int idx = tid; idx < 8192; idx += 256) {
    const int i = idx >> 7, px = idx & 127;
    xs[i * 128 + px] = xb[(size_t)i * HW_ + px];
  }
  __syncthreads();
  const int ty = tid >> 4, tx = tid & 15;
  const int ty8 = ty * 8, tx8 = tx * 8;
  float acc[8][8];
#pragma unroll
  for (int j = 0; j < 8; ++j)
#pragma unroll
    for (int p = 0; p < 8; ++p) acc[j][p] = 0.f;
#pragma unroll 8
  for (int k = 0; k < 64; ++k) {
    const int wb = k * 128 + (ty8 ^ ((k & 15) << 3));
    const float4 wv0 = *reinterpret_cast<const float4*>(&wt[wb]);
    const float4 wv1 = *reinterpret_cast<const float4*>(&wt[wb + 4]);
    const float4 xv0 = *reinterpret_cast<const float4*>(&xs[k * 128 + tx8]);
    const float4 xv1 = *reinterpret_cast<const float4*>(&xs[k * 128 + tx8 + 4]);
    const float wr[8] = {wv0.x, wv0.y, wv0.z, wv0.w, wv1.x, wv1.y, wv1.z, wv1.w};
    const float xr[8] = {xv0.x, xv0.y, xv0.z, xv0.w, xv1.x, xv1.y, xv1.z, xv1.w};
#pragma unroll
    for (int j = 0; j < 8; ++j)
#pragma unroll
      for (int p = 0; p < 8; ++p) acc[j][p] += wr[j] * xr[p];
  }
  // epilogue: +bias, convert to bf16, 16B stores
#pragma unroll
  for (int j = 0; j < 8; ++j) {
    const int o = ty8 + j;
    const float bv = kv_b[o];
    union { int4 v; bf16 h[8]; } ou;
#pragma unroll
    for (int p = 0; p < 8; ++p) ou.h[p] = __float2bfloat16(acc[j][p] + bv);
    *reinterpret_cast<int4*>(kv1 + (size_t)(b * 128 + o) * HW_ + s0 + tx8) = ou.v;
  }
}

// ---------------------------------------------------------------------------
// K1b: depthwise 3x3 (pad=1) on bf16 kv1 -> bf16 k||v (in d_out), fp32 math.
__global__ __launch_bounds__(256) void k1b_dw(
    const bf16* __restrict__ kv1, const float* __restrict__ dw_w,
    const float* __restrict__ dw_b, bf16* __restrict__ kvout,
    float* __restrict__ ssqpart) {
  const int tid = threadIdx.x;
  const int cchunk = tid & 63;            // 64 col-chunks of 8
  const int ch_sub = tid >> 6;            // 4 channels per block
  const int rs = blockIdx.x;              // 16 row strips of 32
  const int chgrp = blockIdx.y;           // 32
  const int b = blockIdx.z;
  const int ch = chgrp * 4 + ch_sub;
  const int c0 = cchunk * 8;
  const int r0 = rs * 32;
  const bf16* src = kv1 + (size_t)(b * 128 + ch) * HW_;
  const bool is_k = (ch < 64);
  const size_t obase = is_k ? (size_t)(b * 64 + ch) * HW_
                            : (size_t)(128 + b * 64 + (ch - 64)) * HW_;
  bf16* dst = kvout + obase;
  float dwr[9];
#pragma unroll
  for (int t = 0; t < 9; ++t) dwr[t] = dw_w[ch * 9 + t];
  const float bd = dw_b[ch];

  float a0[10], a1[10], a2[10];
  auto loadrow = [&](int gr, float* a) {
    if (gr < 0 || gr >= H_) {
#pragma unroll
      for (int t = 0; t < 10; ++t) a[t] = 0.f;
      return;
    }
    const bf16* rp = src + (size_t)gr * W_ + c0;
    union { int4 v; bf16 h[8]; } raw;
    raw.v = *reinterpret_cast<const int4*>(rp);
#pragma unroll
    for (int t = 0; t < 8; ++t) a[t + 1] = __bfloat162float(raw.h[t]);
    a[0] = (c0 > 0) ? __bfloat162float(rp[-1]) : 0.f;
    a[9] = (c0 < 504) ? __bfloat162float(rp[8]) : 0.f;
  };
  loadrow(r0 - 1, a0);
  loadrow(r0, a1);
  float sq = 0.f;
#pragma unroll 4
  for (int rr = 0; rr < 32; ++rr) {
    loadrow(r0 + rr + 1, a2);
    union { int4 v; bf16 h[8]; } ou;
#pragma unroll
    for (int j = 0; j < 8; ++j) {
      const float ov = bd
          + dwr[0] * a0[j] + dwr[1] * a0[j + 1] + dwr[2] * a0[j + 2]
          + dwr[3] * a1[j] + dwr[4] * a1[j + 1] + dwr[5] * a1[j + 2]
          + dwr[6] * a2[j] + dwr[7] * a2[j + 1] + dwr[8] * a2[j + 2];
      sq += ov * ov;
      ou.h[j] = __float2bfloat16(ov);
    }
    *reinterpret_cast<int4*>(dst + (size_t)(r0 + rr) * W_ + c0) = ou.v;
#pragma unroll
    for (int t = 0; t < 10; ++t) { a0[t] = a1[t]; a1[t] = a2[t]; }
  }
  // wave reduction of sq over the 64 col-chunk lanes (same ch per wave)
#pragma unroll
  for (int off = 32; off > 0; off >>= 1) sq += __shfl_down(sq, off, 64);
  if (is_k && cchunk == 0)
    ssqpart[(size_t)(b * 64 + ch) * 16 + rs] = sq;
}

// ---------------------------------------------------------------------------
// K2: reduce sumsq partials -> rnorm; qn = qsign*rnorm*temps
__global__ __launch_bounds__(256) void k2_finalize(
    const float* __restrict__ ssqpart, const float* __restrict__ temps,
    const float* __restrict__ qsign, float* __restrict__ rnorm,
    float* __restrict__ qn) {
  const int tid = threadIdx.x;
  if (tid < 128) {
    const int b = tid >> 6, c = tid & 63;
    float s = 0.f;
    for (int p = 0; p < 16; ++p) s += ssqpart[(size_t)(b * 64 + c) * 16 + p];
    rnorm[tid] = 1.f / fmaxf(sqrtf(s), EPSV);
  }
  __syncthreads();
  for (int idx = tid; idx < 512; idx += 256) {
    const int b = idx >> 8, n = (idx >> 6) & 3, d = idx & 63;
    qn[idx] = qsign[idx] * rnorm[b * 64 + d] * temps[n * 8 + (d >> 3)];
  }
}

// ---------------------------------------------------------------------------
// K3: softmax denominators from bf16 k. 8 px/thread, 16B k loads.
// grid (64 tiles, 8 e, 2 b); dpart[(b*32+n*8+e)*64 + tile].
__global__ __launch_bounds__(256) void k3_denom(
    const bf16* __restrict__ kbuf, const float* __restrict__ qn,
    float* __restrict__ dpart) {
  const int tile = blockIdx.x, e = blockIdx.y, b = blockIdx.z;
  const int tid = threadIdx.x;
  float q[4][8];
#pragma unroll
  for (int n = 0; n < 4; ++n)
#pragma unroll
    for (int cc = 0; cc < 8; ++cc)
      q[n][cc] = qn[b * 256 + n * 64 + e * 8 + cc];
  const bf16* kb = kbuf + (size_t)(b * 64 + e * 8) * HW_;
  float dsum[4] = {0.f, 0.f, 0.f, 0.f};
  const int sbase = tile * 4096;
#pragma unroll
  for (int it = 0; it < 2; ++it) {
    const int s = sbase + (it * 256 + tid) * 8;
    float kf[8][8];
#pragma unroll
    for (int cc = 0; cc < 8; ++cc) {
      union { int4 v; bf16 h[8]; } r;
      r.v = *reinterpret_cast<const int4*>(kb + (size_t)cc * HW_ + s);
#pragma unroll
      for (int j = 0; j < 8; ++j) kf[cc][j] = __bfloat162float(r.h[j]);
    }
#pragma unroll
    for (int n = 0; n < 4; ++n) {
#pragma unroll
      for (int px = 0; px < 8; ++px) {
        float l = 0.f;
#pragma unroll
        for (int cc = 0; cc < 8; ++cc) l += q[n][cc] * kf[cc][px];
        dsum[n] += __expf(l);
      }
    }
  }
  __shared__ float red[256];
#pragma unroll
  for (int n = 0; n < 4; ++n) {
    red[tid] = dsum[n];
    __syncthreads();
    for (int st = 128; st > 0; st >>= 1) {
      if (tid < st) red[tid] += red[tid + st];
      __syncthreads();
    }
    if (tid == 0) dpart[(b * 32 + n * 8 + e) * 64 + tile] = red[0];
    __syncthreads();
  }
}

// ---------------------------------------------------------------------------
// K4: mid[b,cc,s] = sum_e (sum_n exp(l)/denom) * v[b,e,cc,s]  (bf16 k,v)
// 4 px/thread, 8B ushort4 loads, grid (256, 2).
__global__ __launch_bounds__(256) void k4_attend(
    const bf16* __restrict__ kvbuf, const float* __restrict__ qn,
    const float* __restrict__ dpart, float* __restrict__ mid) {
  const int b = blockIdx.y;
  const int tid = threadIdx.x;
  __shared__ float qnl[256];
  __shared__ float rdl[32];
  qnl[tid] = qn[b * 256 + tid];
  if (tid < 32) {
    float s = 0.f;
    for (int t = 0; t < 64; ++t) s += dpart[(b * 32 + tid) * 64 + t];
    rdl[tid] = 1.f / s;
  }
  __syncthreads();
  const bf16* kb = kvbuf + (size_t)(b * 64) * HW_;
  const bf16* vb = kvbuf + (size_t)(128 + b * 64) * HW_;
  float* mb = mid + (size_t)b * 8 * HW_;
  const int s = (blockIdx.x * 256 + tid) * 4;
  float macc[8][4];
#pragma unroll
  for (int cc = 0; cc < 8; ++cc)
#pragma unroll
    for (int px = 0; px < 4; ++px) macc[cc][px] = 0.f;
#pragma unroll
  for (int e = 0; e < 8; ++e) {
    float kf[8][4];
#pragma unroll
    for (int cc = 0; cc < 8; ++cc) {
      union { ushort4 v; bf16 h[4]; } r;
      r.v = *reinterpret_cast<const ushort4*>(kb + (size_t)(e * 8 + cc) * HW_ + s);
#pragma unroll
      for (int px = 0; px < 4; ++px) kf[cc][px] = __bfloat162float(r.h[px]);
    }
    float wsum[4] = {0.f, 0.f, 0.f, 0.f};
#pragma unroll
    for (int n = 0; n < 4; ++n) {
      const float rd = rdl[n * 8 + e];
#pragma unroll
      for (int px = 0; px < 4; ++px) {
        float l = 0.f;
#pragma unroll
        for (int cc = 0; cc < 8; ++cc) l += qnl[n * 64 + e * 8 + cc] * kf[cc][px];
        wsum[px] += __expf(l) * rd;
      }
    }
#pragma unroll
    for (int cc = 0; cc < 8; ++cc) {
      union { ushort4 v; bf16 h[4]; } r;
      r.v = *reinterpret_cast<const ushort4*>(vb + (size_t)(e * 8 + cc) * HW_ + s);
#pragma unroll
      for (int px = 0; px < 4; ++px)
        macc[cc][px] += wsum[px] * __bfloat162float(r.h[px]);
    }
  }
#pragma unroll
  for (int cc = 0; cc < 8; ++cc)
    *reinterpret_cast<float4*>(mb + (size_t)cc * HW_ + s) =
        make_float4(macc[cc][0], macc[cc][1], macc[cc][2], macc[cc][3]);
}

// ---------------------------------------------------------------------------
// K5: grouped 3x3 (8->64, groups=8) + exact GELU + 1x1 (64->64).
__global__ __launch_bounds__(256) void k5_cross(
    const float* __restrict__ mid, const float* __restrict__ cc1_w,
    const float* __restrict__ cc1_b, const float* __restrict__ cc2_w,
    const float* __restrict__ cc2_b, float* __restrict__ out) {
  const int c0 = blockIdx.x * 256;
  const int row = blockIdx.y;
  const int b = blockIdx.z;
  const int tid = threadIdx.x;
  __shared__ float midl[8 * 3 * 260];
  __shared__ float w2t[4096];  // [oo][p]
  __shared__ float w1l[576];
  __shared__ float b1l[64];
  for (int idx = tid; idx < 8 * 3 * 258; idx += 256) {
    const int ch = idx / (3 * 258);
    const int rem = idx % (3 * 258);
    const int dr = rem / 258, cc = rem % 258;
    const int gr = row - 1 + dr, gc = c0 - 1 + cc;
    float v = 0.f;
    if (gr >= 0 && gr < H_ && gc >= 0 && gc < W_)
      v = mid[(size_t)(b * 8 + ch) * HW_ + (size_t)gr * W_ + gc];
    midl[(ch * 3 + dr) * 260 + cc] = v;
  }
  for (int idx = tid; idx < 4096; idx += 256) {
    const int p = idx >> 6, oo = idx & 63;
    w2t[oo * 64 + p] = cc2_w[idx];
  }
  for (int idx = tid; idx < 576; idx += 256) w1l[idx] = cc1_w[idx];
  if (tid < 64) b1l[tid] = cc1_b[tid];
  __syncthreads();

  float g[64];
#pragma unroll
  for (int ch = 0; ch < 8; ++ch) {
    const float* m0 = &midl[(ch * 3 + 0) * 260 + tid];
    const float* m1 = &midl[(ch * 3 + 1) * 260 + tid];
    const float* m2 = &midl[(ch * 3 + 2) * 260 + tid];
    const float a00 = m0[0], a01 = m0[1], a02 = m0[2];
    const float a10 = m1[0], a11 = m1[1], a12 = m1[2];
    const float a20 = m2[0], a21 = m2[1], a22 = m2[2];
#pragma unroll
    for (int j = 0; j < 8; ++j) {
      const int oo = ch * 8 + j;
      const float* w = &w1l[oo * 9];
      float a = b1l[oo] + w[0] * a00 + w[1] * a01 + w[2] * a02
                        + w[3] * a10 + w[4] * a11 + w[5] * a12
                        + w[6] * a20 + w[7] * a21 + w[8] * a22;
      g[oo] = 0.5f * a * (1.f + erff(a * 0.70710678118654752f));
    }
  }
  const size_t sbase = (size_t)row * W_ + c0 + tid;
#pragma unroll 1
  for (int p0 = 0; p0 < 64; p0 += 16) {
    float y[16];
#pragma unroll
    for (int j = 0; j < 16; ++j) y[j] = cc2_b[p0 + j];
#pragma unroll
    for (int oo = 0; oo < 64; ++oo) {
      const float gv = g[oo];
      const float* wp = &w2t[oo * 64 + p0];
#pragma unroll
      for (int j = 0; j < 16; ++j) y[j] += gv * wp[j];
    }
#pragma unroll
    for (int j = 0; j < 16; ++j)
      out[(size_t)(b * 64 + p0 + j) * HW_ + sbase] = y[j];
  }
}

// ---------------------------------------------------------------------------
extern "C" void kernel_launch(void* const* d_in, const int* in_sizes, int n_in,
                              void* d_out, int out_size, void* d_ws, size_t ws_size,
                              hipStream_t stream) {
  const float* x        = (const float*)d_in[0];
  const float* metainfo = (const float*)d_in[1];
  const float* Wq       = (const float*)d_in[2];
  const float* bq       = (const float*)d_in[3];
  const float* temps    = (const float*)d_in[4];
  const float* kv_w     = (const float*)d_in[5];
  const float* kv_b     = (const float*)d_in[6];
  const float* dw_w     = (const float*)d_in[7];
  const float* dw_b     = (const float*)d_in[8];
  const float* cc1_w    = (const float*)d_in[9];
  const float* cc1_b    = (const float*)d_in[10];
  const float* cc2_w    = (const float*)d_in[11];
  const float* cc2_b    = (const float*)d_in[12];
  float* out = (float*)d_out;

  // ws layout (float offsets): kv1 bf16 occupies [0, 33554432) float-equiv.
  float* ws      = (float*)d_ws;
  bf16*  kv1     = (bf16*)d_ws;           // 2*128*HW bf16 = 134.2 MB
  float* mid     = ws + 33554432;         // 2*8*HW fp32   = 16.8 MB
  float* small_  = ws + 37748736;
  float* ssqpart = small_;                // 2*64*16 = 2048
  float* qsign   = small_ + 2048;         // 512
  float* rnorm   = small_ + 2560;         // 128
  float* qn      = small_ + 2688;         // 512
  float* dpart   = small_ + 3200;         // 64*64 = 4096

  // k (bf16) and v (bf16) live in d_out until K5 overwrites it with fp32 out.
  bf16* kvout = (bf16*)d_out;             // [k: 2*64*HW][v: 2*64*HW] bf16

  k0_qsign<<<1, 256, 0, stream>>>(metainfo, Wq, bq, qsign);
  k1a_conv1x1<<<4096, 256, 0, stream>>>(x, kv_w, kv_b, kv1);
  k1b_dw<<<dim3(16, 32, 2), 256, 0, stream>>>(kv1, dw_w, dw_b, kvout, ssqpart);
  k2_finalize<<<1, 256, 0, stream>>>(ssqpart, temps, qsign, rnorm, qn);
  k3_denom<<<dim3(64, 8, 2), 256, 0, stream>>>(kvout, qn, dpart);
  k4_attend<<<dim3(256, 2), 256, 0, stream>>>(kvout, qn, dpart, mid);
  k5_cross<<<dim3(2, 512, 2), 256, 0, stream>>>(mid, cc1_w, cc1_b, cc2_w,
                                                cc2_b, out);
}

// Round 4
// 453.214 us; speedup vs baseline: 3.1009x; 1.2728x over previous
//
#include <hip/hip_runtime.h>
#include <hip/hip_bf16.h>

#define B_    2
#define H_    512
#define W_    512
#define HW_   262144   // 512*512
#define EPSV  1e-12f

typedef __hip_bfloat16 bf16;

// ---------------------------------------------------------------------------
// K0: q = metainfo @ Wq^T + bq, then elementwise sign.
__global__ __launch_bounds__(256) void k0_qsign(
    const float* __restrict__ metainfo, const float* __restrict__ Wq,
    const float* __restrict__ bq, float* __restrict__ qsign) {
  for (int idx = threadIdx.x; idx < 512; idx += 256) {
    const int b = idx >> 8, n = (idx >> 6) & 3, d = idx & 63;
    float acc = bq[n * 64 + d];
#pragma unroll
    for (int m = 0; m < 4; ++m)
      acc += metainfo[(b * 4 + n) * 4 + m] * Wq[(n * 64 + d) * 4 + m];
    qsign[idx] = acc / fmaxf(fabsf(acc), EPSV);
  }
}

// ---------------------------------------------------------------------------
// K1a: 1x1 conv as GEMM. kv1[b][o][s] (bf16) = sum_i W[o][i]*x[b][i][s] + bias
__global__ __launch_bounds__(256) void k1a_conv1x1(
    const float* __restrict__ x, const float* __restrict__ kv_w,
    const float* __restrict__ kv_b, bf16* __restrict__ kv1) {
  const int tid = threadIdx.x;
  const int p0 = blockIdx.x * 128;     // global pixel in [0, 2*HW)
  const int b  = p0 >> 18;
  const int s0 = p0 & (HW_ - 1);
  __shared__ float xs[64 * 128];
  __shared__ float wt[64 * 128];
  // stage W transposed with swizzle: wt[k][o ^ ((k&15)<<3)] = W[o][k]
  for (int idx = tid; idx < 8192; idx += 256) {
    const int o = idx >> 6, k = idx & 63;
    wt[k * 128 + (o ^ ((k & 15) << 3))] = kv_w[idx];
  }
  // stage x tile (coalesced rows)
  const float* xb = x + (size_t)b * 64 * HW_ + s0;
  for (int idx = tid; idx < 8192; idx += 256) {
    const int i = idx >> 7, px = idx & 127;
    xs[i * 128 + px] = xb[(size_t)i * HW_ + px];
  }
  __syncthreads();
  const int ty = tid >> 4, tx = tid & 15;
  const int ty8 = ty * 8, tx8 = tx * 8;
  float acc[8][8];
#pragma unroll
  for (int j = 0; j < 8; ++j)
#pragma unroll
    for (int p = 0; p < 8; ++p) acc[j][p] = 0.f;
#pragma unroll 8
  for (int k = 0; k < 64; ++k) {
    const int wb = k * 128 + (ty8 ^ ((k & 15) << 3));
    const float4 wv0 = *reinterpret_cast<const float4*>(&wt[wb]);
    const float4 wv1 = *reinterpret_cast<const float4*>(&wt[wb + 4]);
    const float4 xv0 = *reinterpret_cast<const float4*>(&xs[k * 128 + tx8]);
    const float4 xv1 = *reinterpret_cast<const float4*>(&xs[k * 128 + tx8 + 4]);
    const float wr[8] = {wv0.x, wv0.y, wv0.z, wv0.w, wv1.x, wv1.y, wv1.z, wv1.w};
    const float xr[8] = {xv0.x, xv0.y, xv0.z, xv0.w, xv1.x, xv1.y, xv1.z, xv1.w};
#pragma unroll
    for (int j = 0; j < 8; ++j)
#pragma unroll
      for (int p = 0; p < 8; ++p) acc[j][p] += wr[j] * xr[p];
  }
  // epilogue: +bias, convert to bf16, 16B stores
#pragma unroll
  for (int j = 0; j < 8; ++j) {
    const int o = ty8 + j;
    const float bv = kv_b[o];
    union { int4 v; bf16 h[8]; } ou;
#pragma unroll
    for (int p = 0; p < 8; ++p) ou.h[p] = __float2bfloat16(acc[j][p] + bv);
    *reinterpret_cast<int4*>(kv1 + (size_t)(b * 128 + o) * HW_ + s0 + tx8) = ou.v;
  }
}

// ---------------------------------------------------------------------------
// K1b: depthwise 3x3 (pad=1) on bf16 kv1 -> bf16 k||v (in d_out), fp32 math.
__global__ __launch_bounds__(256) void k1b_dw(
    const bf16* __restrict__ kv1, const float* __restrict__ dw_w,
    const float* __restrict__ dw_b, bf16* __restrict__ kvout,
    float* __restrict__ ssqpart) {
  const int tid = threadIdx.x;
  const int cchunk = tid & 63;            // 64 col-chunks of 8
  const int ch_sub = tid >> 6;            // 4 channels per block
  const int rs = blockIdx.x;              // 16 row strips of 32
  const int chgrp = blockIdx.y;           // 32
  const int b = blockIdx.z;
  const int ch = chgrp * 4 + ch_sub;
  const int c0 = cchunk * 8;
  const int r0 = rs * 32;
  const bf16* src = kv1 + (size_t)(b * 128 + ch) * HW_;
  const bool is_k = (ch < 64);
  const size_t obase = is_k ? (size_t)(b * 64 + ch) * HW_
                            : (size_t)(128 + b * 64 + (ch - 64)) * HW_;
  bf16* dst = kvout + obase;
  float dwr[9];
#pragma unroll
  for (int t = 0; t < 9; ++t) dwr[t] = dw_w[ch * 9 + t];
  const float bd = dw_b[ch];

  float a0[10], a1[10], a2[10];
  auto loadrow = [&](int gr, float* a) {
    if (gr < 0 || gr >= H_) {
#pragma unroll
      for (int t = 0; t < 10; ++t) a[t] = 0.f;
      return;
    }
    const bf16* rp = src + (size_t)gr * W_ + c0;
    union { int4 v; bf16 h[8]; } raw;
    raw.v = *reinterpret_cast<const int4*>(rp);
#pragma unroll
    for (int t = 0; t < 8; ++t) a[t + 1] = __bfloat162float(raw.h[t]);
    a[0] = (c0 > 0) ? __bfloat162float(rp[-1]) : 0.f;
    a[9] = (c0 < 504) ? __bfloat162float(rp[8]) : 0.f;
  };
  loadrow(r0 - 1, a0);
  loadrow(r0, a1);
  float sq = 0.f;
#pragma unroll 4
  for (int rr = 0; rr < 32; ++rr) {
    loadrow(r0 + rr + 1, a2);
    union { int4 v; bf16 h[8]; } ou;
#pragma unroll
    for (int j = 0; j < 8; ++j) {
      const float ov = bd
          + dwr[0] * a0[j] + dwr[1] * a0[j + 1] + dwr[2] * a0[j + 2]
          + dwr[3] * a1[j] + dwr[4] * a1[j + 1] + dwr[5] * a1[j + 2]
          + dwr[6] * a2[j] + dwr[7] * a2[j + 1] + dwr[8] * a2[j + 2];
      sq += ov * ov;
      ou.h[j] = __float2bfloat16(ov);
    }
    *reinterpret_cast<int4*>(dst + (size_t)(r0 + rr) * W_ + c0) = ou.v;
#pragma unroll
    for (int t = 0; t < 10; ++t) { a0[t] = a1[t]; a1[t] = a2[t]; }
  }
  // wave reduction of sq over the 64 col-chunk lanes (same ch per wave)
#pragma unroll
  for (int off = 32; off > 0; off >>= 1) sq += __shfl_down(sq, off, 64);
  if (is_k && cchunk == 0)
    ssqpart[(size_t)(b * 64 + ch) * 16 + rs] = sq;
}

// ---------------------------------------------------------------------------
// K2: reduce sumsq partials -> rnorm; qn = qsign*rnorm*temps
__global__ __launch_bounds__(256) void k2_finalize(
    const float* __restrict__ ssqpart, const float* __restrict__ temps,
    const float* __restrict__ qsign, float* __restrict__ rnorm,
    float* __restrict__ qn) {
  const int tid = threadIdx.x;
  if (tid < 128) {
    const int b = tid >> 6, c = tid & 63;
    float s = 0.f;
    for (int p = 0; p < 16; ++p) s += ssqpart[(size_t)(b * 64 + c) * 16 + p];
    rnorm[tid] = 1.f / fmaxf(sqrtf(s), EPSV);
  }
  __syncthreads();
  for (int idx = tid; idx < 512; idx += 256) {
    const int b = idx >> 8, n = (idx >> 6) & 3, d = idx & 63;
    qn[idx] = qsign[idx] * rnorm[b * 64 + d] * temps[n * 8 + (d >> 3)];
  }
}

// ---------------------------------------------------------------------------
// K3: softmax denominators from bf16 k. 8 px/thread, 16B k loads.
__global__ __launch_bounds__(256) void k3_denom(
    const bf16* __restrict__ kbuf, const float* __restrict__ qn,
    float* __restrict__ dpart) {
  const int tile = blockIdx.x, e = blockIdx.y, b = blockIdx.z;
  const int tid = threadIdx.x;
  float q[4][8];
#pragma unroll
  for (int n = 0; n < 4; ++n)
#pragma unroll
    for (int cc = 0; cc < 8; ++cc)
      q[n][cc] = qn[b * 256 + n * 64 + e * 8 + cc];
  const bf16* kb = kbuf + (size_t)(b * 64 + e * 8) * HW_;
  float dsum[4] = {0.f, 0.f, 0.f, 0.f};
  const int sbase = tile * 4096;
#pragma unroll
  for (int it = 0; it < 2; ++it) {
    const int s = sbase + (it * 256 + tid) * 8;
    float kf[8][8];
#pragma unroll
    for (int cc = 0; cc < 8; ++cc) {
      union { int4 v; bf16 h[8]; } r;
      r.v = *reinterpret_cast<const int4*>(kb + (size_t)cc * HW_ + s);
#pragma unroll
      for (int j = 0; j < 8; ++j) kf[cc][j] = __bfloat162float(r.h[j]);
    }
#pragma unroll
    for (int n = 0; n < 4; ++n) {
#pragma unroll
      for (int px = 0; px < 8; ++px) {
        float l = 0.f;
#pragma unroll
        for (int cc = 0; cc < 8; ++cc) l += q[n][cc] * kf[cc][px];
        dsum[n] += __expf(l);
      }
    }
  }
  __shared__ float red[256];
#pragma unroll
  for (int n = 0; n < 4; ++n) {
    red[tid] = dsum[n];
    __syncthreads();
    for (int st = 128; st > 0; st >>= 1) {
      if (tid < st) red[tid] += red[tid + st];
      __syncthreads();
    }
    if (tid == 0) dpart[(b * 32 + n * 8 + e) * 64 + tile] = red[0];
    __syncthreads();
  }
}

// ---------------------------------------------------------------------------
// K4: mid[b,cc,s] = sum_e (sum_n exp(l)/denom) * v[b,e,cc,s]  (bf16 k,v)
__global__ __launch_bounds__(256) void k4_attend(
    const bf16* __restrict__ kvbuf, const float* __restrict__ qn,
    const float* __restrict__ dpart, float* __restrict__ mid) {
  const int b = blockIdx.y;
  const int tid = threadIdx.x;
  __shared__ float qnl[256];
  __shared__ float rdl[32];
  qnl[tid] = qn[b * 256 + tid];
  if (tid < 32) {
    float s = 0.f;
    for (int t = 0; t < 64; ++t) s += dpart[(b * 32 + tid) * 64 + t];
    rdl[tid] = 1.f / s;
  }
  __syncthreads();
  const bf16* kb = kvbuf + (size_t)(b * 64) * HW_;
  const bf16* vb = kvbuf + (size_t)(128 + b * 64) * HW_;
  float* mb = mid + (size_t)b * 8 * HW_;
  const int s = (blockIdx.x * 256 + tid) * 4;
  float macc[8][4];
#pragma unroll
  for (int cc = 0; cc < 8; ++cc)
#pragma unroll
    for (int px = 0; px < 4; ++px) macc[cc][px] = 0.f;
#pragma unroll
  for (int e = 0; e < 8; ++e) {
    float kf[8][4];
#pragma unroll
    for (int cc = 0; cc < 8; ++cc) {
      union { ushort4 v; bf16 h[4]; } r;
      r.v = *reinterpret_cast<const ushort4*>(kb + (size_t)(e * 8 + cc) * HW_ + s);
#pragma unroll
      for (int px = 0; px < 4; ++px) kf[cc][px] = __bfloat162float(r.h[px]);
    }
    float wsum[4] = {0.f, 0.f, 0.f, 0.f};
#pragma unroll
    for (int n = 0; n < 4; ++n) {
      const float rd = rdl[n * 8 + e];
#pragma unroll
      for (int px = 0; px < 4; ++px) {
        float l = 0.f;
#pragma unroll
        for (int cc = 0; cc < 8; ++cc) l += qnl[n * 64 + e * 8 + cc] * kf[cc][px];
        wsum[px] += __expf(l) * rd;
      }
    }
#pragma unroll
    for (int cc = 0; cc < 8; ++cc) {
      union { ushort4 v; bf16 h[4]; } r;
      r.v = *reinterpret_cast<const ushort4*>(vb + (size_t)(e * 8 + cc) * HW_ + s);
#pragma unroll
      for (int px = 0; px < 4; ++px)
        macc[cc][px] += wsum[px] * __bfloat162float(r.h[px]);
    }
  }
#pragma unroll
  for (int cc = 0; cc < 8; ++cc)
    *reinterpret_cast<float4*>(mb + (size_t)cc * HW_ + s) =
        make_float4(macc[cc][0], macc[cc][1], macc[cc][2], macc[cc][3]);
}

// ---------------------------------------------------------------------------
// K5: grouped 3x3 (8->64, groups=8) + exact GELU + 1x1 (64->64).
// Block = 2 rows x 128 cols (256 px) x all 64 outputs.
// Phase 1: thread (ty,tx) computes g (GELU of cc1) for mid-ch=ty,
//          oo in [ty*8,ty*8+8), 8 px -> bf16 LDS gs[64][256].
// Phase 2: register GEMM, thread tile 8 outs x 8 px, w2t broadcast b128.
__global__ __launch_bounds__(256) void k5_cross(
    const float* __restrict__ mid, const float* __restrict__ cc1_w,
    const float* __restrict__ cc1_b, const float* __restrict__ cc2_w,
    const float* __restrict__ cc2_b, float* __restrict__ out) {
  const int tid = threadIdx.x;
  const int c0 = blockIdx.x * 128;
  const int r0 = blockIdx.y * 2;
  const int b = blockIdx.z;
  __shared__ float midl[8 * 4 * 132];   // [ch][4 rows][132], rows r0-1..r0+2
  __shared__ bf16 gs[64 * 256];         // [oo][px]
  __shared__ float w2t[4096];           // [oo][p] = cc2_w[p][oo]
  __shared__ float w1l[576];
  __shared__ float b1l[64], b2l[64];
  // stage mid tile (coalesced along cols)
  for (int idx = tid; idx < 8 * 4 * 130; idx += 256) {
    const int ch = idx / 520;
    const int rem = idx % 520;
    const int dr = rem / 130, lc = rem % 130;
    const int gr = r0 - 1 + dr, gc = c0 - 1 + lc;
    float v = 0.f;
    if (gr >= 0 && gr < H_ && gc >= 0 && gc < W_)
      v = mid[(size_t)(b * 8 + ch) * HW_ + (size_t)gr * W_ + gc];
    midl[(ch * 4 + dr) * 132 + lc] = v;
  }
  // stage w2 transposed; lanes vary p -> stride-1 LDS writes (no conflicts)
  for (int idx = tid; idx < 4096; idx += 256) {
    const int p = idx & 63, oo = idx >> 6;
    w2t[oo * 64 + p] = cc2_w[p * 64 + oo];
  }
  for (int idx = tid; idx < 576; idx += 256) w1l[idx] = cc1_w[idx];
  if (tid < 64) { b1l[tid] = cc1_b[tid]; b2l[tid] = cc2_b[tid]; }
  __syncthreads();

  const int ty = tid >> 5, tx = tid & 31;
  // ---- phase 1: grouped 3x3 + GELU -> gs (bf16) ----
  {
    const int rl = tx >> 4;            // local output row 0/1
    const int cb = (tx & 15) * 8;      // local col base
    float m[3][10];
#pragma unroll
    for (int dr = 0; dr < 3; ++dr)
#pragma unroll
      for (int t = 0; t < 10; ++t)
        m[dr][t] = midl[(ty * 4 + rl + dr) * 132 + cb + t];
    const int pxb = rl * 128 + cb;
#pragma unroll
    for (int j = 0; j < 8; ++j) {
      const int oo = ty * 8 + j;
      float w[9];
#pragma unroll
      for (int t = 0; t < 9; ++t) w[t] = w1l[oo * 9 + t];
      const float bb = b1l[oo];
      union { int4 v; bf16 h[8]; } gv;
#pragma unroll
      for (int i = 0; i < 8; ++i) {
        float a = bb;
#pragma unroll
        for (int dr = 0; dr < 3; ++dr)
#pragma unroll
          for (int dc = 0; dc < 3; ++dc)
            a += w[dr * 3 + dc] * m[dr][i + dc];
        a = 0.5f * a * (1.f + erff(a * 0.70710678118654752f));
        gv.h[i] = __float2bfloat16(a);
      }
      *reinterpret_cast<int4*>(&gs[oo * 256 + pxb]) = gv.v;
    }
  }
  __syncthreads();
  // ---- phase 2: out[p][px] = b2[p] + sum_oo w2[p][oo] * g[oo][px] ----
  const int p8 = ty * 8;
  const int px8 = tx * 8;
  float acc[8][8];
#pragma unroll
  for (int j = 0; j < 8; ++j)
#pragma unroll
    for (int i = 0; i < 8; ++i) acc[j][i] = 0.f;
#pragma unroll 8
  for (int k = 0; k < 64; ++k) {
    const float4 wv0 = *reinterpret_cast<const float4*>(&w2t[k * 64 + p8]);
    const float4 wv1 = *reinterpret_cast<const float4*>(&w2t[k * 64 + p8 + 4]);
    const float wr[8] = {wv0.x, wv0.y, wv0.z, wv0.w, wv1.x, wv1.y, wv1.z, wv1.w};
    union { int4 v; bf16 h[8]; } gr_;
    gr_.v = *reinterpret_cast<const int4*>(&gs[k * 256 + px8]);
    float gf[8];
#pragma unroll
    for (int i = 0; i < 8; ++i) gf[i] = __bfloat162float(gr_.h[i]);
#pragma unroll
    for (int j = 0; j < 8; ++j)
#pragma unroll
      for (int i = 0; i < 8; ++i) acc[j][i] += wr[j] * gf[i];
  }
  const int grow = r0 + (px8 >> 7);
  const int gcol = c0 + (px8 & 127);
  const size_t sb = (size_t)grow * W_ + gcol;
#pragma unroll
  for (int j = 0; j < 8; ++j) {
    const float bv = b2l[p8 + j];
    float* op = out + (size_t)(b * 64 + p8 + j) * HW_ + sb;
    *reinterpret_cast<float4*>(op) =
        make_float4(acc[j][0] + bv, acc[j][1] + bv, acc[j][2] + bv, acc[j][3] + bv);
    *reinterpret_cast<float4*>(op + 4) =
        make_float4(acc[j][4] + bv, acc[j][5] + bv, acc[j][6] + bv, acc[j][7] + bv);
  }
}

// ---------------------------------------------------------------------------
extern "C" void kernel_launch(void* const* d_in, const int* in_sizes, int n_in,
                              void* d_out, int out_size, void* d_ws, size_t ws_size,
                              hipStream_t stream) {
  const float* x        = (const float*)d_in[0];
  const float* metainfo = (const float*)d_in[1];
  const float* Wq       = (const float*)d_in[2];
  const float* bq       = (const float*)d_in[3];
  const float* temps    = (const float*)d_in[4];
  const float* kv_w     = (const float*)d_in[5];
  const float* kv_b     = (const float*)d_in[6];
  const float* dw_w     = (const float*)d_in[7];
  const float* dw_b     = (const float*)d_in[8];
  const float* cc1_w    = (const float*)d_in[9];
  const float* cc1_b    = (const float*)d_in[10];
  const float* cc2_w    = (const float*)d_in[11];
  const float* cc2_b    = (const float*)d_in[12];
  float* out = (float*)d_out;

  // ws layout (float offsets): kv1 bf16 occupies [0, 33554432) float-equiv.
  float* ws      = (float*)d_ws;
  bf16*  kv1     = (bf16*)d_ws;           // 2*128*HW bf16 = 134.2 MB
  float* mid     = ws + 33554432;         // 2*8*HW fp32   = 16.8 MB
  float* small_  = ws + 37748736;
  float* ssqpart = small_;                // 2*64*16 = 2048
  float* qsign   = small_ + 2048;         // 512
  float* rnorm   = small_ + 2560;         // 128
  float* qn      = small_ + 2688;         // 512
  float* dpart   = small_ + 3200;         // 64*64 = 4096

  // k (bf16) and v (bf16) live in d_out until K5 overwrites it with fp32 out.
  bf16* kvout = (bf16*)d_out;             // [k: 2*64*HW][v: 2*64*HW] bf16

  k0_qsign<<<1, 256, 0, stream>>>(metainfo, Wq, bq, qsign);
  k1a_conv1x1<<<4096, 256, 0, stream>>>(x, kv_w, kv_b, kv1);
  k1b_dw<<<dim3(16, 32, 2), 256, 0, stream>>>(kv1, dw_w, dw_b, kvout, ssqpart);
  k2_finalize<<<1, 256, 0, stream>>>(ssqpart, temps, qsign, rnorm, qn);
  k3_denom<<<dim3(64, 8, 2), 256, 0, stream>>>(kvout, qn, dpart);
  k4_attend<<<dim3(256, 2), 256, 0, stream>>>(kvout, qn, dpart, mid);
  k5_cross<<<dim3(4, 256, 2), 256, 0, stream>>>(mid, cc1_w, cc1_b, cc2_w,
                                                cc2_b, out);
}

// Round 6
// 389.371 us; speedup vs baseline: 3.6094x; 1.1640x over previous
//
#include <hip/hip_runtime.h>
#include <hip/hip_bf16.h>

#define B_    2
#define H_    512
#define W_    512
#define HW_   262144   // 512*512
#define EPSV  1e-12f

typedef __hip_bfloat16 bf16;
typedef __fp16 h16x2 __attribute__((ext_vector_type(2)));

// pack two fp32 into a dword of two fp16 (lo = a, hi = b), round-toward-zero
__device__ __forceinline__ uint pack2(float a, float b) {
  auto p = __builtin_amdgcn_cvt_pkrtz(a, b);   // V2h
  return __builtin_bit_cast(uint, p);
}

// d = a.lo*b.lo + a.hi*b.hi + c  (v_dot2_f32_f16)
__device__ __forceinline__ float fdot2h(uint a, uint b, float c) {
  return __builtin_amdgcn_fdot2(__builtin_bit_cast(h16x2, a),
                                __builtin_bit_cast(h16x2, b), c, false);
}

// ---------------------------------------------------------------------------
// K0: q = metainfo @ Wq^T + bq, then elementwise sign.
__global__ __launch_bounds__(256) void k0_qsign(
    const float* __restrict__ metainfo, const float* __restrict__ Wq,
    const float* __restrict__ bq, float* __restrict__ qsign) {
  for (int idx = threadIdx.x; idx < 512; idx += 256) {
    const int b = idx >> 8, n = (idx >> 6) & 3, d = idx & 63;
    float acc = bq[n * 64 + d];
#pragma unroll
    for (int m = 0; m < 4; ++m)
      acc += metainfo[(b * 4 + n) * 4 + m] * Wq[(n * 64 + d) * 4 + m];
    qsign[idx] = acc / fmaxf(fabsf(acc), EPSV);
  }
}

// ---------------------------------------------------------------------------
// K1a: 1x1 conv as packed-f16 dot2 GEMM.
// kv1[b][o][s] (bf16) = sum_i W[o][i]*x[b][i][s] + bias.
// Block tile 128 o x 128 px, K=64 packed as 32 k2-dwords. LDS 32 KB.
// Thread tile 8 o x 8 px (px split tx*4 / tx*4+64 -> 2-way LDS aliasing=free).
__global__ __launch_bounds__(256) void k1a_conv1x1(
    const float* __restrict__ x, const float* __restrict__ kv_w,
    const float* __restrict__ kv_b, bf16* __restrict__ kv1) {
  const int tid = threadIdx.x;
  const int p0 = blockIdx.x * 128;     // global pixel in [0, 2*HW)
  const int b  = p0 >> 18;
  const int s0 = p0 & (HW_ - 1);
  __shared__ uint xs2[32 * 128];   // [k2][px]
  __shared__ uint ws2[32 * 128];   // [k2][o]
  // stage W packed: ws2[k2][o] = (w[o][2k2], w[o][2k2+1])
  for (int t = tid; t < 4096; t += 256) {
    const int k2 = t >> 7, o = t & 127;
    const float2 w2 = *reinterpret_cast<const float2*>(kv_w + o * 64 + 2 * k2);
    ws2[k2 * 128 + o] = pack2(w2.x, w2.y);
  }
  // stage x packed: xs2[k2][px] = (x[2k2][px], x[2k2+1][px])
  const float* xb = x + (size_t)b * 64 * HW_ + s0;
  for (int t = tid; t < 1024; t += 256) {
    const int k2 = t >> 5, px4 = (t & 31) * 4;
    const float4 ev = *reinterpret_cast<const float4*>(xb + (size_t)(2 * k2) * HW_ + px4);
    const float4 od = *reinterpret_cast<const float4*>(xb + (size_t)(2 * k2 + 1) * HW_ + px4);
    uint4 pk;
    pk.x = pack2(ev.x, od.x);
    pk.y = pack2(ev.y, od.y);
    pk.z = pack2(ev.z, od.z);
    pk.w = pack2(ev.w, od.w);
    *reinterpret_cast<uint4*>(&xs2[k2 * 128 + px4]) = pk;
  }
  __syncthreads();
  const int ty = tid >> 4, tx = tid & 15;
  const int o8 = ty * 8;
  const int pxa = tx * 4;            // second half at pxa+64
  float acc[8][8];                   // [o][i]: i<4 -> pxa+i, i>=4 -> pxa+60+i
#pragma unroll
  for (int j = 0; j < 8; ++j)
#pragma unroll
    for (int i = 0; i < 8; ++i) acc[j][i] = 0.f;
#pragma unroll 4
  for (int k2 = 0; k2 < 32; ++k2) {
    const uint4 w0 = *reinterpret_cast<const uint4*>(&ws2[k2 * 128 + o8]);
    const uint4 w1 = *reinterpret_cast<const uint4*>(&ws2[k2 * 128 + o8 + 4]);
    const uint4 xa = *reinterpret_cast<const uint4*>(&xs2[k2 * 128 + pxa]);
    const uint4 xc = *reinterpret_cast<const uint4*>(&xs2[k2 * 128 + pxa + 64]);
    const uint wr[8] = {w0.x, w0.y, w0.z, w0.w, w1.x, w1.y, w1.z, w1.w};
    const uint xr[8] = {xa.x, xa.y, xa.z, xa.w, xc.x, xc.y, xc.z, xc.w};
#pragma unroll
    for (int j = 0; j < 8; ++j)
#pragma unroll
      for (int i = 0; i < 8; ++i) acc[j][i] = fdot2h(wr[j], xr[i], acc[j][i]);
  }
  // epilogue: +bias, bf16, two 8B stores per output row
#pragma unroll
  for (int j = 0; j < 8; ++j) {
    const int o = o8 + j;
    const float bv = kv_b[o];
    union { ushort4 v; bf16 h[4]; } oa, ob;
#pragma unroll
    for (int i = 0; i < 4; ++i) {
      oa.h[i] = __float2bfloat16(acc[j][i] + bv);
      ob.h[i] = __float2bfloat16(acc[j][4 + i] + bv);
    }
    bf16* dst = kv1 + (size_t)(b * 128 + o) * HW_ + s0;
    *reinterpret_cast<ushort4*>(dst + pxa) = oa.v;
    *reinterpret_cast<ushort4*>(dst + pxa + 64) = ob.v;
  }
}

// ---------------------------------------------------------------------------
// K1b: depthwise 3x3 (pad=1) on bf16 kv1 -> bf16 k||v (in d_out), fp32 math.
__global__ __launch_bounds__(256) void k1b_dw(
    const bf16* __restrict__ kv1, const float* __restrict__ dw_w,
    const float* __restrict__ dw_b, bf16* __restrict__ kvout,
    float* __restrict__ ssqpart) {
  const int tid = threadIdx.x;
  const int cchunk = tid & 63;            // 64 col-chunks of 8
  const int ch_sub = tid >> 6;            // 4 channels per block
  const int rs = blockIdx.x;              // 16 row strips of 32
  const int chgrp = blockIdx.y;           // 32
  const int b = blockIdx.z;
  const int ch = chgrp * 4 + ch_sub;
  const int c0 = cchunk * 8;
  const int r0 = rs * 32;
  const bf16* src = kv1 + (size_t)(b * 128 + ch) * HW_;
  const bool is_k = (ch < 64);
  const size_t obase = is_k ? (size_t)(b * 64 + ch) * HW_
                            : (size_t)(128 + b * 64 + (ch - 64)) * HW_;
  bf16* dst = kvout + obase;
  float dwr[9];
#pragma unroll
  for (int t = 0; t < 9; ++t) dwr[t] = dw_w[ch * 9 + t];
  const float bd = dw_b[ch];

  float a0[10], a1[10], a2[10];
  auto loadrow = [&](int gr, float* a) {
    if (gr < 0 || gr >= H_) {
#pragma unroll
      for (int t = 0; t < 10; ++t) a[t] = 0.f;
      return;
    }
    const bf16* rp = src + (size_t)gr * W_ + c0;
    union { int4 v; bf16 h[8]; } raw;
    raw.v = *reinterpret_cast<const int4*>(rp);
#pragma unroll
    for (int t = 0; t < 8; ++t) a[t + 1] = __bfloat162float(raw.h[t]);
    a[0] = (c0 > 0) ? __bfloat162float(rp[-1]) : 0.f;
    a[9] = (c0 < 504) ? __bfloat162float(rp[8]) : 0.f;
  };
  loadrow(r0 - 1, a0);
  loadrow(r0, a1);
  float sq = 0.f;
#pragma unroll 4
  for (int rr = 0; rr < 32; ++rr) {
    loadrow(r0 + rr + 1, a2);
    union { int4 v; bf16 h[8]; } ou;
#pragma unroll
    for (int j = 0; j < 8; ++j) {
      const float ov = bd
          + dwr[0] * a0[j] + dwr[1] * a0[j + 1] + dwr[2] * a0[j + 2]
          + dwr[3] * a1[j] + dwr[4] * a1[j + 1] + dwr[5] * a1[j + 2]
          + dwr[6] * a2[j] + dwr[7] * a2[j + 1] + dwr[8] * a2[j + 2];
      sq += ov * ov;
      ou.h[j] = __float2bfloat16(ov);
    }
    *reinterpret_cast<int4*>(dst + (size_t)(r0 + rr) * W_ + c0) = ou.v;
#pragma unroll
    for (int t = 0; t < 10; ++t) { a0[t] = a1[t]; a1[t] = a2[t]; }
  }
  // wave reduction of sq over the 64 col-chunk lanes (same ch per wave)
#pragma unroll
  for (int off = 32; off > 0; off >>= 1) sq += __shfl_down(sq, off, 64);
  if (is_k && cchunk == 0)
    ssqpart[(size_t)(b * 64 + ch) * 16 + rs] = sq;
}

// ---------------------------------------------------------------------------
// K2: reduce sumsq partials -> rnorm; qn = qsign*rnorm*temps
__global__ __launch_bounds__(256) void k2_finalize(
    const float* __restrict__ ssqpart, const float* __restrict__ temps,
    const float* __restrict__ qsign, float* __restrict__ rnorm,
    float* __restrict__ qn) {
  const int tid = threadIdx.x;
  if (tid < 128) {
    const int b = tid >> 6, c = tid & 63;
    float s = 0.f;
    for (int p = 0; p < 16; ++p) s += ssqpart[(size_t)(b * 64 + c) * 16 + p];
    rnorm[tid] = 1.f / fmaxf(sqrtf(s), EPSV);
  }
  __syncthreads();
  for (int idx = tid; idx < 512; idx += 256) {
    const int b = idx >> 8, n = (idx >> 6) & 3, d = idx & 63;
    qn[idx] = qsign[idx] * rnorm[b * 64 + d] * temps[n * 8 + (d >> 3)];
  }
}

// ---------------------------------------------------------------------------
// K3: softmax denominators from bf16 k. 8 px/thread, 16B k loads.
__global__ __launch_bounds__(256) void k3_denom(
    const bf16* __restrict__ kbuf, const float* __restrict__ qn,
    float* __restrict__ dpart) {
  const int tile = blockIdx.x, e = blockIdx.y, b = blockIdx.z;
  const int tid = threadIdx.x;
  float q[4][8];
#pragma unroll
  for (int n = 0; n < 4; ++n)
#pragma unroll
    for (int cc = 0; cc < 8; ++cc)
      q[n][cc] = qn[b * 256 + n * 64 + e * 8 + cc];
  const bf16* kb = kbuf + (size_t)(b * 64 + e * 8) * HW_;
  float dsum[4] = {0.f, 0.f, 0.f, 0.f};
  const int sbase = tile * 4096;
#pragma unroll
  for (int it = 0; it < 2; ++it) {
    const int s = sbase + (it * 256 + tid) * 8;
    float kf[8][8];
#pragma unroll
    for (int cc = 0; cc < 8; ++cc) {
      union { int4 v; bf16 h[8]; } r;
      r.v = *reinterpret_cast<const int4*>(kb + (size_t)cc * HW_ + s);
#pragma unroll
      for (int j = 0; j < 8; ++j) kf[cc][j] = __bfloat162float(r.h[j]);
    }
#pragma unroll
    for (int n = 0; n < 4; ++n) {
#pragma unroll
      for (int px = 0; px < 8; ++px) {
        float l = 0.f;
#pragma unroll
        for (int cc = 0; cc < 8; ++cc) l += q[n][cc] * kf[cc][px];
        dsum[n] += __expf(l);
      }
    }
  }
  __shared__ float red[256];
#pragma unroll
  for (int n = 0; n < 4; ++n) {
    red[tid] = dsum[n];
    __syncthreads();
    for (int st = 128; st > 0; st >>= 1) {
      if (tid < st) red[tid] += red[tid + st];
      __syncthreads();
    }
    if (tid == 0) dpart[(b * 32 + n * 8 + e) * 64 + tile] = red[0];
    __syncthreads();
  }
}

// ---------------------------------------------------------------------------
// K4: mid[b,cc,s] = sum_e (sum_n exp(l)/denom) * v[b,e,cc,s]  (bf16 k,v)
__global__ __launch_bounds__(256) void k4_attend(
    const bf16* __restrict__ kvbuf, const float* __restrict__ qn,
    const float* __restrict__ dpart, float* __restrict__ mid) {
  const int b = blockIdx.y;
  const int tid = threadIdx.x;
  __shared__ float qnl[256];
  __shared__ float rdl[32];
  qnl[tid] = qn[b * 256 + tid];
  if (tid < 32) {
    float s = 0.f;
    for (int t = 0; t < 64; ++t) s += dpart[(b * 32 + tid) * 64 + t];
    rdl[tid] = 1.f / s;
  }
  __syncthreads();
  const bf16* kb = kvbuf + (size_t)(b * 64) * HW_;
  const bf16* vb = kvbuf + (size_t)(128 + b * 64) * HW_;
  float* mb = mid + (size_t)b * 8 * HW_;
  const int s = (blockIdx.x * 256 + tid) * 4;
  float macc[8][4];
#pragma unroll
  for (int cc = 0; cc < 8; ++cc)
#pragma unroll
    for (int px = 0; px < 4; ++px) macc[cc][px] = 0.f;
#pragma unroll
  for (int e = 0; e < 8; ++e) {
    float kf[8][4];
#pragma unroll
    for (int cc = 0; cc < 8; ++cc) {
      union { ushort4 v; bf16 h[4]; } r;
      r.v = *reinterpret_cast<const ushort4*>(kb + (size_t)(e * 8 + cc) * HW_ + s);
#pragma unroll
      for (int px = 0; px < 4; ++px) kf[cc][px] = __bfloat162float(r.h[px]);
    }
    float wsum[4] = {0.f, 0.f, 0.f, 0.f};
#pragma unroll
    for (int n = 0; n < 4; ++n) {
      const float rd = rdl[n * 8 + e];
#pragma unroll
      for (int px = 0; px < 4; ++px) {
        float l = 0.f;
#pragma unroll
        for (int cc = 0; cc < 8; ++cc) l += qnl[n * 64 + e * 8 + cc] * kf[cc][px];
        wsum[px] += __expf(l) * rd;
      }
    }
#pragma unroll
    for (int cc = 0; cc < 8; ++cc) {
      union { ushort4 v; bf16 h[4]; } r;
      r.v = *reinterpret_cast<const ushort4*>(vb + (size_t)(e * 8 + cc) * HW_ + s);
#pragma unroll
      for (int px = 0; px < 4; ++px)
        macc[cc][px] += wsum[px] * __bfloat162float(r.h[px]);
    }
  }
#pragma unroll
  for (int cc = 0; cc < 8; ++cc)
    *reinterpret_cast<float4*>(mb + (size_t)cc * HW_ + s) =
        make_float4(macc[cc][0], macc[cc][1], macc[cc][2], macc[cc][3]);
}

// ---------------------------------------------------------------------------
// K5: grouped 3x3 (8->64, groups=8) + exact GELU + 1x1 (64->64).
__global__ __launch_bounds__(256) void k5_cross(
    const float* __restrict__ mid, const float* __restrict__ cc1_w,
    const float* __restrict__ cc1_b, const float* __restrict__ cc2_w,
    const float* __restrict__ cc2_b, float* __restrict__ out) {
  const int tid = threadIdx.x;
  const int c0 = blockIdx.x * 128;
  const int r0 = blockIdx.y * 2;
  const int b = blockIdx.z;
  __shared__ float midl[8 * 4 * 132];   // [ch][4 rows][132], rows r0-1..r0+2
  __shared__ bf16 gs[64 * 256];         // [oo][px]
  __shared__ float w2t[4096];           // [oo][p] = cc2_w[p][oo]
  __shared__ float w1l[576];
  __shared__ float b1l[64], b2l[64];
  // stage mid tile (coalesced along cols)
  for (int idx = tid; idx < 8 * 4 * 130; idx += 256) {
    const int ch = idx / 520;
    const int rem = idx % 520;
    const int dr = rem / 130, lc = rem % 130;
    const int gr = r0 - 1 + dr, gc = c0 - 1 + lc;
    float v = 0.f;
    if (gr >= 0 && gr < H_ && gc >= 0 && gc < W_)
      v = mid[(size_t)(b * 8 + ch) * HW_ + (size_t)gr * W_ + gc];
    midl[(ch * 4 + dr) * 132 + lc] = v;
  }
  // stage w2 transposed; lanes vary p -> stride-1 LDS writes (no conflicts)
  for (int idx = tid; idx < 4096; idx += 256) {
    const int p = idx & 63, oo = idx >> 6;
    w2t[oo * 64 + p] = cc2_w[p * 64 + oo];
  }
  for (int idx = tid; idx < 576; idx += 256) w1l[idx] = cc1_w[idx];
  if (tid < 64) { b1l[tid] = cc1_b[tid]; b2l[tid] = cc2_b[tid]; }
  __syncthreads();

  const int ty = tid >> 5, tx = tid & 31;
  // ---- phase 1: grouped 3x3 + GELU -> gs (bf16) ----
  {
    const int rl = tx >> 4;            // local output row 0/1
    const int cb = (tx & 15) * 8;      // local col base
    float m[3][10];
#pragma unroll
    for (int dr = 0; dr < 3; ++dr)
#pragma unroll
      for (int t = 0; t < 10; ++t)
        m[dr][t] = midl[(ty * 4 + rl + dr) * 132 + cb + t];
    const int pxb = rl * 128 + cb;
#pragma unroll
    for (int j = 0; j < 8; ++j) {
      const int oo = ty * 8 + j;
      float w[9];
#pragma unroll
      for (int t = 0; t < 9; ++t) w[t] = w1l[oo * 9 + t];
      const float bb = b1l[oo];
      union { int4 v; bf16 h[8]; } gv;
#pragma unroll
      for (int i = 0; i < 8; ++i) {
        float a = bb;
#pragma unroll
        for (int dr = 0; dr < 3; ++dr)
#pragma unroll
          for (int dc = 0; dc < 3; ++dc)
            a += w[dr * 3 + dc] * m[dr][i + dc];
        a = 0.5f * a * (1.f + erff(a * 0.70710678118654752f));
        gv.h[i] = __float2bfloat16(a);
      }
      *reinterpret_cast<int4*>(&gs[oo * 256 + pxb]) = gv.v;
    }
  }
  __syncthreads();
  // ---- phase 2: out[p][px] = b2[p] + sum_oo w2[p][oo] * g[oo][px] ----
  const int p8 = ty * 8;
  const int px8 = tx * 8;
  float acc[8][8];
#pragma unroll
  for (int j = 0; j < 8; ++j)
#pragma unroll
    for (int i = 0; i < 8; ++i) acc[j][i] = 0.f;
#pragma unroll 8
  for (int k = 0; k < 64; ++k) {
    const float4 wv0 = *reinterpret_cast<const float4*>(&w2t[k * 64 + p8]);
    const float4 wv1 = *reinterpret_cast<const float4*>(&w2t[k * 64 + p8 + 4]);
    const float wr[8] = {wv0.x, wv0.y, wv0.z, wv0.w, wv1.x, wv1.y, wv1.z, wv1.w};
    union { int4 v; bf16 h[8]; } gr_;
    gr_.v = *reinterpret_cast<const int4*>(&gs[k * 256 + px8]);
    float gf[8];
#pragma unroll
    for (int i = 0; i < 8; ++i) gf[i] = __bfloat162float(gr_.h[i]);
#pragma unroll
    for (int j = 0; j < 8; ++j)
#pragma unroll
      for (int i = 0; i < 8; ++i) acc[j][i] += wr[j] * gf[i];
  }
  const int grow = r0 + (px8 >> 7);
  const int gcol = c0 + (px8 & 127);
  const size_t sb = (size_t)grow * W_ + gcol;
#pragma unroll
  for (int j = 0; j < 8; ++j) {
    const float bv = b2l[p8 + j];
    float* op = out + (size_t)(b * 64 + p8 + j) * HW_ + sb;
    *reinterpret_cast<float4*>(op) =
        make_float4(acc[j][0] + bv, acc[j][1] + bv, acc[j][2] + bv, acc[j][3] + bv);
    *reinterpret_cast<float4*>(op + 4) =
        make_float4(acc[j][4] + bv, acc[j][5] + bv, acc[j][6] + bv, acc[j][7] + bv);
  }
}

// ---------------------------------------------------------------------------
extern "C" void kernel_launch(void* const* d_in, const int* in_sizes, int n_in,
                              void* d_out, int out_size, void* d_ws, size_t ws_size,
                              hipStream_t stream) {
  const float* x        = (const float*)d_in[0];
  const float* metainfo = (const float*)d_in[1];
  const float* Wq       = (const float*)d_in[2];
  const float* bq       = (const float*)d_in[3];
  const float* temps    = (const float*)d_in[4];
  const float* kv_w     = (const float*)d_in[5];
  const float* kv_b     = (const float*)d_in[6];
  const float* dw_w     = (const float*)d_in[7];
  const float* dw_b     = (const float*)d_in[8];
  const float* cc1_w    = (const float*)d_in[9];
  const float* cc1_b    = (const float*)d_in[10];
  const float* cc2_w    = (const float*)d_in[11];
  const float* cc2_b    = (const float*)d_in[12];
  float* out = (float*)d_out;

  // ws layout (float offsets): kv1 bf16 occupies [0, 33554432) float-equiv.
  float* ws      = (float*)d_ws;
  bf16*  kv1     = (bf16*)d_ws;           // 2*128*HW bf16 = 134.2 MB
  float* mid     = ws + 33554432;         // 2*8*HW fp32   = 16.8 MB
  float* small_  = ws + 37748736;
  float* ssqpart = small_;                // 2*64*16 = 2048
  float* qsign   = small_ + 2048;         // 512
  float* rnorm   = small_ + 2560;         // 128
  float* qn      = small_ + 2688;         // 512
  float* dpart   = small_ + 3200;         // 64*64 = 4096

  // k (bf16) and v (bf16) live in d_out until K5 overwrites it with fp32 out.
  bf16* kvout = (bf16*)d_out;             // [k: 2*64*HW][v: 2*64*HW] bf16

  k0_qsign<<<1, 256, 0, stream>>>(metainfo, Wq, bq, qsign);
  k1a_conv1x1<<<4096, 256, 0, stream>>>(x, kv_w, kv_b, kv1);
  k1b_dw<<<dim3(16, 32, 2), 256, 0, stream>>>(kv1, dw_w, dw_b, kvout, ssqpart);
  k2_finalize<<<1, 256, 0, stream>>>(ssqpart, temps, qsign, rnorm, qn);
  k3_denom<<<dim3(64, 8, 2), 256, 0, stream>>>(kvout, qn, dpart);
  k4_attend<<<dim3(256, 2), 256, 0, stream>>>(kvout, qn, dpart, mid);
  k5_cross<<<dim3(4, 256, 2), 256, 0, stream>>>(mid, cc1_w, cc1_b, cc2_w,
                                                cc2_b, out);
}

// Round 7
// 362.359 us; speedup vs baseline: 3.8784x; 1.0745x over previous
//
#include <hip/hip_runtime.h>
#include <hip/hip_bf16.h>

#define B_    2
#define H_    512
#define W_    512
#define HW_   262144   // 512*512
#define EPSV  1e-12f

typedef __hip_bfloat16 bf16;
typedef __fp16 h16x8 __attribute__((ext_vector_type(8)));
typedef float f32x4 __attribute__((ext_vector_type(4)));

// ---------------------------------------------------------------------------
// K1a: 1x1 conv as f16 MFMA GEMM. kv1[b][o][s] (bf16) = sum_i W[o][i]*x[i][s]+b
// Block tile: M=128 (all outs) x N=128 px, K=64. 4 waves, each 64x64.
// LDS layout [kg][row][8] f16 (kg = k/8): frag reads are 16 consecutive
// 16B slots per 16 lanes -> conflict-free ds_read_b128.
__global__ __launch_bounds__(256) void k1a_conv1x1(
    const float* __restrict__ x, const float* __restrict__ kv_w,
    const float* __restrict__ kv_b, bf16* __restrict__ kv1) {
  const int tid = threadIdx.x;
  const int p0 = blockIdx.x * 128;     // global pixel in [0, 2*HW)
  const int b  = p0 >> 18;
  const int s0 = p0 & (HW_ - 1);
  __shared__ __fp16 Wl[8 * 128 * 8];   // [kg][o][e]  16 KB
  __shared__ __fp16 Xl[8 * 128 * 8];   // [kg][px][e] 16 KB

  // ---- stage W: thread t -> o = t>>1, k-half = t&1 (32 k's) ----
  {
    const int o = tid >> 1, half = tid & 1;
    const float* wp = kv_w + o * 64 + half * 32;
#pragma unroll
    for (int j = 0; j < 4; ++j) {
      const float4 a = *reinterpret_cast<const float4*>(wp + j * 8);
      const float4 c = *reinterpret_cast<const float4*>(wp + j * 8 + 4);
      h16x8 h;
      h[0] = (__fp16)a.x; h[1] = (__fp16)a.y; h[2] = (__fp16)a.z; h[3] = (__fp16)a.w;
      h[4] = (__fp16)c.x; h[5] = (__fp16)c.y; h[6] = (__fp16)c.z; h[7] = (__fp16)c.w;
      *reinterpret_cast<h16x8*>(&Wl[((half * 4 + j) * 128 + o) * 8]) = h;
    }
  }
  // ---- stage x transposed via registers: px = t&127, kg-half = t>>7 ----
  {
    const int px = tid & 127, kgh = tid >> 7;
    const float* xp = x + (size_t)b * 64 * HW_ + s0 + px;
#pragma unroll
    for (int j = 0; j < 4; ++j) {
      const int kg = kgh * 4 + j;
      h16x8 h;
#pragma unroll
      for (int e = 0; e < 8; ++e)
        h[e] = (__fp16)xp[(size_t)(kg * 8 + e) * HW_];
      *reinterpret_cast<h16x8*>(&Xl[(kg * 128 + px) * 8]) = h;
    }
  }
  __syncthreads();

  // ---- MFMA: wave wv covers M-half (wv&1)*64, N-half (wv>>1)*64 ----
  const int wv = tid >> 6, lane = tid & 63;
  const int m0 = (wv & 1) * 64, n0 = (wv >> 1) * 64;
  const int lr = lane & 15, lg = lane >> 4;
  f32x4 acc[4][4];
#pragma unroll
  for (int mt = 0; mt < 4; ++mt)
#pragma unroll
    for (int nt = 0; nt < 4; ++nt) acc[mt][nt] = (f32x4){0.f, 0.f, 0.f, 0.f};
#pragma unroll
  for (int ks = 0; ks < 2; ++ks) {
    h16x8 af[4], bfr[4];
#pragma unroll
    for (int mt = 0; mt < 4; ++mt)
      af[mt] = *reinterpret_cast<const h16x8*>(
          &Wl[((ks * 4 + lg) * 128 + m0 + mt * 16 + lr) * 8]);
#pragma unroll
    for (int nt = 0; nt < 4; ++nt)
      bfr[nt] = *reinterpret_cast<const h16x8*>(
          &Xl[((ks * 4 + lg) * 128 + n0 + nt * 16 + lr) * 8]);
#pragma unroll
    for (int mt = 0; mt < 4; ++mt)
#pragma unroll
      for (int nt = 0; nt < 4; ++nt)
        acc[mt][nt] = __builtin_amdgcn_mfma_f32_16x16x32_f16(
            af[mt], bfr[nt], acc[mt][nt], 0, 0, 0);
  }
  // ---- epilogue: C/D layout col=lane&15 (px), row=(lane>>4)*4+r (o) ----
  bf16* dst = kv1 + (size_t)b * 128 * HW_ + s0;
#pragma unroll
  for (int mt = 0; mt < 4; ++mt) {
#pragma unroll
    for (int r = 0; r < 4; ++r) {
      const int o = m0 + mt * 16 + lg * 4 + r;
      const float bv = kv_b[o];
      bf16* op = dst + (size_t)o * HW_;
#pragma unroll
      for (int nt = 0; nt < 4; ++nt)
        op[n0 + nt * 16 + lr] = __float2bfloat16(acc[mt][nt][r] + bv);
    }
  }
}

// ---------------------------------------------------------------------------
// K1b: depthwise 3x3 (pad=1) on bf16 kv1 -> bf16 k||v (in d_out), fp32 math.
__global__ __launch_bounds__(256) void k1b_dw(
    const bf16* __restrict__ kv1, const float* __restrict__ dw_w,
    const float* __restrict__ dw_b, bf16* __restrict__ kvout,
    float* __restrict__ ssqpart) {
  const int tid = threadIdx.x;
  const int cchunk = tid & 63;            // 64 col-chunks of 8
  const int ch_sub = tid >> 6;            // 4 channels per block
  const int rs = blockIdx.x;              // 16 row strips of 32
  const int chgrp = blockIdx.y;           // 32
  const int b = blockIdx.z;
  const int ch = chgrp * 4 + ch_sub;
  const int c0 = cchunk * 8;
  const int r0 = rs * 32;
  const bf16* src = kv1 + (size_t)(b * 128 + ch) * HW_;
  const bool is_k = (ch < 64);
  const size_t obase = is_k ? (size_t)(b * 64 + ch) * HW_
                            : (size_t)(128 + b * 64 + (ch - 64)) * HW_;
  bf16* dst = kvout + obase;
  float dwr[9];
#pragma unroll
  for (int t = 0; t < 9; ++t) dwr[t] = dw_w[ch * 9 + t];
  const float bd = dw_b[ch];

  float a0[10], a1[10], a2[10];
  auto loadrow = [&](int gr, float* a) {
    if (gr < 0 || gr >= H_) {
#pragma unroll
      for (int t = 0; t < 10; ++t) a[t] = 0.f;
      return;
    }
    const bf16* rp = src + (size_t)gr * W_ + c0;
    union { int4 v; bf16 h[8]; } raw;
    raw.v = *reinterpret_cast<const int4*>(rp);
#pragma unroll
    for (int t = 0; t < 8; ++t) a[t + 1] = __bfloat162float(raw.h[t]);
    a[0] = (c0 > 0) ? __bfloat162float(rp[-1]) : 0.f;
    a[9] = (c0 < 504) ? __bfloat162float(rp[8]) : 0.f;
  };
  loadrow(r0 - 1, a0);
  loadrow(r0, a1);
  float sq = 0.f;
#pragma unroll 4
  for (int rr = 0; rr < 32; ++rr) {
    loadrow(r0 + rr + 1, a2);
    union { int4 v; bf16 h[8]; } ou;
#pragma unroll
    for (int j = 0; j < 8; ++j) {
      const float ov = bd
          + dwr[0] * a0[j] + dwr[1] * a0[j + 1] + dwr[2] * a0[j + 2]
          + dwr[3] * a1[j] + dwr[4] * a1[j + 1] + dwr[5] * a1[j + 2]
          + dwr[6] * a2[j] + dwr[7] * a2[j + 1] + dwr[8] * a2[j + 2];
      sq += ov * ov;
      ou.h[j] = __float2bfloat16(ov);
    }
    *reinterpret_cast<int4*>(dst + (size_t)(r0 + rr) * W_ + c0) = ou.v;
#pragma unroll
    for (int t = 0; t < 10; ++t) { a0[t] = a1[t]; a1[t] = a2[t]; }
  }
  // wave reduction of sq over the 64 col-chunk lanes (same ch per wave)
#pragma unroll
  for (int off = 32; off > 0; off >>= 1) sq += __shfl_down(sq, off, 64);
  if (is_k && cchunk == 0)
    ssqpart[(size_t)(b * 64 + ch) * 16 + rs] = sq;
}

// ---------------------------------------------------------------------------
// K2: reduce sumsq partials -> rnorm; qn = sign(q)*rnorm*temps (k0 folded in)
__global__ __launch_bounds__(256) void k2_finalize(
    const float* __restrict__ ssqpart, const float* __restrict__ temps,
    const float* __restrict__ metainfo, const float* __restrict__ Wq,
    const float* __restrict__ bq, float* __restrict__ rnorm,
    float* __restrict__ qn) {
  const int tid = threadIdx.x;
  if (tid < 128) {
    const int b = tid >> 6, c = tid & 63;
    float s = 0.f;
    for (int p = 0; p < 16; ++p) s += ssqpart[(size_t)(b * 64 + c) * 16 + p];
    rnorm[tid] = 1.f / fmaxf(sqrtf(s), EPSV);
  }
  __syncthreads();
  for (int idx = tid; idx < 512; idx += 256) {
    const int b = idx >> 8, n = (idx >> 6) & 3, d = idx & 63;
    float acc = bq[n * 64 + d];
#pragma unroll
    for (int m = 0; m < 4; ++m)
      acc += metainfo[(b * 4 + n) * 4 + m] * Wq[(n * 64 + d) * 4 + m];
    const float sgn = acc / fmaxf(fabsf(acc), EPSV);
    qn[idx] = sgn * rnorm[b * 64 + d] * temps[n * 8 + (d >> 3)];
  }
}

// ---------------------------------------------------------------------------
// K3: softmax denominators from bf16 k. 8 px/thread, 16B k loads.
__global__ __launch_bounds__(256) void k3_denom(
    const bf16* __restrict__ kbuf, const float* __restrict__ qn,
    float* __restrict__ dpart) {
  const int tile = blockIdx.x, e = blockIdx.y, b = blockIdx.z;
  const int tid = threadIdx.x;
  float q[4][8];
#pragma unroll
  for (int n = 0; n < 4; ++n)
#pragma unroll
    for (int cc = 0; cc < 8; ++cc)
      q[n][cc] = qn[b * 256 + n * 64 + e * 8 + cc];
  const bf16* kb = kbuf + (size_t)(b * 64 + e * 8) * HW_;
  float dsum[4] = {0.f, 0.f, 0.f, 0.f};
  const int sbase = tile * 4096;
#pragma unroll
  for (int it = 0; it < 2; ++it) {
    const int s = sbase + (it * 256 + tid) * 8;
    float kf[8][8];
#pragma unroll
    for (int cc = 0; cc < 8; ++cc) {
      union { int4 v; bf16 h[8]; } r;
      r.v = *reinterpret_cast<const int4*>(kb + (size_t)cc * HW_ + s);
#pragma unroll
      for (int j = 0; j < 8; ++j) kf[cc][j] = __bfloat162float(r.h[j]);
    }
#pragma unroll
    for (int n = 0; n < 4; ++n) {
#pragma unroll
      for (int px = 0; px < 8; ++px) {
        float l = 0.f;
#pragma unroll
        for (int cc = 0; cc < 8; ++cc) l += q[n][cc] * kf[cc][px];
        dsum[n] += __expf(l);
      }
    }
  }
  __shared__ float red[256];
#pragma unroll
  for (int n = 0; n < 4; ++n) {
    red[tid] = dsum[n];
    __syncthreads();
    for (int st = 128; st > 0; st >>= 1) {
      if (tid < st) red[tid] += red[tid + st];
      __syncthreads();
    }
    if (tid == 0) dpart[(b * 32 + n * 8 + e) * 64 + tile] = red[0];
    __syncthreads();
  }
}

// ---------------------------------------------------------------------------
// K4: mid[b,cc,s] = sum_e (sum_n exp(l)/denom) * v[b,e,cc,s]  (bf16 k,v)
__global__ __launch_bounds__(256) void k4_attend(
    const bf16* __restrict__ kvbuf, const float* __restrict__ qn,
    const float* __restrict__ dpart, float* __restrict__ mid) {
  const int b = blockIdx.y;
  const int tid = threadIdx.x;
  __shared__ float qnl[256];
  __shared__ float rdl[32];
  qnl[tid] = qn[b * 256 + tid];
  if (tid < 32) {
    float s = 0.f;
    for (int t = 0; t < 64; ++t) s += dpart[(b * 32 + tid) * 64 + t];
    rdl[tid] = 1.f / s;
  }
  __syncthreads();
  const bf16* kb = kvbuf + (size_t)(b * 64) * HW_;
  const bf16* vb = kvbuf + (size_t)(128 + b * 64) * HW_;
  float* mb = mid + (size_t)b * 8 * HW_;
  const int s = (blockIdx.x * 256 + tid) * 4;
  float macc[8][4];
#pragma unroll
  for (int cc = 0; cc < 8; ++cc)
#pragma unroll
    for (int px = 0; px < 4; ++px) macc[cc][px] = 0.f;
#pragma unroll
  for (int e = 0; e < 8; ++e) {
    float kf[8][4];
#pragma unroll
    for (int cc = 0; cc < 8; ++cc) {
      union { ushort4 v; bf16 h[4]; } r;
      r.v = *reinterpret_cast<const ushort4*>(kb + (size_t)(e * 8 + cc) * HW_ + s);
#pragma unroll
      for (int px = 0; px < 4; ++px) kf[cc][px] = __bfloat162float(r.h[px]);
    }
    float wsum[4] = {0.f, 0.f, 0.f, 0.f};
#pragma unroll
    for (int n = 0; n < 4; ++n) {
      const float rd = rdl[n * 8 + e];
#pragma unroll
      for (int px = 0; px < 4; ++px) {
        float l = 0.f;
#pragma unroll
        for (int cc = 0; cc < 8; ++cc) l += qnl[n * 64 + e * 8 + cc] * kf[cc][px];
        wsum[px] += __expf(l) * rd;
      }
    }
#pragma unroll
    for (int cc = 0; cc < 8; ++cc) {
      union { ushort4 v; bf16 h[4]; } r;
      r.v = *reinterpret_cast<const ushort4*>(vb + (size_t)(e * 8 + cc) * HW_ + s);
#pragma unroll
      for (int px = 0; px < 4; ++px)
        macc[cc][px] += wsum[px] * __bfloat162float(r.h[px]);
    }
  }
#pragma unroll
  for (int cc = 0; cc < 8; ++cc)
    *reinterpret_cast<float4*>(mb + (size_t)cc * HW_ + s) =
        make_float4(macc[cc][0], macc[cc][1], macc[cc][2], macc[cc][3]);
}

// ---------------------------------------------------------------------------
// K5: grouped 3x3 (8->64, groups=8) + exact GELU + 1x1 (64->64).
__global__ __launch_bounds__(256) void k5_cross(
    const float* __restrict__ mid, const float* __restrict__ cc1_w,
    const float* __restrict__ cc1_b, const float* __restrict__ cc2_w,
    const float* __restrict__ cc2_b, float* __restrict__ out) {
  const int tid = threadIdx.x;
  const int c0 = blockIdx.x * 128;
  const int r0 = blockIdx.y * 2;
  const int b = blockIdx.z;
  __shared__ float midl[8 * 4 * 132];   // [ch][4 rows][132], rows r0-1..r0+2
  __shared__ bf16 gs[64 * 256];         // [oo][px]
  __shared__ float w2t[4096];           // [oo][p] = cc2_w[p][oo]
  __shared__ float w1l[576];
  __shared__ float b1l[64], b2l[64];
  // stage mid tile (coalesced along cols)
  for (int idx = tid; idx < 8 * 4 * 130; idx += 256) {
    const int ch = idx / 520;
    const int rem = idx % 520;
    const int dr = rem / 130, lc = rem % 130;
    const int gr = r0 - 1 + dr, gc = c0 - 1 + lc;
    float v = 0.f;
    if (gr >= 0 && gr < H_ && gc >= 0 && gc < W_)
      v = mid[(size_t)(b * 8 + ch) * HW_ + (size_t)gr * W_ + gc];
    midl[(ch * 4 + dr) * 132 + lc] = v;
  }
  // stage w2 transposed; lanes vary p -> stride-1 LDS writes (no conflicts)
  for (int idx = tid; idx < 4096; idx += 256) {
    const int p = idx & 63, oo = idx >> 6;
    w2t[oo * 64 + p] = cc2_w[p * 64 + oo];
  }
  for (int idx = tid; idx < 576; idx += 256) w1l[idx] = cc1_w[idx];
  if (tid < 64) { b1l[tid] = cc1_b[tid]; b2l[tid] = cc2_b[tid]; }
  __syncthreads();

  const int ty = tid >> 5, tx = tid & 31;
  // ---- phase 1: grouped 3x3 + GELU -> gs (bf16) ----
  {
    const int rl = tx >> 4;            // local output row 0/1
    const int cb = (tx & 15) * 8;      // local col base
    float m[3][10];
#pragma unroll
    for (int dr = 0; dr < 3; ++dr)
#pragma unroll
      for (int t = 0; t < 10; ++t)
        m[dr][t] = midl[(ty * 4 + rl + dr) * 132 + cb + t];
    const int pxb = rl * 128 + cb;
#pragma unroll
    for (int j = 0; j < 8; ++j) {
      const int oo = ty * 8 + j;
      float w[9];
#pragma unroll
      for (int t = 0; t < 9; ++t) w[t] = w1l[oo * 9 + t];
      const float bb = b1l[oo];
      union { int4 v; bf16 h[8]; } gv;
#pragma unroll
      for (int i = 0; i < 8; ++i) {
        float a = bb;
#pragma unroll
        for (int dr = 0; dr < 3; ++dr)
#pragma unroll
          for (int dc = 0; dc < 3; ++dc)
            a += w[dr * 3 + dc] * m[dr][i + dc];
        a = 0.5f * a * (1.f + erff(a * 0.70710678118654752f));
        gv.h[i] = __float2bfloat16(a);
      }
      *reinterpret_cast<int4*>(&gs[oo * 256 + pxb]) = gv.v;
    }
  }
  __syncthreads();
  // ---- phase 2: out[p][px] = b2[p] + sum_oo w2[p][oo] * g[oo][px] ----
  const int p8 = ty * 8;
  const int px8 = tx * 8;
  float acc[8][8];
#pragma unroll
  for (int j = 0; j < 8; ++j)
#pragma unroll
    for (int i = 0; i < 8; ++i) acc[j][i] = 0.f;
#pragma unroll 8
  for (int k = 0; k < 64; ++k) {
    const float4 wv0 = *reinterpret_cast<const float4*>(&w2t[k * 64 + p8]);
    const float4 wv1 = *reinterpret_cast<const float4*>(&w2t[k * 64 + p8 + 4]);
    const float wr[8] = {wv0.x, wv0.y, wv0.z, wv0.w, wv1.x, wv1.y, wv1.z, wv1.w};
    union { int4 v; bf16 h[8]; } gr_;
    gr_.v = *reinterpret_cast<const int4*>(&gs[k * 256 + px8]);
    float gf[8];
#pragma unroll
    for (int i = 0; i < 8; ++i) gf[i] = __bfloat162float(gr_.h[i]);
#pragma unroll
    for (int j = 0; j < 8; ++j)
#pragma unroll
      for (int i = 0; i < 8; ++i) acc[j][i] += wr[j] * gf[i];
  }
  const int grow = r0 + (px8 >> 7);
  const int gcol = c0 + (px8 & 127);
  const size_t sb = (size_t)grow * W_ + gcol;
#pragma unroll
  for (int j = 0; j < 8; ++j) {
    const float bv = b2l[p8 + j];
    float* op = out + (size_t)(b * 64 + p8 + j) * HW_ + sb;
    *reinterpret_cast<float4*>(op) =
        make_float4(acc[j][0] + bv, acc[j][1] + bv, acc[j][2] + bv, acc[j][3] + bv);
    *reinterpret_cast<float4*>(op + 4) =
        make_float4(acc[j][4] + bv, acc[j][5] + bv, acc[j][6] + bv, acc[j][7] + bv);
  }
}

// ---------------------------------------------------------------------------
extern "C" void kernel_launch(void* const* d_in, const int* in_sizes, int n_in,
                              void* d_out, int out_size, void* d_ws, size_t ws_size,
                              hipStream_t stream) {
  const float* x        = (const float*)d_in[0];
  const float* metainfo = (const float*)d_in[1];
  const float* Wq       = (const float*)d_in[2];
  const float* bq       = (const float*)d_in[3];
  const float* temps    = (const float*)d_in[4];
  const float* kv_w     = (const float*)d_in[5];
  const float* kv_b     = (const float*)d_in[6];
  const float* dw_w     = (const float*)d_in[7];
  const float* dw_b     = (const float*)d_in[8];
  const float* cc1_w    = (const float*)d_in[9];
  const float* cc1_b    = (const float*)d_in[10];
  const float* cc2_w    = (const float*)d_in[11];
  const float* cc2_b    = (const float*)d_in[12];
  float* out = (float*)d_out;

  // ws layout (float offsets): kv1 bf16 occupies [0, 33554432) float-equiv.
  float* ws      = (float*)d_ws;
  bf16*  kv1     = (bf16*)d_ws;           // 2*128*HW bf16 = 134.2 MB
  float* mid     = ws + 33554432;         // 2*8*HW fp32   = 16.8 MB
  float* small_  = ws + 37748736;
  float* ssqpart = small_;                // 2*64*16 = 2048
  float* rnorm   = small_ + 2560;         // 128
  float* qn      = small_ + 2688;         // 512
  float* dpart   = small_ + 3200;         // 64*64 = 4096

  // k (bf16) and v (bf16) live in d_out until K5 overwrites it with fp32 out.
  bf16* kvout = (bf16*)d_out;             // [k: 2*64*HW][v: 2*64*HW] bf16

  k1a_conv1x1<<<4096, 256, 0, stream>>>(x, kv_w, kv_b, kv1);
  k1b_dw<<<dim3(16, 32, 2), 256, 0, stream>>>(kv1, dw_w, dw_b, kvout, ssqpart);
  k2_finalize<<<1, 256, 0, stream>>>(ssqpart, temps, metainfo, Wq, bq,
                                     rnorm, qn);
  k3_denom<<<dim3(64, 8, 2), 256, 0, stream>>>(kvout, qn, dpart);
  k4_attend<<<dim3(256, 2), 256, 0, stream>>>(kvout, qn, dpart, mid);
  k5_cross<<<dim3(4, 256, 2), 256, 0, stream>>>(mid, cc1_w, cc1_b, cc2_w,
                                                cc2_b, out);
}

// Round 8
// 313.037 us; speedup vs baseline: 4.4895x; 1.1576x over previous
//
#include <hip/hip_runtime.h>
#include <hip/hip_bf16.h>

#define B_    2
#define H_    512
#define W_    512
#define HW_   262144   // 512*512
#define EPSV  1e-12f

typedef __hip_bfloat16 bf16;
typedef __fp16 h16x8 __attribute__((ext_vector_type(8)));
typedef float f32x4 __attribute__((ext_vector_type(4)));

// ---------------------------------------------------------------------------
// K1a: 1x1 conv as f16 MFMA GEMM. kv1[b][o][s] (bf16) = sum_i W[o][i]*x[i][s]+b
__global__ __launch_bounds__(256) void k1a_conv1x1(
    const float* __restrict__ x, const float* __restrict__ kv_w,
    const float* __restrict__ kv_b, bf16* __restrict__ kv1) {
  const int tid = threadIdx.x;
  const int p0 = blockIdx.x * 128;     // global pixel in [0, 2*HW)
  const int b  = p0 >> 18;
  const int s0 = p0 & (HW_ - 1);
  __shared__ __fp16 Wl[8 * 128 * 8];   // [kg][o][e]  16 KB
  __shared__ __fp16 Xl[8 * 128 * 8];   // [kg][px][e] 16 KB

  // ---- stage W: thread t -> o = t>>1, k-half = t&1 (32 k's) ----
  {
    const int o = tid >> 1, half = tid & 1;
    const float* wp = kv_w + o * 64 + half * 32;
#pragma unroll
    for (int j = 0; j < 4; ++j) {
      const float4 a = *reinterpret_cast<const float4*>(wp + j * 8);
      const float4 c = *reinterpret_cast<const float4*>(wp + j * 8 + 4);
      h16x8 h;
      h[0] = (__fp16)a.x; h[1] = (__fp16)a.y; h[2] = (__fp16)a.z; h[3] = (__fp16)a.w;
      h[4] = (__fp16)c.x; h[5] = (__fp16)c.y; h[6] = (__fp16)c.z; h[7] = (__fp16)c.w;
      *reinterpret_cast<h16x8*>(&Wl[((half * 4 + j) * 128 + o) * 8]) = h;
    }
  }
  // ---- stage x transposed via registers: px = t&127, kg-half = t>>7 ----
  {
    const int px = tid & 127, kgh = tid >> 7;
    const float* xp = x + (size_t)b * 64 * HW_ + s0 + px;
#pragma unroll
    for (int j = 0; j < 4; ++j) {
      const int kg = kgh * 4 + j;
      h16x8 h;
#pragma unroll
      for (int e = 0; e < 8; ++e)
        h[e] = (__fp16)xp[(size_t)(kg * 8 + e) * HW_];
      *reinterpret_cast<h16x8*>(&Xl[(kg * 128 + px) * 8]) = h;
    }
  }
  __syncthreads();

  // ---- MFMA: wave wv covers M-half (wv&1)*64, N-half (wv>>1)*64 ----
  const int wv = tid >> 6, lane = tid & 63;
  const int m0 = (wv & 1) * 64, n0 = (wv >> 1) * 64;
  const int lr = lane & 15, lg = lane >> 4;
  f32x4 acc[4][4];
#pragma unroll
  for (int mt = 0; mt < 4; ++mt)
#pragma unroll
    for (int nt = 0; nt < 4; ++nt) acc[mt][nt] = (f32x4){0.f, 0.f, 0.f, 0.f};
#pragma unroll
  for (int ks = 0; ks < 2; ++ks) {
    h16x8 af[4], bfr[4];
#pragma unroll
    for (int mt = 0; mt < 4; ++mt)
      af[mt] = *reinterpret_cast<const h16x8*>(
          &Wl[((ks * 4 + lg) * 128 + m0 + mt * 16 + lr) * 8]);
#pragma unroll
    for (int nt = 0; nt < 4; ++nt)
      bfr[nt] = *reinterpret_cast<const h16x8*>(
          &Xl[((ks * 4 + lg) * 128 + n0 + nt * 16 + lr) * 8]);
#pragma unroll
    for (int mt = 0; mt < 4; ++mt)
#pragma unroll
      for (int nt = 0; nt < 4; ++nt)
        acc[mt][nt] = __builtin_amdgcn_mfma_f32_16x16x32_f16(
            af[mt], bfr[nt], acc[mt][nt], 0, 0, 0);
  }
  // ---- epilogue: C/D layout col=lane&15 (px), row=(lane>>4)*4+r (o) ----
  bf16* dst = kv1 + (size_t)b * 128 * HW_ + s0;
#pragma unroll
  for (int mt = 0; mt < 4; ++mt) {
#pragma unroll
    for (int r = 0; r < 4; ++r) {
      const int o = m0 + mt * 16 + lg * 4 + r;
      const float bv = kv_b[o];
      bf16* op = dst + (size_t)o * HW_;
#pragma unroll
      for (int nt = 0; nt < 4; ++nt)
        op[n0 + nt * 16 + lr] = __float2bfloat16(acc[mt][nt][r] + bv);
    }
  }
}

// ---------------------------------------------------------------------------
// K1b: depthwise 3x3 (pad=1) on bf16 kv1 -> bf16 k||v (in d_out), fp32 math.
__global__ __launch_bounds__(256) void k1b_dw(
    const bf16* __restrict__ kv1, const float* __restrict__ dw_w,
    const float* __restrict__ dw_b, bf16* __restrict__ kvout,
    float* __restrict__ ssqpart) {
  const int tid = threadIdx.x;
  const int cchunk = tid & 63;            // 64 col-chunks of 8
  const int ch_sub = tid >> 6;            // 4 channels per block
  const int rs = blockIdx.x;              // 16 row strips of 32
  const int chgrp = blockIdx.y;           // 32
  const int b = blockIdx.z;
  const int ch = chgrp * 4 + ch_sub;
  const int c0 = cchunk * 8;
  const int r0 = rs * 32;
  const bf16* src = kv1 + (size_t)(b * 128 + ch) * HW_;
  const bool is_k = (ch < 64);
  const size_t obase = is_k ? (size_t)(b * 64 + ch) * HW_
                            : (size_t)(128 + b * 64 + (ch - 64)) * HW_;
  bf16* dst = kvout + obase;
  float dwr[9];
#pragma unroll
  for (int t = 0; t < 9; ++t) dwr[t] = dw_w[ch * 9 + t];
  const float bd = dw_b[ch];

  float a0[10], a1[10], a2[10];
  auto loadrow = [&](int gr, float* a) {
    if (gr < 0 || gr >= H_) {
#pragma unroll
      for (int t = 0; t < 10; ++t) a[t] = 0.f;
      return;
    }
    const bf16* rp = src + (size_t)gr * W_ + c0;
    union { int4 v; bf16 h[8]; } raw;
    raw.v = *reinterpret_cast<const int4*>(rp);
#pragma unroll
    for (int t = 0; t < 8; ++t) a[t + 1] = __bfloat162float(raw.h[t]);
    a[0] = (c0 > 0) ? __bfloat162float(rp[-1]) : 0.f;
    a[9] = (c0 < 504) ? __bfloat162float(rp[8]) : 0.f;
  };
  loadrow(r0 - 1, a0);
  loadrow(r0, a1);
  float sq = 0.f;
#pragma unroll 4
  for (int rr = 0; rr < 32; ++rr) {
    loadrow(r0 + rr + 1, a2);
    union { int4 v; bf16 h[8]; } ou;
#pragma unroll
    for (int j = 0; j < 8; ++j) {
      const float ov = bd
          + dwr[0] * a0[j] + dwr[1] * a0[j + 1] + dwr[2] * a0[j + 2]
          + dwr[3] * a1[j] + dwr[4] * a1[j + 1] + dwr[5] * a1[j + 2]
          + dwr[6] * a2[j] + dwr[7] * a2[j + 1] + dwr[8] * a2[j + 2];
      sq += ov * ov;
      ou.h[j] = __float2bfloat16(ov);
    }
    *reinterpret_cast<int4*>(dst + (size_t)(r0 + rr) * W_ + c0) = ou.v;
#pragma unroll
    for (int t = 0; t < 10; ++t) { a0[t] = a1[t]; a1[t] = a2[t]; }
  }
  // wave reduction of sq over the 64 col-chunk lanes (same ch per wave)
#pragma unroll
  for (int off = 32; off > 0; off >>= 1) sq += __shfl_down(sq, off, 64);
  if (is_k && cchunk == 0)
    ssqpart[(size_t)(b * 64 + ch) * 16 + rs] = sq;
}

// ---------------------------------------------------------------------------
// K2: reduce sumsq partials -> rnorm; qn = sign(q)*rnorm*temps (k0 folded in)
__global__ __launch_bounds__(256) void k2_finalize(
    const float* __restrict__ ssqpart, const float* __restrict__ temps,
    const float* __restrict__ metainfo, const float* __restrict__ Wq,
    const float* __restrict__ bq, float* __restrict__ rnorm,
    float* __restrict__ qn) {
  const int tid = threadIdx.x;
  if (tid < 128) {
    const int b = tid >> 6, c = tid & 63;
    float s = 0.f;
    for (int p = 0; p < 16; ++p) s += ssqpart[(size_t)(b * 64 + c) * 16 + p];
    rnorm[tid] = 1.f / fmaxf(sqrtf(s), EPSV);
  }
  __syncthreads();
  for (int idx = tid; idx < 512; idx += 256) {
    const int b = idx >> 8, n = (idx >> 6) & 3, d = idx & 63;
    float acc = bq[n * 64 + d];
#pragma unroll
    for (int m = 0; m < 4; ++m)
      acc += metainfo[(b * 4 + n) * 4 + m] * Wq[(n * 64 + d) * 4 + m];
    const float sgn = acc / fmaxf(fabsf(acc), EPSV);
    qn[idx] = sgn * rnorm[b * 64 + d] * temps[n * 8 + (d >> 3)];
  }
}

// ---------------------------------------------------------------------------
// K3: softmax denominators from bf16 k. 8 px/thread, 16B k loads.
__global__ __launch_bounds__(256) void k3_denom(
    const bf16* __restrict__ kbuf, const float* __restrict__ qn,
    float* __restrict__ dpart) {
  const int tile = blockIdx.x, e = blockIdx.y, b = blockIdx.z;
  const int tid = threadIdx.x;
  float q[4][8];
#pragma unroll
  for (int n = 0; n < 4; ++n)
#pragma unroll
    for (int cc = 0; cc < 8; ++cc)
      q[n][cc] = qn[b * 256 + n * 64 + e * 8 + cc];
  const bf16* kb = kbuf + (size_t)(b * 64 + e * 8) * HW_;
  float dsum[4] = {0.f, 0.f, 0.f, 0.f};
  const int sbase = tile * 4096;
#pragma unroll
  for (int it = 0; it < 2; ++it) {
    const int s = sbase + (it * 256 + tid) * 8;
    float kf[8][8];
#pragma unroll
    for (int cc = 0; cc < 8; ++cc) {
      union { int4 v; bf16 h[8]; } r;
      r.v = *reinterpret_cast<const int4*>(kb + (size_t)cc * HW_ + s);
#pragma unroll
      for (int j = 0; j < 8; ++j) kf[cc][j] = __bfloat162float(r.h[j]);
    }
#pragma unroll
    for (int n = 0; n < 4; ++n) {
#pragma unroll
      for (int px = 0; px < 8; ++px) {
        float l = 0.f;
#pragma unroll
        for (int cc = 0; cc < 8; ++cc) l += q[n][cc] * kf[cc][px];
        dsum[n] += __expf(l);
      }
    }
  }
  __shared__ float red[256];
#pragma unroll
  for (int n = 0; n < 4; ++n) {
    red[tid] = dsum[n];
    __syncthreads();
    for (int st = 128; st > 0; st >>= 1) {
      if (tid < st) red[tid] += red[tid + st];
      __syncthreads();
    }
    if (tid == 0) dpart[(b * 32 + n * 8 + e) * 64 + tile] = red[0];
    __syncthreads();
  }
}

// ---------------------------------------------------------------------------
// K4: mid[b,cc,s] = sum_e (sum_n exp(l)/denom) * v[b,e,cc,s]  (bf16 k,v)
__global__ __launch_bounds__(256) void k4_attend(
    const bf16* __restrict__ kvbuf, const float* __restrict__ qn,
    const float* __restrict__ dpart, float* __restrict__ mid) {
  const int b = blockIdx.y;
  const int tid = threadIdx.x;
  __shared__ float qnl[256];
  __shared__ float rdl[32];
  qnl[tid] = qn[b * 256 + tid];
  if (tid < 32) {
    float s = 0.f;
    for (int t = 0; t < 64; ++t) s += dpart[(b * 32 + tid) * 64 + t];
    rdl[tid] = 1.f / s;
  }
  __syncthreads();
  const bf16* kb = kvbuf + (size_t)(b * 64) * HW_;
  const bf16* vb = kvbuf + (size_t)(128 + b * 64) * HW_;
  float* mb = mid + (size_t)b * 8 * HW_;
  const int s = (blockIdx.x * 256 + tid) * 4;
  float macc[8][4];
#pragma unroll
  for (int cc = 0; cc < 8; ++cc)
#pragma unroll
    for (int px = 0; px < 4; ++px) macc[cc][px] = 0.f;
#pragma unroll
  for (int e = 0; e < 8; ++e) {
    float kf[8][4];
#pragma unroll
    for (int cc = 0; cc < 8; ++cc) {
      union { ushort4 v; bf16 h[4]; } r;
      r.v = *reinterpret_cast<const ushort4*>(kb + (size_t)(e * 8 + cc) * HW_ + s);
#pragma unroll
      for (int px = 0; px < 4; ++px) kf[cc][px] = __bfloat162float(r.h[px]);
    }
    float wsum[4] = {0.f, 0.f, 0.f, 0.f};
#pragma unroll
    for (int n = 0; n < 4; ++n) {
      const float rd = rdl[n * 8 + e];
#pragma unroll
      for (int px = 0; px < 4; ++px) {
        float l = 0.f;
#pragma unroll
        for (int cc = 0; cc < 8; ++cc) l += qnl[n * 64 + e * 8 + cc] * kf[cc][px];
        wsum[px] += __expf(l) * rd;
      }
    }
#pragma unroll
    for (int cc = 0; cc < 8; ++cc) {
      union { ushort4 v; bf16 h[4]; } r;
      r.v = *reinterpret_cast<const ushort4*>(vb + (size_t)(e * 8 + cc) * HW_ + s);
#pragma unroll
      for (int px = 0; px < 4; ++px)
        macc[cc][px] += wsum[px] * __bfloat162float(r.h[px]);
    }
  }
#pragma unroll
  for (int cc = 0; cc < 8; ++cc)
    *reinterpret_cast<float4*>(mb + (size_t)cc * HW_ + s) =
        make_float4(macc[cc][0], macc[cc][1], macc[cc][2], macc[cc][3]);
}

// ---------------------------------------------------------------------------
// K5: grouped 3x3 (8->64, groups=8) + exact GELU + 1x1 (64->64) via f16 MFMA.
// Block = 2 rows x 128 cols (256 px) x all 64 outputs.
// Phase 1: thread (ty,tx) computes GELU(cc1) for oo chunk ty (8 ch) x 8 px,
//          packs h16x8 per px -> gs[px][ooc] (XOR-swizzled, conflict-free).
// Phase 2: 4 waves, each M=64 (p) x N=64 (px), K=64 -> 32 MFMA.
__global__ __launch_bounds__(256) void k5_cross(
    const float* __restrict__ mid, const float* __restrict__ cc1_w,
    const float* __restrict__ cc1_b, const float* __restrict__ cc2_w,
    const float* __restrict__ cc2_b, float* __restrict__ out) {
  const int tid = threadIdx.x;
  const int c0 = blockIdx.x * 128;
  const int r0 = blockIdx.y * 2;
  const int b = blockIdx.z;
  __shared__ float midl[8 * 4 * 132];   // [ch][4 rows][132]  16.5 KB
  __shared__ __fp16 gs[256 * 64];       // [px][oo] swizzled  32 KB
  __shared__ __fp16 w2s[64 * 64];       // [p][oo] swizzled    8 KB
  __shared__ float w1l[576];
  __shared__ float b1l[64], b2l[64];
  // stage mid tile (coalesced along cols)
  for (int idx = tid; idx < 8 * 4 * 130; idx += 256) {
    const int ch = idx / 520;
    const int rem = idx % 520;
    const int dr = rem / 130, lc = rem % 130;
    const int gr = r0 - 1 + dr, gc = c0 - 1 + lc;
    float v = 0.f;
    if (gr >= 0 && gr < H_ && gc >= 0 && gc < W_)
      v = mid[(size_t)(b * 8 + ch) * HW_ + (size_t)gr * W_ + gc];
    midl[(ch * 4 + dr) * 132 + lc] = v;
  }
  // stage w2 as f16 chunks: w2s[p][ooc^(p&7)] = cc2_w[p][ooc*8..+8]
#pragma unroll
  for (int rr = 0; rr < 2; ++rr) {
    const int idx = tid + rr * 256;
    const int p = idx >> 3, ooc = idx & 7;
    const float4 a = *reinterpret_cast<const float4*>(cc2_w + p * 64 + ooc * 8);
    const float4 c = *reinterpret_cast<const float4*>(cc2_w + p * 64 + ooc * 8 + 4);
    h16x8 h;
    h[0] = (__fp16)a.x; h[1] = (__fp16)a.y; h[2] = (__fp16)a.z; h[3] = (__fp16)a.w;
    h[4] = (__fp16)c.x; h[5] = (__fp16)c.y; h[6] = (__fp16)c.z; h[7] = (__fp16)c.w;
    *reinterpret_cast<h16x8*>(&w2s[p * 64 + ((ooc ^ (p & 7)) << 3)]) = h;
  }
  for (int idx = tid; idx < 576; idx += 256) w1l[idx] = cc1_w[idx];
  if (tid < 64) { b1l[tid] = cc1_b[tid]; b2l[tid] = cc2_b[tid]; }
  __syncthreads();

  // ---- phase 1: grouped 3x3 + GELU -> gs (f16, swizzled) ----
  {
    const int ty = tid >> 5, tx = tid & 31;
    const int rl = tx >> 4;            // local output row 0/1
    const int cb = (tx & 15) * 8;      // local col base
    float m[3][10];
#pragma unroll
    for (int dr = 0; dr < 3; ++dr)
#pragma unroll
      for (int t = 0; t < 10; ++t)
        m[dr][t] = midl[(ty * 4 + rl + dr) * 132 + cb + t];
    const int pxb = rl * 128 + cb;
#pragma unroll
    for (int hh = 0; hh < 2; ++hh) {
      float g[8][4];
#pragma unroll
      for (int j = 0; j < 8; ++j) {
        const int oo = ty * 8 + j;
        float w[9];
#pragma unroll
        for (int t = 0; t < 9; ++t) w[t] = w1l[oo * 9 + t];
        const float bb = b1l[oo];
#pragma unroll
        for (int i2 = 0; i2 < 4; ++i2) {
          const int i = hh * 4 + i2;
          float a = bb;
#pragma unroll
          for (int dr = 0; dr < 3; ++dr)
#pragma unroll
            for (int dc = 0; dc < 3; ++dc)
              a += w[dr * 3 + dc] * m[dr][i + dc];
          g[j][i2] = 0.5f * a * (1.f + erff(a * 0.70710678118654752f));
        }
      }
#pragma unroll
      for (int i2 = 0; i2 < 4; ++i2) {
        const int px = pxb + hh * 4 + i2;
        const int swz = (px ^ (px >> 3)) & 7;
        h16x8 h;
#pragma unroll
        for (int j = 0; j < 8; ++j) h[j] = (__fp16)g[j][i2];
        *reinterpret_cast<h16x8*>(&gs[px * 64 + ((ty ^ swz) << 3)]) = h;
      }
    }
  }
  __syncthreads();

  // ---- phase 2: out[p][px] = b2[p] + sum_oo w2[p][oo]*g[oo][px] via MFMA ----
  const int wv = tid >> 6, lane = tid & 63;
  const int n0 = wv * 64;
  const int lr = lane & 15, lg = lane >> 4;
  f32x4 acc[4][4];
#pragma unroll
  for (int mt = 0; mt < 4; ++mt)
#pragma unroll
    for (int nt = 0; nt < 4; ++nt) acc[mt][nt] = (f32x4){0.f, 0.f, 0.f, 0.f};
#pragma unroll
  for (int ks = 0; ks < 2; ++ks) {
    const int ooc = ks * 4 + lg;
    h16x8 af[4], bfr[4];
#pragma unroll
    for (int mt = 0; mt < 4; ++mt) {
      const int p = mt * 16 + lr;
      af[mt] = *reinterpret_cast<const h16x8*>(
          &w2s[p * 64 + ((ooc ^ (p & 7)) << 3)]);
    }
#pragma unroll
    for (int nt = 0; nt < 4; ++nt) {
      const int px = n0 + nt * 16 + lr;
      const int swz = (px ^ (px >> 3)) & 7;
      bfr[nt] = *reinterpret_cast<const h16x8*>(
          &gs[px * 64 + ((ooc ^ swz) << 3)]);
    }
#pragma unroll
    for (int mt = 0; mt < 4; ++mt)
#pragma unroll
      for (int nt = 0; nt < 4; ++nt)
        acc[mt][nt] = __builtin_amdgcn_mfma_f32_16x16x32_f16(
            af[mt], bfr[nt], acc[mt][nt], 0, 0, 0);
  }
  // ---- epilogue: C col = px (lane&15), row = p ((lane>>4)*4+r) ----
#pragma unroll
  for (int mt = 0; mt < 4; ++mt) {
#pragma unroll
    for (int r = 0; r < 4; ++r) {
      const int p = mt * 16 + lg * 4 + r;
      const float bv = b2l[p];
      float* op = out + (size_t)(b * 64 + p) * HW_;
#pragma unroll
      for (int nt = 0; nt < 4; ++nt) {
        const int px = n0 + nt * 16 + lr;
        const int grow = r0 + (px >> 7), gcol = c0 + (px & 127);
        op[(size_t)grow * W_ + gcol] = acc[mt][nt][r] + bv;
      }
    }
  }
}

// ---------------------------------------------------------------------------
extern "C" void kernel_launch(void* const* d_in, const int* in_sizes, int n_in,
                              void* d_out, int out_size, void* d_ws, size_t ws_size,
                              hipStream_t stream) {
  const float* x        = (const float*)d_in[0];
  const float* metainfo = (const float*)d_in[1];
  const float* Wq       = (const float*)d_in[2];
  const float* bq       = (const float*)d_in[3];
  const float* temps    = (const float*)d_in[4];
  const float* kv_w     = (const float*)d_in[5];
  const float* kv_b     = (const float*)d_in[6];
  const float* dw_w     = (const float*)d_in[7];
  const float* dw_b     = (const float*)d_in[8];
  const float* cc1_w    = (const float*)d_in[9];
  const float* cc1_b    = (const float*)d_in[10];
  const float* cc2_w    = (const float*)d_in[11];
  const float* cc2_b    = (const float*)d_in[12];
  float* out = (float*)d_out;

  // ws layout (float offsets): kv1 bf16 occupies [0, 33554432) float-equiv.
  float* ws      = (float*)d_ws;
  bf16*  kv1     = (bf16*)d_ws;           // 2*128*HW bf16 = 134.2 MB
  float* mid     = ws + 33554432;         // 2*8*HW fp32   = 16.8 MB
  float* small_  = ws + 37748736;
  float* ssqpart = small_;                // 2*64*16 = 2048
  float* rnorm   = small_ + 2560;         // 128
  float* qn      = small_ + 2688;         // 512
  float* dpart   = small_ + 3200;         // 64*64 = 4096

  // k (bf16) and v (bf16) live in d_out until K5 overwrites it with fp32 out.
  bf16* kvout = (bf16*)d_out;             // [k: 2*64*HW][v: 2*64*HW] bf16

  k1a_conv1x1<<<4096, 256, 0, stream>>>(x, kv_w, kv_b, kv1);
  k1b_dw<<<dim3(16, 32, 2), 256, 0, stream>>>(kv1, dw_w, dw_b, kvout, ssqpart);
  k2_finalize<<<1, 256, 0, stream>>>(ssqpart, temps, metainfo, Wq, bq,
                                     rnorm, qn);
  k3_denom<<<dim3(64, 8, 2), 256, 0, stream>>>(kvout, qn, dpart);
  k4_attend<<<dim3(256, 2), 256, 0, stream>>>(kvout, qn, dpart, mid);
  k5_cross<<<dim3(4, 256, 2), 256, 0, stream>>>(mid, cc1_w, cc1_b, cc2_w,
                                                cc2_b, out);
}

// Round 9
// 297.817 us; speedup vs baseline: 4.7189x; 1.0511x over previous
//
#include <hip/hip_runtime.h>
#include <hip/hip_bf16.h>

#define B_    2
#define H_    512
#define W_    512
#define HW_   262144   // 512*512
#define EPSV  1e-12f

typedef __hip_bfloat16 bf16;
typedef __fp16 h16x8 __attribute__((ext_vector_type(8)));
typedef float f32x4 __attribute__((ext_vector_type(4)));

// ---------------------------------------------------------------------------
// K1a: 1x1 conv as f16 MFMA GEMM. kv1[b][o][s] (bf16) = sum_i W[o][i]*x[i][s]+b
// Block tile: M=128 (all outs) x N=128 px, K=64. 4 waves, each 64x64.
// x staged via float2 loads (512B/wave) into even/odd px LDS buffers.
__global__ __launch_bounds__(256) void k1a_conv1x1(
    const float* __restrict__ x, const float* __restrict__ kv_w,
    const float* __restrict__ kv_b, bf16* __restrict__ kv1) {
  const int tid = threadIdx.x;
  const int p0 = blockIdx.x * 128;     // global pixel in [0, 2*HW)
  const int b  = p0 >> 18;
  const int s0 = p0 & (HW_ - 1);
  __shared__ __fp16 Wl[8 * 128 * 8];   // [kg][o][e]   16 KB
  __shared__ __fp16 Xe[8 * 64 * 8];    // [kg][px/2][e] 8 KB (even px)
  __shared__ __fp16 Xo[8 * 64 * 8];    // [kg][px/2][e] 8 KB (odd px)

  // ---- stage W: thread t -> o = t>>1, k-half = t&1 (32 k's) ----
  {
    const int o = tid >> 1, half = tid & 1;
    const float* wp = kv_w + o * 64 + half * 32;
#pragma unroll
    for (int j = 0; j < 4; ++j) {
      const float4 a = *reinterpret_cast<const float4*>(wp + j * 8);
      const float4 c = *reinterpret_cast<const float4*>(wp + j * 8 + 4);
      h16x8 h;
      h[0] = (__fp16)a.x; h[1] = (__fp16)a.y; h[2] = (__fp16)a.z; h[3] = (__fp16)a.w;
      h[4] = (__fp16)c.x; h[5] = (__fp16)c.y; h[6] = (__fp16)c.z; h[7] = (__fp16)c.w;
      *reinterpret_cast<h16x8*>(&Wl[((half * 4 + j) * 128 + o) * 8]) = h;
    }
  }
  // ---- stage x: thread t -> px pair (2m, 2m+1), kg quarter (2 kgs) ----
  {
    const int m = tid & 63, kgq = tid >> 6;
    const float* xp = x + (size_t)b * 64 * HW_ + s0 + m * 2;
#pragma unroll
    for (int kk = 0; kk < 2; ++kk) {
      const int kg = kgq * 2 + kk;
      h16x8 he, ho;
#pragma unroll
      for (int e = 0; e < 8; ++e) {
        const float2 v =
            *reinterpret_cast<const float2*>(xp + (size_t)(kg * 8 + e) * HW_);
        he[e] = (__fp16)v.x; ho[e] = (__fp16)v.y;
      }
      *reinterpret_cast<h16x8*>(&Xe[(kg * 64 + m) * 8]) = he;
      *reinterpret_cast<h16x8*>(&Xo[(kg * 64 + m) * 8]) = ho;
    }
  }
  __syncthreads();

  // ---- MFMA: wave wv covers M-half (wv&1)*64, N-half (wv>>1)*64 ----
  const int wv = tid >> 6, lane = tid & 63;
  const int m0 = (wv & 1) * 64, n0 = (wv >> 1) * 64;
  const int lr = lane & 15, lg = lane >> 4;
  const __fp16* xb2 = (lr & 1) ? Xo : Xe;   // adjacent lanes pair-read: free
  f32x4 acc[4][4];
#pragma unroll
  for (int mt = 0; mt < 4; ++mt)
#pragma unroll
    for (int nt = 0; nt < 4; ++nt) acc[mt][nt] = (f32x4){0.f, 0.f, 0.f, 0.f};
#pragma unroll
  for (int ks = 0; ks < 2; ++ks) {
    h16x8 af[4], bfr[4];
#pragma unroll
    for (int mt = 0; mt < 4; ++mt)
      af[mt] = *reinterpret_cast<const h16x8*>(
          &Wl[((ks * 4 + lg) * 128 + m0 + mt * 16 + lr) * 8]);
#pragma unroll
    for (int nt = 0; nt < 4; ++nt)
      bfr[nt] = *reinterpret_cast<const h16x8*>(
          &xb2[((ks * 4 + lg) * 64 + (n0 >> 1) + nt * 8 + (lr >> 1)) * 8]);
#pragma unroll
    for (int mt = 0; mt < 4; ++mt)
#pragma unroll
      for (int nt = 0; nt < 4; ++nt)
        acc[mt][nt] = __builtin_amdgcn_mfma_f32_16x16x32_f16(
            af[mt], bfr[nt], acc[mt][nt], 0, 0, 0);
  }
  // ---- epilogue: C/D layout col=lane&15 (px), row=(lane>>4)*4+r (o) ----
  bf16* dst = kv1 + (size_t)b * 128 * HW_ + s0;
#pragma unroll
  for (int mt = 0; mt < 4; ++mt) {
#pragma unroll
    for (int r = 0; r < 4; ++r) {
      const int o = m0 + mt * 16 + lg * 4 + r;
      const float bv = kv_b[o];
      bf16* op = dst + (size_t)o * HW_;
#pragma unroll
      for (int nt = 0; nt < 4; ++nt)
        op[n0 + nt * 16 + lr] = __float2bfloat16(acc[mt][nt][r] + bv);
    }
  }
}

// ---------------------------------------------------------------------------
// K1b: depthwise 3x3 (pad=1) on bf16 kv1 -> bf16 k||v (in d_out), fp32 math.
// One wave spans a full 512-col row of one channel; halo cols come from
// neighbor lanes via shuffle (no misaligned scalar loads).
__global__ __launch_bounds__(256) void k1b_dw(
    const bf16* __restrict__ kv1, const float* __restrict__ dw_w,
    const float* __restrict__ dw_b, bf16* __restrict__ kvout,
    float* __restrict__ ssqpart) {
  const int tid = threadIdx.x;
  const int cchunk = tid & 63;            // 64 col-chunks of 8
  const int ch_sub = tid >> 6;            // 4 channels per block
  const int rs = blockIdx.x;              // 16 row strips of 32
  const int chgrp = blockIdx.y;           // 32
  const int b = blockIdx.z;
  const int ch = chgrp * 4 + ch_sub;
  const int c0 = cchunk * 8;
  const int r0 = rs * 32;
  const bf16* src = kv1 + (size_t)(b * 128 + ch) * HW_;
  const bool is_k = (ch < 64);
  const size_t obase = is_k ? (size_t)(b * 64 + ch) * HW_
                            : (size_t)(128 + b * 64 + (ch - 64)) * HW_;
  bf16* dst = kvout + obase;
  float dwr[9];
#pragma unroll
  for (int t = 0; t < 9; ++t) dwr[t] = dw_w[ch * 9 + t];
  const float bd = dw_b[ch];

  float a0[10], a1[10], a2[10];
  auto loadrow = [&](int gr, float* a) {
    if (gr < 0 || gr >= H_) {
#pragma unroll
      for (int t = 0; t < 10; ++t) a[t] = 0.f;
      return;
    }
    union { int4 v; bf16 h[8]; } raw;
    raw.v = *reinterpret_cast<const int4*>(src + (size_t)gr * W_ + c0);
#pragma unroll
    for (int t = 0; t < 8; ++t) a[t + 1] = __bfloat162float(raw.h[t]);
    const float left = __shfl_up(a[8], 1);     // lane-1's col c0-1
    const float right = __shfl_down(a[1], 1);  // lane+1's col c0+8
    a[0] = (cchunk == 0) ? 0.f : left;
    a[9] = (cchunk == 63) ? 0.f : right;
  };
  loadrow(r0 - 1, a0);
  loadrow(r0, a1);
  float sq = 0.f;
#pragma unroll 4
  for (int rr = 0; rr < 32; ++rr) {
    loadrow(r0 + rr + 1, a2);
    union { int4 v; bf16 h[8]; } ou;
#pragma unroll
    for (int j = 0; j < 8; ++j) {
      const float ov = bd
          + dwr[0] * a0[j] + dwr[1] * a0[j + 1] + dwr[2] * a0[j + 2]
          + dwr[3] * a1[j] + dwr[4] * a1[j + 1] + dwr[5] * a1[j + 2]
          + dwr[6] * a2[j] + dwr[7] * a2[j + 1] + dwr[8] * a2[j + 2];
      sq += ov * ov;
      ou.h[j] = __float2bfloat16(ov);
    }
    *reinterpret_cast<int4*>(dst + (size_t)(r0 + rr) * W_ + c0) = ou.v;
#pragma unroll
    for (int t = 0; t < 10; ++t) { a0[t] = a1[t]; a1[t] = a2[t]; }
  }
  // wave reduction of sq over the 64 col-chunk lanes (same ch per wave)
#pragma unroll
  for (int off = 32; off > 0; off >>= 1) sq += __shfl_down(sq, off, 64);
  if (is_k && cchunk == 0)
    ssqpart[(size_t)(b * 64 + ch) * 16 + rs] = sq;
}

// ---------------------------------------------------------------------------
// K2: reduce sumsq partials -> rnorm; qn = sign(q)*rnorm*temps (k0 folded in)
__global__ __launch_bounds__(256) void k2_finalize(
    const float* __restrict__ ssqpart, const float* __restrict__ temps,
    const float* __restrict__ metainfo, const float* __restrict__ Wq,
    const float* __restrict__ bq, float* __restrict__ rnorm,
    float* __restrict__ qn) {
  const int tid = threadIdx.x;
  if (tid < 128) {
    const int b = tid >> 6, c = tid & 63;
    float s = 0.f;
    for (int p = 0; p < 16; ++p) s += ssqpart[(size_t)(b * 64 + c) * 16 + p];
    rnorm[tid] = 1.f / fmaxf(sqrtf(s), EPSV);
  }
  __syncthreads();
  for (int idx = tid; idx < 512; idx += 256) {
    const int b = idx >> 8, n = (idx >> 6) & 3, d = idx & 63;
    float acc = bq[n * 64 + d];
#pragma unroll
    for (int m = 0; m < 4; ++m)
      acc += metainfo[(b * 4 + n) * 4 + m] * Wq[(n * 64 + d) * 4 + m];
    const float sgn = acc / fmaxf(fabsf(acc), EPSV);
    qn[idx] = sgn * rnorm[b * 64 + d] * temps[n * 8 + (d >> 3)];
  }
}

// ---------------------------------------------------------------------------
// K3: softmax denominators from bf16 k. 8 px/thread, 16B k loads.
__global__ __launch_bounds__(256) void k3_denom(
    const bf16* __restrict__ kbuf, const float* __restrict__ qn,
    float* __restrict__ dpart) {
  const int tile = blockIdx.x, e = blockIdx.y, b = blockIdx.z;
  const int tid = threadIdx.x;
  float q[4][8];
#pragma unroll
  for (int n = 0; n < 4; ++n)
#pragma unroll
    for (int cc = 0; cc < 8; ++cc)
      q[n][cc] = qn[b * 256 + n * 64 + e * 8 + cc];
  const bf16* kb = kbuf + (size_t)(b * 64 + e * 8) * HW_;
  float dsum[4] = {0.f, 0.f, 0.f, 0.f};
  const int sbase = tile * 4096;
#pragma unroll
  for (int it = 0; it < 2; ++it) {
    const int s = sbase + (it * 256 + tid) * 8;
    float kf[8][8];
#pragma unroll
    for (int cc = 0; cc < 8; ++cc) {
      union { int4 v; bf16 h[8]; } r;
      r.v = *reinterpret_cast<const int4*>(kb + (size_t)cc * HW_ + s);
#pragma unroll
      for (int j = 0; j < 8; ++j) kf[cc][j] = __bfloat162float(r.h[j]);
    }
#pragma unroll
    for (int n = 0; n < 4; ++n) {
#pragma unroll
      for (int px = 0; px < 8; ++px) {
        float l = 0.f;
#pragma unroll
        for (int cc = 0; cc < 8; ++cc) l += q[n][cc] * kf[cc][px];
        dsum[n] += __expf(l);
      }
    }
  }
  __shared__ float red[256];
#pragma unroll
  for (int n = 0; n < 4; ++n) {
    red[tid] = dsum[n];
    __syncthreads();
    for (int st = 128; st > 0; st >>= 1) {
      if (tid < st) red[tid] += red[tid + st];
      __syncthreads();
    }
    if (tid == 0) dpart[(b * 32 + n * 8 + e) * 64 + tile] = red[0];
    __syncthreads();
  }
}

// ---------------------------------------------------------------------------
// K4: mid[b,cc,s] = sum_e (sum_n exp(l)/denom) * v[b,e,cc,s]  (bf16 k,v)
__global__ __launch_bounds__(256) void k4_attend(
    const bf16* __restrict__ kvbuf, const float* __restrict__ qn,
    const float* __restrict__ dpart, float* __restrict__ mid) {
  const int b = blockIdx.y;
  const int tid = threadIdx.x;
  __shared__ float qnl[256];
  __shared__ float rdl[32];
  qnl[tid] = qn[b * 256 + tid];
  if (tid < 32) {
    float s = 0.f;
    for (int t = 0; t < 64; ++t) s += dpart[(b * 32 + tid) * 64 + t];
    rdl[tid] = 1.f / s;
  }
  __syncthreads();
  const bf16* kb = kvbuf + (size_t)(b * 64) * HW_;
  const bf16* vb = kvbuf + (size_t)(128 + b * 64) * HW_;
  float* mb = mid + (size_t)b * 8 * HW_;
  const int s = (blockIdx.x * 256 + tid) * 4;
  float macc[8][4];
#pragma unroll
  for (int cc = 0; cc < 8; ++cc)
#pragma unroll
    for (int px = 0; px < 4; ++px) macc[cc][px] = 0.f;
#pragma unroll
  for (int e = 0; e < 8; ++e) {
    float kf[8][4];
#pragma unroll
    for (int cc = 0; cc < 8; ++cc) {
      union { ushort4 v; bf16 h[4]; } r;
      r.v = *reinterpret_cast<const ushort4*>(kb + (size_t)(e * 8 + cc) * HW_ + s);
#pragma unroll
      for (int px = 0; px < 4; ++px) kf[cc][px] = __bfloat162float(r.h[px]);
    }
    float wsum[4] = {0.f, 0.f, 0.f, 0.f};
#pragma unroll
    for (int n = 0; n < 4; ++n) {
      const float rd = rdl[n * 8 + e];
#pragma unroll
      for (int px = 0; px < 4; ++px) {
        float l = 0.f;
#pragma unroll
        for (int cc = 0; cc < 8; ++cc) l += qnl[n * 64 + e * 8 + cc] * kf[cc][px];
        wsum[px] += __expf(l) * rd;
      }
    }
#pragma unroll
    for (int cc = 0; cc < 8; ++cc) {
      union { ushort4 v; bf16 h[4]; } r;
      r.v = *reinterpret_cast<const ushort4*>(vb + (size_t)(e * 8 + cc) * HW_ + s);
#pragma unroll
      for (int px = 0; px < 4; ++px)
        macc[cc][px] += wsum[px] * __bfloat162float(r.h[px]);
    }
  }
#pragma unroll
  for (int cc = 0; cc < 8; ++cc)
    *reinterpret_cast<float4*>(mb + (size_t)cc * HW_ + s) =
        make_float4(macc[cc][0], macc[cc][1], macc[cc][2], macc[cc][3]);
}

// ---------------------------------------------------------------------------
// K5: grouped 3x3 (8->64, groups=8) + exact GELU + 1x1 (64->64) via f16 MFMA.
__global__ __launch_bounds__(256) void k5_cross(
    const float* __restrict__ mid, const float* __restrict__ cc1_w,
    const float* __restrict__ cc1_b, const float* __restrict__ cc2_w,
    const float* __restrict__ cc2_b, float* __restrict__ out) {
  const int tid = threadIdx.x;
  const int c0 = blockIdx.x * 128;
  const int r0 = blockIdx.y * 2;
  const int b = blockIdx.z;
  __shared__ float midl[8 * 4 * 132];   // [ch][4 rows][132]  16.5 KB
  __shared__ __fp16 gs[256 * 64];       // [px][oo] swizzled  32 KB
  __shared__ __fp16 w2s[64 * 64];       // [p][oo] swizzled    8 KB
  __shared__ float w1l[576];
  __shared__ float b1l[64], b2l[64];
  // stage mid tile (coalesced along cols)
  for (int idx = tid; idx < 8 * 4 * 130; idx += 256) {
    const int ch = idx / 520;
    const int rem = idx % 520;
    const int dr = rem / 130, lc = rem % 130;
    const int gr = r0 - 1 + dr, gc = c0 - 1 + lc;
    float v = 0.f;
    if (gr >= 0 && gr < H_ && gc >= 0 && gc < W_)
      v = mid[(size_t)(b * 8 + ch) * HW_ + (size_t)gr * W_ + gc];
    midl[(ch * 4 + dr) * 132 + lc] = v;
  }
  // stage w2 as f16 chunks: w2s[p][ooc^(p&7)] = cc2_w[p][ooc*8..+8]
#pragma unroll
  for (int rr = 0; rr < 2; ++rr) {
    const int idx = tid + rr * 256;
    const int p = idx >> 3, ooc = idx & 7;
    const float4 a = *reinterpret_cast<const float4*>(cc2_w + p * 64 + ooc * 8);
    const float4 c = *reinterpret_cast<const float4*>(cc2_w + p * 64 + ooc * 8 + 4);
    h16x8 h;
    h[0] = (__fp16)a.x; h[1] = (__fp16)a.y; h[2] = (__fp16)a.z; h[3] = (__fp16)a.w;
    h[4] = (__fp16)c.x; h[5] = (__fp16)c.y; h[6] = (__fp16)c.z; h[7] = (__fp16)c.w;
    *reinterpret_cast<h16x8*>(&w2s[p * 64 + ((ooc ^ (p & 7)) << 3)]) = h;
  }
  for (int idx = tid; idx < 576; idx += 256) w1l[idx] = cc1_w[idx];
  if (tid < 64) { b1l[tid] = cc1_b[tid]; b2l[tid] = cc2_b[tid]; }
  __syncthreads();

  // ---- phase 1: grouped 3x3 + GELU -> gs (f16, swizzled) ----
  {
    const int ty = tid >> 5, tx = tid & 31;
    const int rl = tx >> 4;            // local output row 0/1
    const int cb = (tx & 15) * 8;      // local col base
    float m[3][10];
#pragma unroll
    for (int dr = 0; dr < 3; ++dr)
#pragma unroll
      for (int t = 0; t < 10; ++t)
        m[dr][t] = midl[(ty * 4 + rl + dr) * 132 + cb + t];
    const int pxb = rl * 128 + cb;
#pragma unroll
    for (int hh = 0; hh < 2; ++hh) {
      float g[8][4];
#pragma unroll
      for (int j = 0; j < 8; ++j) {
        const int oo = ty * 8 + j;
        float w[9];
#pragma unroll
        for (int t = 0; t < 9; ++t) w[t] = w1l[oo * 9 + t];
        const float bb = b1l[oo];
#pragma unroll
        for (int i2 = 0; i2 < 4; ++i2) {
          const int i = hh * 4 + i2;
          float a = bb;
#pragma unroll
          for (int dr = 0; dr < 3; ++dr)
#pragma unroll
            for (int dc = 0; dc < 3; ++dc)
              a += w[dr * 3 + dc] * m[dr][i + dc];
          g[j][i2] = 0.5f * a * (1.f + erff(a * 0.70710678118654752f));
        }
      }
#pragma unroll
      for (int i2 = 0; i2 < 4; ++i2) {
        const int px = pxb + hh * 4 + i2;
        const int swz = (px ^ (px >> 3)) & 7;
        h16x8 h;
#pragma unroll
        for (int j = 0; j < 8; ++j) h[j] = (__fp16)g[j][i2];
        *reinterpret_cast<h16x8*>(&gs[px * 64 + ((ty ^ swz) << 3)]) = h;
      }
    }
  }
  __syncthreads();

  // ---- phase 2: out[p][px] = b2[p] + sum_oo w2[p][oo]*g[oo][px] via MFMA ----
  const int wv = tid >> 6, lane = tid & 63;
  const int n0 = wv * 64;
  const int lr = lane & 15, lg = lane >> 4;
  f32x4 acc[4][4];
#pragma unroll
  for (int mt = 0; mt < 4; ++mt)
#pragma unroll
    for (int nt = 0; nt < 4; ++nt) acc[mt][nt] = (f32x4){0.f, 0.f, 0.f, 0.f};
#pragma unroll
  for (int ks = 0; ks < 2; ++ks) {
    const int ooc = ks * 4 + lg;
    h16x8 af[4], bfr[4];
#pragma unroll
    for (int mt = 0; mt < 4; ++mt) {
      const int p = mt * 16 + lr;
      af[mt] = *reinterpret_cast<const h16x8*>(
          &w2s[p * 64 + ((ooc ^ (p & 7)) << 3)]);
    }
#pragma unroll
    for (int nt = 0; nt < 4; ++nt) {
      const int px = n0 + nt * 16 + lr;
      const int swz = (px ^ (px >> 3)) & 7;
      bfr[nt] = *reinterpret_cast<const h16x8*>(
          &gs[px * 64 + ((ooc ^ swz) << 3)]);
    }
#pragma unroll
    for (int mt = 0; mt < 4; ++mt)
#pragma unroll
      for (int nt = 0; nt < 4; ++nt)
        acc[mt][nt] = __builtin_amdgcn_mfma_f32_16x16x32_f16(
            af[mt], bfr[nt], acc[mt][nt], 0, 0, 0);
  }
  // ---- epilogue: C col = px (lane&15), row = p ((lane>>4)*4+r) ----
#pragma unroll
  for (int mt = 0; mt < 4; ++mt) {
#pragma unroll
    for (int r = 0; r < 4; ++r) {
      const int p = mt * 16 + lg * 4 + r;
      const float bv = b2l[p];
      float* op = out + (size_t)(b * 64 + p) * HW_;
#pragma unroll
      for (int nt = 0; nt < 4; ++nt) {
        const int px = n0 + nt * 16 + lr;
        const int grow = r0 + (px >> 7), gcol = c0 + (px & 127);
        op[(size_t)grow * W_ + gcol] = acc[mt][nt][r] + bv;
      }
    }
  }
}

// ---------------------------------------------------------------------------
extern "C" void kernel_launch(void* const* d_in, const int* in_sizes, int n_in,
                              void* d_out, int out_size, void* d_ws, size_t ws_size,
                              hipStream_t stream) {
  const float* x        = (const float*)d_in[0];
  const float* metainfo = (const float*)d_in[1];
  const float* Wq       = (const float*)d_in[2];
  const float* bq       = (const float*)d_in[3];
  const float* temps    = (const float*)d_in[4];
  const float* kv_w     = (const float*)d_in[5];
  const float* kv_b     = (const float*)d_in[6];
  const float* dw_w     = (const float*)d_in[7];
  const float* dw_b     = (const float*)d_in[8];
  const float* cc1_w    = (const float*)d_in[9];
  const float* cc1_b    = (const float*)d_in[10];
  const float* cc2_w    = (const float*)d_in[11];
  const float* cc2_b    = (const float*)d_in[12];
  float* out = (float*)d_out;

  // ws layout (float offsets): kv1 bf16 occupies [0, 33554432) float-equiv.
  float* ws      = (float*)d_ws;
  bf16*  kv1     = (bf16*)d_ws;           // 2*128*HW bf16 = 134.2 MB
  float* mid     = ws + 33554432;         // 2*8*HW fp32   = 16.8 MB
  float* small_  = ws + 37748736;
  float* ssqpart = small_;                // 2*64*16 = 2048
  float* rnorm   = small_ + 2560;         // 128
  float* qn      = small_ + 2688;         // 512
  float* dpart   = small_ + 3200;         // 64*64 = 4096

  // k (bf16) and v (bf16) live in d_out until K5 overwrites it with fp32 out.
  bf16* kvout = (bf16*)d_out;             // [k: 2*64*HW][v: 2*64*HW] bf16

  k1a_conv1x1<<<4096, 256, 0, stream>>>(x, kv_w, kv_b, kv1);
  k1b_dw<<<dim3(16, 32, 2), 256, 0, stream>>>(kv1, dw_w, dw_b, kvout, ssqpart);
  k2_finalize<<<1, 256, 0, stream>>>(ssqpart, temps, metainfo, Wq, bq,
                                     rnorm, qn);
  k3_denom<<<dim3(64, 8, 2), 256, 0, stream>>>(kvout, qn, dpart);
  k4_attend<<<dim3(256, 2), 256, 0, stream>>>(kvout, qn, dpart, mid);
  k5_cross<<<dim3(4, 256, 2), 256, 0, stream>>>(mid, cc1_w, cc1_b, cc2_w,
                                                cc2_b, out);
}

// Round 10
// 278.277 us; speedup vs baseline: 5.0503x; 1.0702x over previous
//
#include <hip/hip_runtime.h>
#include <hip/hip_bf16.h>

#define B_    2
#define H_    512
#define W_    512
#define HW_   262144   // 512*512
#define EPSV  1e-12f

typedef __hip_bfloat16 bf16;
typedef __fp16 h16x8 __attribute__((ext_vector_type(8)));
typedef float f32x4 __attribute__((ext_vector_type(4)));

// ---------------------------------------------------------------------------
// K1a: 1x1 conv as f16 MFMA GEMM, 4 tiles per block, software-pipelined.
// kv1[b][o][s] (bf16) = sum_i W[o][i]*x[i][s]+b. Block = 4 x (128o x 128px).
// W staged once per block; x loads for tile t+1 issued before computing t.
__global__ __launch_bounds__(256) void k1a_conv1x1(
    const float* __restrict__ x, const float* __restrict__ kv_w,
    const float* __restrict__ kv_b, bf16* __restrict__ kv1) {
  const int tid = threadIdx.x;
  const int base = blockIdx.x * 512;   // 4 tiles of 128 px, same b
  const int b  = base >> 18;
  const int sb = base & (HW_ - 1);
  __shared__ __fp16 Wl[8 * 128 * 8];     // [kg][o][e]        16 KB
  __shared__ __fp16 Xe[2][8 * 64 * 8];   // [buf][kg][px/2][e] 16 KB
  __shared__ __fp16 Xo[2][8 * 64 * 8];   // [buf][kg][px/2][e] 16 KB

  // ---- stage W once: thread t -> o = t>>1, k-half = t&1 (32 k's) ----
  {
    const int o = tid >> 1, half = tid & 1;
    const float* wp = kv_w + o * 64 + half * 32;
#pragma unroll
    for (int j = 0; j < 4; ++j) {
      const float4 a = *reinterpret_cast<const float4*>(wp + j * 8);
      const float4 c = *reinterpret_cast<const float4*>(wp + j * 8 + 4);
      h16x8 h;
      h[0] = (__fp16)a.x; h[1] = (__fp16)a.y; h[2] = (__fp16)a.z; h[3] = (__fp16)a.w;
      h[4] = (__fp16)c.x; h[5] = (__fp16)c.y; h[6] = (__fp16)c.z; h[7] = (__fp16)c.w;
      *reinterpret_cast<h16x8*>(&Wl[((half * 4 + j) * 128 + o) * 8]) = h;
    }
  }
  // ---- x staging geometry: thread -> px pair (2m,2m+1), 16 planes ----
  const int m = tid & 63, kgq = tid >> 6;
  const float* xbase = x + (size_t)b * 64 * HW_ + sb + m * 2;

  float2 cur[16], nxt[16];
#pragma unroll
  for (int u = 0; u < 16; ++u)
    cur[u] = *reinterpret_cast<const float2*>(xbase + (size_t)(kgq * 16 + u) * HW_);

  const int wv = tid >> 6, lane = tid & 63;
  const int m0 = (wv & 1) * 64, n0 = (wv >> 1) * 64;
  const int lr = lane & 15, lg = lane >> 4;

#pragma unroll
  for (int t = 0; t < 4; ++t) {
    // ---- prefetch next tile's x into registers (issue only) ----
    if (t < 3) {
#pragma unroll
      for (int u = 0; u < 16; ++u)
        nxt[u] = *reinterpret_cast<const float2*>(
            xbase + (t + 1) * 128 + (size_t)(kgq * 16 + u) * HW_);
    }
    // ---- pack cur -> LDS buf[t&1] ----
#pragma unroll
    for (int kk = 0; kk < 2; ++kk) {
      h16x8 he, ho;
#pragma unroll
      for (int e = 0; e < 8; ++e) {
        he[e] = (__fp16)cur[kk * 8 + e].x;
        ho[e] = (__fp16)cur[kk * 8 + e].y;
      }
      const int kg = kgq * 2 + kk;
      *reinterpret_cast<h16x8*>(&Xe[t & 1][(kg * 64 + m) * 8]) = he;
      *reinterpret_cast<h16x8*>(&Xo[t & 1][(kg * 64 + m) * 8]) = ho;
    }
    __syncthreads();
    // ---- MFMA: wave covers M-half (wv&1)*64, N-half (wv>>1)*64 ----
    const __fp16* xb2 = (lr & 1) ? Xo[t & 1] : Xe[t & 1];
    f32x4 acc[4][4];
#pragma unroll
    for (int mt = 0; mt < 4; ++mt)
#pragma unroll
      for (int nt = 0; nt < 4; ++nt) acc[mt][nt] = (f32x4){0.f, 0.f, 0.f, 0.f};
#pragma unroll
    for (int ks = 0; ks < 2; ++ks) {
      h16x8 af[4], bfr[4];
#pragma unroll
      for (int mt = 0; mt < 4; ++mt)
        af[mt] = *reinterpret_cast<const h16x8*>(
            &Wl[((ks * 4 + lg) * 128 + m0 + mt * 16 + lr) * 8]);
#pragma unroll
      for (int nt = 0; nt < 4; ++nt)
        bfr[nt] = *reinterpret_cast<const h16x8*>(
            &xb2[((ks * 4 + lg) * 64 + (n0 >> 1) + nt * 8 + (lr >> 1)) * 8]);
#pragma unroll
      for (int mt = 0; mt < 4; ++mt)
#pragma unroll
        for (int nt = 0; nt < 4; ++nt)
          acc[mt][nt] = __builtin_amdgcn_mfma_f32_16x16x32_f16(
              af[mt], bfr[nt], acc[mt][nt], 0, 0, 0);
    }
    // ---- epilogue tile t: C col=lane&15 (px), row=(lane>>4)*4+r (o) ----
    bf16* dst = kv1 + (size_t)b * 128 * HW_ + sb + t * 128;
#pragma unroll
    for (int mt = 0; mt < 4; ++mt) {
#pragma unroll
      for (int r = 0; r < 4; ++r) {
        const int o = m0 + mt * 16 + lg * 4 + r;
        const float bv = kv_b[o];
        bf16* op = dst + (size_t)o * HW_;
#pragma unroll
        for (int nt = 0; nt < 4; ++nt)
          op[n0 + nt * 16 + lr] = __float2bfloat16(acc[mt][nt][r] + bv);
      }
    }
    // ---- rotate prefetch registers ----
    if (t < 3) {
#pragma unroll
      for (int u = 0; u < 16; ++u) cur[u] = nxt[u];
    }
  }
}

// ---------------------------------------------------------------------------
// K1b: depthwise 3x3 (pad=1) on bf16 kv1 -> bf16 k||v (in d_out), fp32 math.
// Halo cols via wave shuffle.
__global__ __launch_bounds__(256) void k1b_dw(
    const bf16* __restrict__ kv1, const float* __restrict__ dw_w,
    const float* __restrict__ dw_b, bf16* __restrict__ kvout,
    float* __restrict__ ssqpart) {
  const int tid = threadIdx.x;
  const int cchunk = tid & 63;            // 64 col-chunks of 8
  const int ch_sub = tid >> 6;            // 4 channels per block
  const int rs = blockIdx.x;              // 16 row strips of 32
  const int chgrp = blockIdx.y;           // 32
  const int b = blockIdx.z;
  const int ch = chgrp * 4 + ch_sub;
  const int c0 = cchunk * 8;
  const int r0 = rs * 32;
  const bf16* src = kv1 + (size_t)(b * 128 + ch) * HW_;
  const bool is_k = (ch < 64);
  const size_t obase = is_k ? (size_t)(b * 64 + ch) * HW_
                            : (size_t)(128 + b * 64 + (ch - 64)) * HW_;
  bf16* dst = kvout + obase;
  float dwr[9];
#pragma unroll
  for (int t = 0; t < 9; ++t) dwr[t] = dw_w[ch * 9 + t];
  const float bd = dw_b[ch];

  float a0[10], a1[10], a2[10];
  auto loadrow = [&](int gr, float* a) {
    if (gr < 0 || gr >= H_) {
#pragma unroll
      for (int t = 0; t < 10; ++t) a[t] = 0.f;
      return;
    }
    union { int4 v; bf16 h[8]; } raw;
    raw.v = *reinterpret_cast<const int4*>(src + (size_t)gr * W_ + c0);
#pragma unroll
    for (int t = 0; t < 8; ++t) a[t + 1] = __bfloat162float(raw.h[t]);
    const float left = __shfl_up(a[8], 1);     // lane-1's col c0-1
    const float right = __shfl_down(a[1], 1);  // lane+1's col c0+8
    a[0] = (cchunk == 0) ? 0.f : left;
    a[9] = (cchunk == 63) ? 0.f : right;
  };
  loadrow(r0 - 1, a0);
  loadrow(r0, a1);
  float sq = 0.f;
#pragma unroll 4
  for (int rr = 0; rr < 32; ++rr) {
    loadrow(r0 + rr + 1, a2);
    union { int4 v; bf16 h[8]; } ou;
#pragma unroll
    for (int j = 0; j < 8; ++j) {
      const float ov = bd
          + dwr[0] * a0[j] + dwr[1] * a0[j + 1] + dwr[2] * a0[j + 2]
          + dwr[3] * a1[j] + dwr[4] * a1[j + 1] + dwr[5] * a1[j + 2]
          + dwr[6] * a2[j] + dwr[7] * a2[j + 1] + dwr[8] * a2[j + 2];
      sq += ov * ov;
      ou.h[j] = __float2bfloat16(ov);
    }
    *reinterpret_cast<int4*>(dst + (size_t)(r0 + rr) * W_ + c0) = ou.v;
#pragma unroll
    for (int t = 0; t < 10; ++t) { a0[t] = a1[t]; a1[t] = a2[t]; }
  }
  // wave reduction of sq over the 64 col-chunk lanes (same ch per wave)
#pragma unroll
  for (int off = 32; off > 0; off >>= 1) sq += __shfl_down(sq, off, 64);
  if (is_k && cchunk == 0)
    ssqpart[(size_t)(b * 64 + ch) * 16 + rs] = sq;
}

// ---------------------------------------------------------------------------
// K2: reduce sumsq partials -> rnorm; qn = sign(q)*rnorm*temps (k0 folded in)
__global__ __launch_bounds__(256) void k2_finalize(
    const float* __restrict__ ssqpart, const float* __restrict__ temps,
    const float* __restrict__ metainfo, const float* __restrict__ Wq,
    const float* __restrict__ bq, float* __restrict__ rnorm,
    float* __restrict__ qn) {
  const int tid = threadIdx.x;
  if (tid < 128) {
    const int b = tid >> 6, c = tid & 63;
    float s = 0.f;
    for (int p = 0; p < 16; ++p) s += ssqpart[(size_t)(b * 64 + c) * 16 + p];
    rnorm[tid] = 1.f / fmaxf(sqrtf(s), EPSV);
  }
  __syncthreads();
  for (int idx = tid; idx < 512; idx += 256) {
    const int b = idx >> 8, n = (idx >> 6) & 3, d = idx & 63;
    float acc = bq[n * 64 + d];
#pragma unroll
    for (int m = 0; m < 4; ++m)
      acc += metainfo[(b * 4 + n) * 4 + m] * Wq[(n * 64 + d) * 4 + m];
    const float sgn = acc / fmaxf(fabsf(acc), EPSV);
    qn[idx] = sgn * rnorm[b * 64 + d] * temps[n * 8 + (d >> 3)];
  }
}

// ---------------------------------------------------------------------------
// K3: softmax denominators from bf16 k. 8 px/thread, 16B k loads.
__global__ __launch_bounds__(256) void k3_denom(
    const bf16* __restrict__ kbuf, const float* __restrict__ qn,
    float* __restrict__ dpart) {
  const int tile = blockIdx.x, e = blockIdx.y, b = blockIdx.z;
  const int tid = threadIdx.x;
  float q[4][8];
#pragma unroll
  for (int n = 0; n < 4; ++n)
#pragma unroll
    for (int cc = 0; cc < 8; ++cc)
      q[n][cc] = qn[b * 256 + n * 64 + e * 8 + cc];
  const bf16* kb = kbuf + (size_t)(b * 64 + e * 8) * HW_;
  float dsum[4] = {0.f, 0.f, 0.f, 0.f};
  const int sbase = tile * 4096;
#pragma unroll
  for (int it = 0; it < 2; ++it) {
    const int s = sbase + (it * 256 + tid) * 8;
    float kf[8][8];
#pragma unroll
    for (int cc = 0; cc < 8; ++cc) {
      union { int4 v; bf16 h[8]; } r;
      r.v = *reinterpret_cast<const int4*>(kb + (size_t)cc * HW_ + s);
#pragma unroll
      for (int j = 0; j < 8; ++j) kf[cc][j] = __bfloat162float(r.h[j]);
    }
#pragma unroll
    for (int n = 0; n < 4; ++n) {
#pragma unroll
      for (int px = 0; px < 8; ++px) {
        float l = 0.f;
#pragma unroll
        for (int cc = 0; cc < 8; ++cc) l += q[n][cc] * kf[cc][px];
        dsum[n] += __expf(l);
      }
    }
  }
  __shared__ float red[256];
#pragma unroll
  for (int n = 0; n < 4; ++n) {
    red[tid] = dsum[n];
    __syncthreads();
    for (int st = 128; st > 0; st >>= 1) {
      if (tid < st) red[tid] += red[tid + st];
      __syncthreads();
    }
    if (tid == 0) dpart[(b * 32 + n * 8 + e) * 64 + tile] = red[0];
    __syncthreads();
  }
}

// ---------------------------------------------------------------------------
// K4: mid[b,cc,s] = sum_e (sum_n exp(l)/denom) * v[b,e,cc,s]  (bf16 k,v)
__global__ __launch_bounds__(256) void k4_attend(
    const bf16* __restrict__ kvbuf, const float* __restrict__ qn,
    const float* __restrict__ dpart, float* __restrict__ mid) {
  const int b = blockIdx.y;
  const int tid = threadIdx.x;
  __shared__ float qnl[256];
  __shared__ float rdl[32];
  qnl[tid] = qn[b * 256 + tid];
  if (tid < 32) {
    float s = 0.f;
    for (int t = 0; t < 64; ++t) s += dpart[(b * 32 + tid) * 64 + t];
    rdl[tid] = 1.f / s;
  }
  __syncthreads();
  const bf16* kb = kvbuf + (size_t)(b * 64) * HW_;
  const bf16* vb = kvbuf + (size_t)(128 + b * 64) * HW_;
  float* mb = mid + (size_t)b * 8 * HW_;
  const int s = (blockIdx.x * 256 + tid) * 4;
  float macc[8][4];
#pragma unroll
  for (int cc = 0; cc < 8; ++cc)
#pragma unroll
    for (int px = 0; px < 4; ++px) macc[cc][px] = 0.f;
#pragma unroll
  for (int e = 0; e < 8; ++e) {
    float kf[8][4];
#pragma unroll
    for (int cc = 0; cc < 8; ++cc) {
      union { ushort4 v; bf16 h[4]; } r;
      r.v = *reinterpret_cast<const ushort4*>(kb + (size_t)(e * 8 + cc) * HW_ + s);
#pragma unroll
      for (int px = 0; px < 4; ++px) kf[cc][px] = __bfloat162float(r.h[px]);
    }
    float wsum[4] = {0.f, 0.f, 0.f, 0.f};
#pragma unroll
    for (int n = 0; n < 4; ++n) {
      const float rd = rdl[n * 8 + e];
#pragma unroll
      for (int px = 0; px < 4; ++px) {
        float l = 0.f;
#pragma unroll
        for (int cc = 0; cc < 8; ++cc) l += qnl[n * 64 + e * 8 + cc] * kf[cc][px];
        wsum[px] += __expf(l) * rd;
      }
    }
#pragma unroll
    for (int cc = 0; cc < 8; ++cc) {
      union { ushort4 v; bf16 h[4]; } r;
      r.v = *reinterpret_cast<const ushort4*>(vb + (size_t)(e * 8 + cc) * HW_ + s);
#pragma unroll
      for (int px = 0; px < 4; ++px)
        macc[cc][px] += wsum[px] * __bfloat162float(r.h[px]);
    }
  }
#pragma unroll
  for (int cc = 0; cc < 8; ++cc)
    *reinterpret_cast<float4*>(mb + (size_t)cc * HW_ + s) =
        make_float4(macc[cc][0], macc[cc][1], macc[cc][2], macc[cc][3]);
}

// ---------------------------------------------------------------------------
// K5: grouped 3x3 (8->64, groups=8) + exact GELU + 1x1 (64->64) via f16 MFMA.
__global__ __launch_bounds__(256) void k5_cross(
    const float* __restrict__ mid, const float* __restrict__ cc1_w,
    const float* __restrict__ cc1_b, const float* __restrict__ cc2_w,
    const float* __restrict__ cc2_b, float* __restrict__ out) {
  const int tid = threadIdx.x;
  const int c0 = blockIdx.x * 128;
  const int r0 = blockIdx.y * 2;
  const int b = blockIdx.z;
  __shared__ float midl[8 * 4 * 132];   // [ch][4 rows][132]  16.5 KB
  __shared__ __fp16 gs[256 * 64];       // [px][oo] swizzled  32 KB
  __shared__ __fp16 w2s[64 * 64];       // [p][oo] swizzled    8 KB
  __shared__ float w1l[576];
  __shared__ float b1l[64], b2l[64];
  // stage mid tile (coalesced along cols)
  for (int idx = tid; idx < 8 * 4 * 130; idx += 256) {
    const int ch = idx / 520;
    const int rem = idx % 520;
    const int dr = rem / 130, lc = rem % 130;
    const int gr = r0 - 1 + dr, gc = c0 - 1 + lc;
    float v = 0.f;
    if (gr >= 0 && gr < H_ && gc >= 0 && gc < W_)
      v = mid[(size_t)(b * 8 + ch) * HW_ + (size_t)gr * W_ + gc];
    midl[(ch * 4 + dr) * 132 + lc] = v;
  }
  // stage w2 as f16 chunks: w2s[p][ooc^(p&7)] = cc2_w[p][ooc*8..+8]
#pragma unroll
  for (int rr = 0; rr < 2; ++rr) {
    const int idx = tid + rr * 256;
    const int p = idx >> 3, ooc = idx & 7;
    const float4 a = *reinterpret_cast<const float4*>(cc2_w + p * 64 + ooc * 8);
    const float4 c = *reinterpret_cast<const float4*>(cc2_w + p * 64 + ooc * 8 + 4);
    h16x8 h;
    h[0] = (__fp16)a.x; h[1] = (__fp16)a.y; h[2] = (__fp16)a.z; h[3] = (__fp16)a.w;
    h[4] = (__fp16)c.x; h[5] = (__fp16)c.y; h[6] = (__fp16)c.z; h[7] = (__fp16)c.w;
    *reinterpret_cast<h16x8*>(&w2s[p * 64 + ((ooc ^ (p & 7)) << 3)]) = h;
  }
  for (int idx = tid; idx < 576; idx += 256) w1l[idx] = cc1_w[idx];
  if (tid < 64) { b1l[tid] = cc1_b[tid]; b2l[tid] = cc2_b[tid]; }
  __syncthreads();

  // ---- phase 1: grouped 3x3 + GELU -> gs (f16, swizzled) ----
  {
    const int ty = tid >> 5, tx = tid & 31;
    const int rl = tx >> 4;            // local output row 0/1
    const int cb = (tx & 15) * 8;      // local col base
    float m[3][10];
#pragma unroll
    for (int dr = 0; dr < 3; ++dr)
#pragma unroll
      for (int t = 0; t < 10; ++t)
        m[dr][t] = midl[(ty * 4 + rl + dr) * 132 + cb + t];
    const int pxb = rl * 128 + cb;
#pragma unroll
    for (int hh = 0; hh < 2; ++hh) {
      float g[8][4];
#pragma unroll
      for (int j = 0; j < 8; ++j) {
        const int oo = ty * 8 + j;
        float w[9];
#pragma unroll
        for (int t = 0; t < 9; ++t) w[t] = w1l[oo * 9 + t];
        const float bb = b1l[oo];
#pragma unroll
        for (int i2 = 0; i2 < 4; ++i2) {
          const int i = hh * 4 + i2;
          float a = bb;
#pragma unroll
          for (int dr = 0; dr < 3; ++dr)
#pragma unroll
            for (int dc = 0; dc < 3; ++dc)
              a += w[dr * 3 + dc] * m[dr][i + dc];
          g[j][i2] = 0.5f * a * (1.f + erff(a * 0.70710678118654752f));
        }
      }
#pragma unroll
      for (int i2 = 0; i2 < 4; ++i2) {
        const int px = pxb + hh * 4 + i2;
        const int swz = (px ^ (px >> 3)) & 7;
        h16x8 h;
#pragma unroll
        for (int j = 0; j < 8; ++j) h[j] = (__fp16)g[j][i2];
        *reinterpret_cast<h16x8*>(&gs[px * 64 + ((ty ^ swz) << 3)]) = h;
      }
    }
  }
  __syncthreads();

  // ---- phase 2: out[p][px] = b2[p] + sum_oo w2[p][oo]*g[oo][px] via MFMA ----
  const int wv = tid >> 6, lane = tid & 63;
  const int n0 = wv * 64;
  const int lr = lane & 15, lg = lane >> 4;
  f32x4 acc[4][4];
#pragma unroll
  for (int mt = 0; mt < 4; ++mt)
#pragma unroll
    for (int nt = 0; nt < 4; ++nt) acc[mt][nt] = (f32x4){0.f, 0.f, 0.f, 0.f};
#pragma unroll
  for (int ks = 0; ks < 2; ++ks) {
    const int ooc = ks * 4 + lg;
    h16x8 af[4], bfr[4];
#pragma unroll
    for (int mt = 0; mt < 4; ++mt) {
      const int p = mt * 16 + lr;
      af[mt] = *reinterpret_cast<const h16x8*>(
          &w2s[p * 64 + ((ooc ^ (p & 7)) << 3)]);
    }
#pragma unroll
    for (int nt = 0; nt < 4; ++nt) {
      const int px = n0 + nt * 16 + lr;
      const int swz = (px ^ (px >> 3)) & 7;
      bfr[nt] = *reinterpret_cast<const h16x8*>(
          &gs[px * 64 + ((ooc ^ swz) << 3)]);
    }
#pragma unroll
    for (int mt = 0; mt < 4; ++mt)
#pragma unroll
      for (int nt = 0; nt < 4; ++nt)
        acc[mt][nt] = __builtin_amdgcn_mfma_f32_16x16x32_f16(
            af[mt], bfr[nt], acc[mt][nt], 0, 0, 0);
  }
  // ---- epilogue: C col = px (lane&15), row = p ((lane>>4)*4+r) ----
#pragma unroll
  for (int mt = 0; mt < 4; ++mt) {
#pragma unroll
    for (int r = 0; r < 4; ++r) {
      const int p = mt * 16 + lg * 4 + r;
      const float bv = b2l[p];
      float* op = out + (size_t)(b * 64 + p) * HW_;
#pragma unroll
      for (int nt = 0; nt < 4; ++nt) {
        const int px = n0 + nt * 16 + lr;
        const int grow = r0 + (px >> 7), gcol = c0 + (px & 127);
        op[(size_t)grow * W_ + gcol] = acc[mt][nt][r] + bv;
      }
    }
  }
}

// ---------------------------------------------------------------------------
extern "C" void kernel_launch(void* const* d_in, const int* in_sizes, int n_in,
                              void* d_out, int out_size, void* d_ws, size_t ws_size,
                              hipStream_t stream) {
  const float* x        = (const float*)d_in[0];
  const float* metainfo = (const float*)d_in[1];
  const float* Wq       = (const float*)d_in[2];
  const float* bq       = (const float*)d_in[3];
  const float* temps    = (const float*)d_in[4];
  const float* kv_w     = (const float*)d_in[5];
  const float* kv_b     = (const float*)d_in[6];
  const float* dw_w     = (const float*)d_in[7];
  const float* dw_b     = (const float*)d_in[8];
  const float* cc1_w    = (const float*)d_in[9];
  const float* cc1_b    = (const float*)d_in[10];
  const float* cc2_w    = (const float*)d_in[11];
  const float* cc2_b    = (const float*)d_in[12];
  float* out = (float*)d_out;

  // ws layout (float offsets): kv1 bf16 occupies [0, 33554432) float-equiv.
  float* ws      = (float*)d_ws;
  bf16*  kv1     = (bf16*)d_ws;           // 2*128*HW bf16 = 134.2 MB
  float* mid     = ws + 33554432;         // 2*8*HW fp32   = 16.8 MB
  float* small_  = ws + 37748736;
  float* ssqpart = small_;                // 2*64*16 = 2048
  float* rnorm   = small_ + 2560;         // 128
  float* qn      = small_ + 2688;         // 512
  float* dpart   = small_ + 3200;         // 64*64 = 4096

  // k (bf16) and v (bf16) live in d_out until K5 overwrites it with fp32 out.
  bf16* kvout = (bf16*)d_out;             // [k: 2*64*HW][v: 2*64*HW] bf16

  k1a_conv1x1<<<1024, 256, 0, stream>>>(x, kv_w, kv_b, kv1);
  k1b_dw<<<dim3(16, 32, 2), 256, 0, stream>>>(kv1, dw_w, dw_b, kvout, ssqpart);
  k2_finalize<<<1, 256, 0, stream>>>(ssqpart, temps, metainfo, Wq, bq,
                                     rnorm, qn);
  k3_denom<<<dim3(64, 8, 2), 256, 0, stream>>>(kvout, qn, dpart);
  k4_attend<<<dim3(256, 2), 256, 0, stream>>>(kvout, qn, dpart, mid);
  k5_cross<<<dim3(4, 256, 2), 256, 0, stream>>>(mid, cc1_w, cc1_b, cc2_w,
                                                cc2_b, out);
}

// Round 11
// 267.441 us; speedup vs baseline: 5.2549x; 1.0405x over previous
//
#include <hip/hip_runtime.h>
#include <hip/hip_bf16.h>

#define B_    2
#define H_    512
#define W_    512
#define HW_   262144   // 512*512
#define EPSV  1e-12f

typedef __hip_bfloat16 bf16;
typedef __fp16 h16x8 __attribute__((ext_vector_type(8)));
typedef float f32x4 __attribute__((ext_vector_type(4)));

// ---------------------------------------------------------------------------
// K1a: 1x1 conv as f16 MFMA GEMM, 4 tiles/block, software-pipelined, with
// LDS-bounce epilogue (8 dwordx4 stores/thread/tile instead of 64 scalar
// 2B stores -> VMEM ops per tile 80 -> 24, under the 63 vmcnt cap).
__global__ __launch_bounds__(256) void k1a_conv1x1(
    const float* __restrict__ x, const float* __restrict__ kv_w,
    const float* __restrict__ kv_b, bf16* __restrict__ kv1) {
  const int tid = threadIdx.x;
  const int base = blockIdx.x * 512;   // 4 tiles of 128 px, same b
  const int b  = base >> 18;
  const int sb = base & (HW_ - 1);
  __shared__ __fp16 Wl[8 * 128 * 8];   // [kg][o][e]    16 KB
  __shared__ __fp16 Xe[8 * 64 * 8];    // [kg][px/2][e]  8 KB (even px)
  __shared__ __fp16 Xo[8 * 64 * 8];    // [kg][px/2][e]  8 KB (odd px)
  __shared__ bf16 Bo[128 * 136];       // bounce [o][px], stride 136 = 34 KB

  // ---- stage W once: thread t -> o = t>>1, k-half = t&1 (32 k's) ----
  {
    const int o = tid >> 1, half = tid & 1;
    const float* wp = kv_w + o * 64 + half * 32;
#pragma unroll
    for (int j = 0; j < 4; ++j) {
      const float4 a = *reinterpret_cast<const float4*>(wp + j * 8);
      const float4 c = *reinterpret_cast<const float4*>(wp + j * 8 + 4);
      h16x8 h;
      h[0] = (__fp16)a.x; h[1] = (__fp16)a.y; h[2] = (__fp16)a.z; h[3] = (__fp16)a.w;
      h[4] = (__fp16)c.x; h[5] = (__fp16)c.y; h[6] = (__fp16)c.z; h[7] = (__fp16)c.w;
      *reinterpret_cast<h16x8*>(&Wl[((half * 4 + j) * 128 + o) * 8]) = h;
    }
  }
  // ---- x staging geometry: thread -> px pair (2m,2m+1), 16 planes ----
  const int m = tid & 63, kgq = tid >> 6;
  const float* xbase = x + (size_t)b * 64 * HW_ + sb + m * 2;

  float2 cur[16], nxt[16];
#pragma unroll
  for (int u = 0; u < 16; ++u)
    cur[u] = *reinterpret_cast<const float2*>(xbase + (size_t)(kgq * 16 + u) * HW_);

  const int wv = tid >> 6, lane = tid & 63;
  const int m0 = (wv & 1) * 64, n0 = (wv >> 1) * 64;
  const int lr = lane & 15, lg = lane >> 4;

#pragma unroll
  for (int t = 0; t < 4; ++t) {
    // ---- pack cur -> LDS (single buffer; WAR-safe via bounce barrier) ----
#pragma unroll
    for (int kk = 0; kk < 2; ++kk) {
      h16x8 he, ho;
#pragma unroll
      for (int e = 0; e < 8; ++e) {
        he[e] = (__fp16)cur[kk * 8 + e].x;
        ho[e] = (__fp16)cur[kk * 8 + e].y;
      }
      const int kg = kgq * 2 + kk;
      *reinterpret_cast<h16x8*>(&Xe[(kg * 64 + m) * 8]) = he;
      *reinterpret_cast<h16x8*>(&Xo[(kg * 64 + m) * 8]) = ho;
    }
    __syncthreads();   // barA: pack visible
    // ---- prefetch next tile's x (issues overlap MFMA + epilogue) ----
    if (t < 3) {
#pragma unroll
      for (int u = 0; u < 16; ++u)
        nxt[u] = *reinterpret_cast<const float2*>(
            xbase + (t + 1) * 128 + (size_t)(kgq * 16 + u) * HW_);
    }
    // ---- MFMA: wave covers M-half (wv&1)*64, N-half (wv>>1)*64 ----
    const __fp16* xb2 = (lr & 1) ? Xo : Xe;
    f32x4 acc[4][4];
#pragma unroll
    for (int mt = 0; mt < 4; ++mt)
#pragma unroll
      for (int nt = 0; nt < 4; ++nt) acc[mt][nt] = (f32x4){0.f, 0.f, 0.f, 0.f};
#pragma unroll
    for (int ks = 0; ks < 2; ++ks) {
      h16x8 af[4], bfr[4];
#pragma unroll
      for (int mt = 0; mt < 4; ++mt)
        af[mt] = *reinterpret_cast<const h16x8*>(
            &Wl[((ks * 4 + lg) * 128 + m0 + mt * 16 + lr) * 8]);
#pragma unroll
      for (int nt = 0; nt < 4; ++nt)
        bfr[nt] = *reinterpret_cast<const h16x8*>(
            &xb2[((ks * 4 + lg) * 64 + (n0 >> 1) + nt * 8 + (lr >> 1)) * 8]);
#pragma unroll
      for (int mt = 0; mt < 4; ++mt)
#pragma unroll
        for (int nt = 0; nt < 4; ++nt)
          acc[mt][nt] = __builtin_amdgcn_mfma_f32_16x16x32_f16(
              af[mt], bfr[nt], acc[mt][nt], 0, 0, 0);
    }
    // ---- bounce acc (+bias, same rounding as before) into LDS ----
#pragma unroll
    for (int mt = 0; mt < 4; ++mt) {
#pragma unroll
      for (int r = 0; r < 4; ++r) {
        const int o = m0 + mt * 16 + lg * 4 + r;
        const float bv = kv_b[o];
#pragma unroll
        for (int nt = 0; nt < 4; ++nt)
          Bo[o * 136 + n0 + nt * 16 + lr] =
              __float2bfloat16(acc[mt][nt][r] + bv);
      }
    }
    __syncthreads();   // barB: bounce visible; also protects X for next pack
    // ---- coalesced stores: 4 full 256B o-rows per instruction ----
    {
      const int oo = tid >> 4;          // 0..15
      const int pxc = (tid & 15) * 8;   // 0..120
      bf16* dst = kv1 + (size_t)b * 128 * HW_ + sb + t * 128 + pxc;
#pragma unroll
      for (int rr = 0; rr < 8; ++rr) {
        const int o = oo + rr * 16;
        const int4 v = *reinterpret_cast<const int4*>(&Bo[o * 136 + pxc]);
        *reinterpret_cast<int4*>(dst + (size_t)o * HW_) = v;
      }
    }
    // ---- rotate prefetch registers ----
    if (t < 3) {
#pragma unroll
      for (int u = 0; u < 16; ++u) cur[u] = nxt[u];
    }
  }
}

// ---------------------------------------------------------------------------
// K1b: depthwise 3x3 (pad=1) on bf16 kv1 -> bf16 k||v (in d_out), fp32 math.
// Halo cols via wave shuffle.
__global__ __launch_bounds__(256) void k1b_dw(
    const bf16* __restrict__ kv1, const float* __restrict__ dw_w,
    const float* __restrict__ dw_b, bf16* __restrict__ kvout,
    float* __restrict__ ssqpart) {
  const int tid = threadIdx.x;
  const int cchunk = tid & 63;            // 64 col-chunks of 8
  const int ch_sub = tid >> 6;            // 4 channels per block
  const int rs = blockIdx.x;              // 16 row strips of 32
  const int chgrp = blockIdx.y;           // 32
  const int b = blockIdx.z;
  const int ch = chgrp * 4 + ch_sub;
  const int c0 = cchunk * 8;
  const int r0 = rs * 32;
  const bf16* src = kv1 + (size_t)(b * 128 + ch) * HW_;
  const bool is_k = (ch < 64);
  const size_t obase = is_k ? (size_t)(b * 64 + ch) * HW_
                            : (size_t)(128 + b * 64 + (ch - 64)) * HW_;
  bf16* dst = kvout + obase;
  float dwr[9];
#pragma unroll
  for (int t = 0; t < 9; ++t) dwr[t] = dw_w[ch * 9 + t];
  const float bd = dw_b[ch];

  float a0[10], a1[10], a2[10];
  auto loadrow = [&](int gr, float* a) {
    if (gr < 0 || gr >= H_) {
#pragma unroll
      for (int t = 0; t < 10; ++t) a[t] = 0.f;
      return;
    }
    union { int4 v; bf16 h[8]; } raw;
    raw.v = *reinterpret_cast<const int4*>(src + (size_t)gr * W_ + c0);
#pragma unroll
    for (int t = 0; t < 8; ++t) a[t + 1] = __bfloat162float(raw.h[t]);
    const float left = __shfl_up(a[8], 1);     // lane-1's col c0-1
    const float right = __shfl_down(a[1], 1);  // lane+1's col c0+8
    a[0] = (cchunk == 0) ? 0.f : left;
    a[9] = (cchunk == 63) ? 0.f : right;
  };
  loadrow(r0 - 1, a0);
  loadrow(r0, a1);
  float sq = 0.f;
#pragma unroll 4
  for (int rr = 0; rr < 32; ++rr) {
    loadrow(r0 + rr + 1, a2);
    union { int4 v; bf16 h[8]; } ou;
#pragma unroll
    for (int j = 0; j < 8; ++j) {
      const float ov = bd
          + dwr[0] * a0[j] + dwr[1] * a0[j + 1] + dwr[2] * a0[j + 2]
          + dwr[3] * a1[j] + dwr[4] * a1[j + 1] + dwr[5] * a1[j + 2]
          + dwr[6] * a2[j] + dwr[7] * a2[j + 1] + dwr[8] * a2[j + 2];
      sq += ov * ov;
      ou.h[j] = __float2bfloat16(ov);
    }
    *reinterpret_cast<int4*>(dst + (size_t)(r0 + rr) * W_ + c0) = ou.v;
#pragma unroll
    for (int t = 0; t < 10; ++t) { a0[t] = a1[t]; a1[t] = a2[t]; }
  }
  // wave reduction of sq over the 64 col-chunk lanes (same ch per wave)
#pragma unroll
  for (int off = 32; off > 0; off >>= 1) sq += __shfl_down(sq, off, 64);
  if (is_k && cchunk == 0)
    ssqpart[(size_t)(b * 64 + ch) * 16 + rs] = sq;
}

// ---------------------------------------------------------------------------
// K2: reduce sumsq partials -> rnorm; qn = sign(q)*rnorm*temps (k0 folded in)
__global__ __launch_bounds__(256) void k2_finalize(
    const float* __restrict__ ssqpart, const float* __restrict__ temps,
    const float* __restrict__ metainfo, const float* __restrict__ Wq,
    const float* __restrict__ bq, float* __restrict__ rnorm,
    float* __restrict__ qn) {
  const int tid = threadIdx.x;
  if (tid < 128) {
    const int b = tid >> 6, c = tid & 63;
    float s = 0.f;
    for (int p = 0; p < 16; ++p) s += ssqpart[(size_t)(b * 64 + c) * 16 + p];
    rnorm[tid] = 1.f / fmaxf(sqrtf(s), EPSV);
  }
  __syncthreads();
  for (int idx = tid; idx < 512; idx += 256) {
    const int b = idx >> 8, n = (idx >> 6) & 3, d = idx & 63;
    float acc = bq[n * 64 + d];
#pragma unroll
    for (int m = 0; m < 4; ++m)
      acc += metainfo[(b * 4 + n) * 4 + m] * Wq[(n * 64 + d) * 4 + m];
    const float sgn = acc / fmaxf(fabsf(acc), EPSV);
    qn[idx] = sgn * rnorm[b * 64 + d] * temps[n * 8 + (d >> 3)];
  }
}

// ---------------------------------------------------------------------------
// K3: softmax denominators from bf16 k. 8 px/thread, 16B k loads.
__global__ __launch_bounds__(256) void k3_denom(
    const bf16* __restrict__ kbuf, const float* __restrict__ qn,
    float* __restrict__ dpart) {
  const int tile = blockIdx.x, e = blockIdx.y, b = blockIdx.z;
  const int tid = threadIdx.x;
  float q[4][8];
#pragma unroll
  for (int n = 0; n < 4; ++n)
#pragma unroll
    for (int cc = 0; cc < 8; ++cc)
      q[n][cc] = qn[b * 256 + n * 64 + e * 8 + cc];
  const bf16* kb = kbuf + (size_t)(b * 64 + e * 8) * HW_;
  float dsum[4] = {0.f, 0.f, 0.f, 0.f};
  const int sbase = tile * 4096;
#pragma unroll
  for (int it = 0; it < 2; ++it) {
    const int s = sbase + (it * 256 + tid) * 8;
    float kf[8][8];
#pragma unroll
    for (int cc = 0; cc < 8; ++cc) {
      union { int4 v; bf16 h[8]; } r;
      r.v = *reinterpret_cast<const int4*>(kb + (size_t)cc * HW_ + s);
#pragma unroll
      for (int j = 0; j < 8; ++j) kf[cc][j] = __bfloat162float(r.h[j]);
    }
#pragma unroll
    for (int n = 0; n < 4; ++n) {
#pragma unroll
      for (int px = 0; px < 8; ++px) {
        float l = 0.f;
#pragma unroll
        for (int cc = 0; cc < 8; ++cc) l += q[n][cc] * kf[cc][px];
        dsum[n] += __expf(l);
      }
    }
  }
  __shared__ float red[256];
#pragma unroll
  for (int n = 0; n < 4; ++n) {
    red[tid] = dsum[n];
    __syncthreads();
    for (int st = 128; st > 0; st >>= 1) {
      if (tid < st) red[tid] += red[tid + st];
      __syncthreads();
    }
    if (tid == 0) dpart[(b * 32 + n * 8 + e) * 64 + tile] = red[0];
    __syncthreads();
  }
}

// ---------------------------------------------------------------------------
// K4: mid[b,cc,s] = sum_e (sum_n exp(l)/denom) * v[b,e,cc,s]  (bf16 k,v)
__global__ __launch_bounds__(256) void k4_attend(
    const bf16* __restrict__ kvbuf, const float* __restrict__ qn,
    const float* __restrict__ dpart, float* __restrict__ mid) {
  const int b = blockIdx.y;
  const int tid = threadIdx.x;
  __shared__ float qnl[256];
  __shared__ float rdl[32];
  qnl[tid] = qn[b * 256 + tid];
  if (tid < 32) {
    float s = 0.f;
    for (int t = 0; t < 64; ++t) s += dpart[(b * 32 + tid) * 64 + t];
    rdl[tid] = 1.f / s;
  }
  __syncthreads();
  const bf16* kb = kvbuf + (size_t)(b * 64) * HW_;
  const bf16* vb = kvbuf + (size_t)(128 + b * 64) * HW_;
  float* mb = mid + (size_t)b * 8 * HW_;
  const int s = (blockIdx.x * 256 + tid) * 4;
  float macc[8][4];
#pragma unroll
  for (int cc = 0; cc < 8; ++cc)
#pragma unroll
    for (int px = 0; px < 4; ++px) macc[cc][px] = 0.f;
#pragma unroll
  for (int e = 0; e < 8; ++e) {
    float kf[8][4];
#pragma unroll
    for (int cc = 0; cc < 8; ++cc) {
      union { ushort4 v; bf16 h[4]; } r;
      r.v = *reinterpret_cast<const ushort4*>(kb + (size_t)(e * 8 + cc) * HW_ + s);
#pragma unroll
      for (int px = 0; px < 4; ++px) kf[cc][px] = __bfloat162float(r.h[px]);
    }
    float wsum[4] = {0.f, 0.f, 0.f, 0.f};
#pragma unroll
    for (int n = 0; n < 4; ++n) {
      const float rd = rdl[n * 8 + e];
#pragma unroll
      for (int px = 0; px < 4; ++px) {
        float l = 0.f;
#pragma unroll
        for (int cc = 0; cc < 8; ++cc) l += qnl[n * 64 + e * 8 + cc] * kf[cc][px];
        wsum[px] += __expf(l) * rd;
      }
    }
#pragma unroll
    for (int cc = 0; cc < 8; ++cc) {
      union { ushort4 v; bf16 h[4]; } r;
      r.v = *reinterpret_cast<const ushort4*>(vb + (size_t)(e * 8 + cc) * HW_ + s);
#pragma unroll
      for (int px = 0; px < 4; ++px)
        macc[cc][px] += wsum[px] * __bfloat162float(r.h[px]);
    }
  }
#pragma unroll
  for (int cc = 0; cc < 8; ++cc)
    *reinterpret_cast<float4*>(mb + (size_t)cc * HW_ + s) =
        make_float4(macc[cc][0], macc[cc][1], macc[cc][2], macc[cc][3]);
}

// ---------------------------------------------------------------------------
// K5: grouped 3x3 (8->64, groups=8) + exact GELU + 1x1 (64->64) via f16 MFMA.
__global__ __launch_bounds__(256) void k5_cross(
    const float* __restrict__ mid, const float* __restrict__ cc1_w,
    const float* __restrict__ cc1_b, const float* __restrict__ cc2_w,
    const float* __restrict__ cc2_b, float* __restrict__ out) {
  const int tid = threadIdx.x;
  const int c0 = blockIdx.x * 128;
  const int r0 = blockIdx.y * 2;
  const int b = blockIdx.z;
  __shared__ float midl[8 * 4 * 132];   // [ch][4 rows][132]  16.5 KB
  __shared__ __fp16 gs[256 * 64];       // [px][oo] swizzled  32 KB
  __shared__ __fp16 w2s[64 * 64];       // [p][oo] swizzled    8 KB
  __shared__ float w1l[576];
  __shared__ float b1l[64], b2l[64];
  // stage mid tile (coalesced along cols)
  for (int idx = tid; idx < 8 * 4 * 130; idx += 256) {
    const int ch = idx / 520;
    const int rem = idx % 520;
    const int dr = rem / 130, lc = rem % 130;
    const int gr = r0 - 1 + dr, gc = c0 - 1 + lc;
    float v = 0.f;
    if (gr >= 0 && gr < H_ && gc >= 0 && gc < W_)
      v = mid[(size_t)(b * 8 + ch) * HW_ + (size_t)gr * W_ + gc];
    midl[(ch * 4 + dr) * 132 + lc] = v;
  }
  // stage w2 as f16 chunks: w2s[p][ooc^(p&7)] = cc2_w[p][ooc*8..+8]
#pragma unroll
  for (int rr = 0; rr < 2; ++rr) {
    const int idx = tid + rr * 256;
    const int p = idx >> 3, ooc = idx & 7;
    const float4 a = *reinterpret_cast<const float4*>(cc2_w + p * 64 + ooc * 8);
    const float4 c = *reinterpret_cast<const float4*>(cc2_w + p * 64 + ooc * 8 + 4);
    h16x8 h;
    h[0] = (__fp16)a.x; h[1] = (__fp16)a.y; h[2] = (__fp16)a.z; h[3] = (__fp16)a.w;
    h[4] = (__fp16)c.x; h[5] = (__fp16)c.y; h[6] = (__fp16)c.z; h[7] = (__fp16)c.w;
    *reinterpret_cast<h16x8*>(&w2s[p * 64 + ((ooc ^ (p & 7)) << 3)]) = h;
  }
  for (int idx = tid; idx < 576; idx += 256) w1l[idx] = cc1_w[idx];
  if (tid < 64) { b1l[tid] = cc1_b[tid]; b2l[tid] = cc2_b[tid]; }
  __syncthreads();

  // ---- phase 1: grouped 3x3 + GELU -> gs (f16, swizzled) ----
  {
    const int ty = tid >> 5, tx = tid & 31;
    const int rl = tx >> 4;            // local output row 0/1
    const int cb = (tx & 15) * 8;      // local col base
    float m[3][10];
#pragma unroll
    for (int dr = 0; dr < 3; ++dr)
#pragma unroll
      for (int t = 0; t < 10; ++t)
        m[dr][t] = midl[(ty * 4 + rl + dr) * 132 + cb + t];
    const int pxb = rl * 128 + cb;
#pragma unroll
    for (int hh = 0; hh < 2; ++hh) {
      float g[8][4];
#pragma unroll
      for (int j = 0; j < 8; ++j) {
        const int oo = ty * 8 + j;
        float w[9];
#pragma unroll
        for (int t = 0; t < 9; ++t) w[t] = w1l[oo * 9 + t];
        const float bb = b1l[oo];
#pragma unroll
        for (int i2 = 0; i2 < 4; ++i2) {
          const int i = hh * 4 + i2;
          float a = bb;
#pragma unroll
          for (int dr = 0; dr < 3; ++dr)
#pragma unroll
            for (int dc = 0; dc < 3; ++dc)
              a += w[dr * 3 + dc] * m[dr][i + dc];
          g[j][i2] = 0.5f * a * (1.f + erff(a * 0.70710678118654752f));
        }
      }
#pragma unroll
      for (int i2 = 0; i2 < 4; ++i2) {
        const int px = pxb + hh * 4 + i2;
        const int swz = (px ^ (px >> 3)) & 7;
        h16x8 h;
#pragma unroll
        for (int j = 0; j < 8; ++j) h[j] = (__fp16)g[j][i2];
        *reinterpret_cast<h16x8*>(&gs[px * 64 + ((ty ^ swz) << 3)]) = h;
      }
    }
  }
  __syncthreads();

  // ---- phase 2: out[p][px] = b2[p] + sum_oo w2[p][oo]*g[oo][px] via MFMA ----
  const int wv = tid >> 6, lane = tid & 63;
  const int n0 = wv * 64;
  const int lr = lane & 15, lg = lane >> 4;
  f32x4 acc[4][4];
#pragma unroll
  for (int mt = 0; mt < 4; ++mt)
#pragma unroll
    for (int nt = 0; nt < 4; ++nt) acc[mt][nt] = (f32x4){0.f, 0.f, 0.f, 0.f};
#pragma unroll
  for (int ks = 0; ks < 2; ++ks) {
    const int ooc = ks * 4 + lg;
    h16x8 af[4], bfr[4];
#pragma unroll
    for (int mt = 0; mt < 4; ++mt) {
      const int p = mt * 16 + lr;
      af[mt] = *reinterpret_cast<const h16x8*>(
          &w2s[p * 64 + ((ooc ^ (p & 7)) << 3)]);
    }
#pragma unroll
    for (int nt = 0; nt < 4; ++nt) {
      const int px = n0 + nt * 16 + lr;
      const int swz = (px ^ (px >> 3)) & 7;
      bfr[nt] = *reinterpret_cast<const h16x8*>(
          &gs[px * 64 + ((ooc ^ swz) << 3)]);
    }
#pragma unroll
    for (int mt = 0; mt < 4; ++mt)
#pragma unroll
      for (int nt = 0; nt < 4; ++nt)
        acc[mt][nt] = __builtin_amdgcn_mfma_f32_16x16x32_f16(
            af[mt], bfr[nt], acc[mt][nt], 0, 0, 0);
  }
  // ---- epilogue: C col = px (lane&15), row = p ((lane>>4)*4+r) ----
#pragma unroll
  for (int mt = 0; mt < 4; ++mt) {
#pragma unroll
    for (int r = 0; r < 4; ++r) {
      const int p = mt * 16 + lg * 4 + r;
      const float bv = b2l[p];
      float* op = out + (size_t)(b * 64 + p) * HW_;
#pragma unroll
      for (int nt = 0; nt < 4; ++nt) {
        const int px = n0 + nt * 16 + lr;
        const int grow = r0 + (px >> 7), gcol = c0 + (px & 127);
        op[(size_t)grow * W_ + gcol] = acc[mt][nt][r] + bv;
      }
    }
  }
}

// ---------------------------------------------------------------------------
extern "C" void kernel_launch(void* const* d_in, const int* in_sizes, int n_in,
                              void* d_out, int out_size, void* d_ws, size_t ws_size,
                              hipStream_t stream) {
  const float* x        = (const float*)d_in[0];
  const float* metainfo = (const float*)d_in[1];
  const float* Wq       = (const float*)d_in[2];
  const float* bq       = (const float*)d_in[3];
  const float* temps    = (const float*)d_in[4];
  const float* kv_w     = (const float*)d_in[5];
  const float* kv_b     = (const float*)d_in[6];
  const float* dw_w     = (const float*)d_in[7];
  const float* dw_b     = (const float*)d_in[8];
  const float* cc1_w    = (const float*)d_in[9];
  const float* cc1_b    = (const float*)d_in[10];
  const float* cc2_w    = (const float*)d_in[11];
  const float* cc2_b    = (const float*)d_in[12];
  float* out = (float*)d_out;

  // ws layout (float offsets): kv1 bf16 occupies [0, 33554432) float-equiv.
  float* ws      = (float*)d_ws;
  bf16*  kv1     = (bf16*)d_ws;           // 2*128*HW bf16 = 134.2 MB
  float* mid     = ws + 33554432;         // 2*8*HW fp32   = 16.8 MB
  float* small_  = ws + 37748736;
  float* ssqpart = small_;                // 2*64*16 = 2048
  float* rnorm   = small_ + 2560;         // 128
  float* qn      = small_ + 2688;         // 512
  float* dpart   = small_ + 3200;         // 64*64 = 4096

  // k (bf16) and v (bf16) live in d_out until K5 overwrites it with fp32 out.
  bf16* kvout = (bf16*)d_out;             // [k: 2*64*HW][v: 2*64*HW] bf16

  k1a_conv1x1<<<1024, 256, 0, stream>>>(x, kv_w, kv_b, kv1);
  k1b_dw<<<dim3(16, 32, 2), 256, 0, stream>>>(kv1, dw_w, dw_b, kvout, ssqpart);
  k2_finalize<<<1, 256, 0, stream>>>(ssqpart, temps, metainfo, Wq, bq,
                                     rnorm, qn);
  k3_denom<<<dim3(64, 8, 2), 256, 0, stream>>>(kvout, qn, dpart);
  k4_attend<<<dim3(256, 2), 256, 0, stream>>>(kvout, qn, dpart, mid);
  k5_cross<<<dim3(4, 256, 2), 256, 0, stream>>>(mid, cc1_w, cc1_b, cc2_w,
                                                cc2_b, out);
}